// Round 6
// baseline (509.511 us; speedup 1.0000x reference)
//
#include <hip/hip_runtime.h>
#include <math.h>

#define NN 50000
#define NE 800000
#define HD 128
#define FD 16
#define NPATH 16
#define PL 8
#define NM 6
#define NS 320
#define NB 196   // ceil(NN/256)
#define NSB 782  // ceil(NN/64)
#define AK 320   // K for fused GEMM (hsum128 | h128 | ef16 | deg | 1 | pad)
#define AKU 160  // uints per A row
#define NEGV -1000000000.0f

typedef unsigned int uint;
typedef unsigned short ushort;
typedef short bf16x8 __attribute__((ext_vector_type(8)));
typedef float f32x4 __attribute__((ext_vector_type(4)));

__device__ __forceinline__ float sigm(float x){ return 1.0f/(1.0f+expf(-x)); }

__device__ __forceinline__ ushort f2b(float f){
    union{float f; uint u;} v; v.f=f;
    uint r = v.u + 0x7FFFu + ((v.u>>16)&1u);
    return (ushort)(r>>16);
}
__device__ __forceinline__ float b2f(ushort s){
    union{uint u; float f;} v; v.u = ((uint)s)<<16; return v.f;
}
__device__ __forceinline__ float blo(uint v){ return b2f((ushort)(v&0xFFFF)); }
__device__ __forceinline__ float bhi(uint v){ return b2f((ushort)(v>>16)); }
__device__ __forceinline__ uint pack2(float a, float b){ return (uint)f2b(a) | (((uint)f2b(b))<<16); }

// ---- degree histogram ----
__global__ void k_deg(const int* __restrict__ ei, int* __restrict__ deg){
    int e = blockIdx.x*256 + threadIdx.x;
    if (e >= NE) return;
    atomicAdd(&deg[ei[NE + e]], 1);
}

// ---- hierarchical exclusive scan ----
__global__ void k_scan1(const int* __restrict__ deg, int* __restrict__ offs, int* __restrict__ bsum){
    int tid = threadIdx.x, bid = blockIdx.x;
    int idx = bid*256 + tid;
    int v = (idx<NN) ? deg[idx] : 0;
    int lane = tid&63, w = tid>>6;
    int x = v;
    #pragma unroll
    for (int d=1; d<64; d<<=1){ int y = __shfl_up(x,d); if (lane>=d) x += y; }
    __shared__ int wsum[4];
    if (lane==63) wsum[w] = x;
    __syncthreads();
    int base = 0;
    #pragma unroll
    for (int j=0;j<4;j++) if (j<w) base += wsum[j];
    if (idx<NN) offs[idx] = base + x - v;
    if (tid==255) bsum[bid] = base + x;
}
__global__ void k_scan2(int* __restrict__ bsum, int* __restrict__ offs){
    int tid = threadIdx.x;
    int v = (tid<NB) ? bsum[tid] : 0;
    int lane = tid&63, w = tid>>6;
    int x = v;
    #pragma unroll
    for (int d=1; d<64; d<<=1){ int y = __shfl_up(x,d); if (lane>=d) x += y; }
    __shared__ int wsum[4];
    if (lane==63) wsum[w] = x;
    __syncthreads();
    int base = 0;
    #pragma unroll
    for (int j=0;j<4;j++) if (j<w) base += wsum[j];
    if (tid<NB) bsum[tid] = base + x - v;
    if (tid==255) offs[NN] = base + x;
}
__global__ void k_scan3(const int* __restrict__ bsum, int* __restrict__ offs, int* __restrict__ cursor){
    int idx = blockIdx.x*256 + threadIdx.x;
    if (idx>=NN) return;
    int o = offs[idx] + bsum[blockIdx.x];
    offs[idx]=o; cursor[idx]=o;
}

// ---- fill CSR with src node + edge id ----
__global__ void k_fill(const int* __restrict__ ei, int* __restrict__ cursor,
                       int* __restrict__ csr_src, int* __restrict__ csr_eid){
    int e = blockIdx.x*256 + threadIdx.x;
    if (e >= NE) return;
    int dst = ei[NE+e];
    int src = ei[e];
    int pos = atomicAdd(&cursor[dst], 1);
    csr_src[pos] = src;
    csr_eid[pos] = e;
}

// ---- per-node 16-wide sums of edge_feat (by eid) and node_feat (by src) ----
__global__ void k_gat16(const int* __restrict__ csr_eid, const int* __restrict__ csr_src,
                        const float* __restrict__ edge_feat, const float* __restrict__ nf,
                        const int* __restrict__ offs,
                        float* __restrict__ ef_sum, float* __restrict__ nf_sum){
    int node = blockIdx.x*4 + (threadIdx.x>>6);
    int lane = threadIdx.x & 63;
    int k = lane & 15, sub = lane >> 4;
    int b = offs[node], e2 = offs[node+1];
    float ae = 0.f, an = 0.f;
    int i = b + sub;
    for (; i + 4 < e2; i += 8){
        int e0 = csr_eid[i], e1 = csr_eid[i+4];
        int s0 = csr_src[i], s1 = csr_src[i+4];
        float f0 = edge_feat[(size_t)e0*FD + k];
        float g0 = nf[(size_t)s0*FD + k];
        float f1 = edge_feat[(size_t)e1*FD + k];
        float g1 = nf[(size_t)s1*FD + k];
        ae += f0 + f1; an += g0 + g1;
    }
    if (i < e2){
        int e0 = csr_eid[i]; int s0 = csr_src[i];
        ae += edge_feat[(size_t)e0*FD + k];
        an += nf[(size_t)s0*FD + k];
    }
    ae += __shfl_xor(ae, 16); ae += __shfl_xor(ae, 32);
    an += __shfl_xor(an, 16); an += __shfl_xor(an, 32);
    if (sub == 0){ ef_sum[node*FD + k] = ae; nf_sum[node*FD + k] = an; }
}

// ---- Wf = W_ep@W_e ; bfv = b_ep@W_e + b_msg ----
__global__ void k_folds(const float* __restrict__ W_ep, const float* __restrict__ b_ep,
                        const float* __restrict__ W_msg, const float* __restrict__ b_msg,
                        float* __restrict__ Wf, float* __restrict__ bfv){
    int o = blockIdx.x*256 + threadIdx.x;
    if (o < FD*HD){
        int k=o>>7, c=o&127;
        float acc=0.f;
        for (int m=0;m<HD;m++) acc += W_ep[k*HD+m]*W_msg[(HD+m)*HD+c];
        Wf[o]=acc;
    } else if (o < FD*HD+HD){
        int c=o-FD*HD;
        float acc=b_msg[c];
        for (int m=0;m<HD;m++) acc += b_ep[m]*W_msg[(HD+m)*HD+c];
        bfv[c]=acc;
    }
}

// ---- build folded mega-weight W2T[512][320], col-interleaved gates: col = 4*j + g ----
// gates: 0=r, 1=z, 2=gi_n, 3=gh_n. Biases folded into k=273 (constant-1 column).
__global__ void k_wprep2(const float* __restrict__ W_ih, const float* __restrict__ W_hh,
                         const float* __restrict__ W_msg, const float* __restrict__ Wf,
                         const float* __restrict__ bfv,
                         const float* __restrict__ b_ih, const float* __restrict__ b_hh,
                         ushort* __restrict__ W2T){
    int c = blockIdx.x;       // 0..511
    int k = threadIdx.x;      // 0..319
    int j = c>>2, g = c&3;
    float v = 0.f;
    if (k < 128){
        if (g < 3){
            const float* wm = W_msg + (size_t)k*HD;
            const float* wi = W_ih + (size_t)(g*HD+j)*HD;
            float acc=0.f;
            for (int m=0;m<HD;m++) acc += wm[m]*wi[m];
            v = acc;
        }
    } else if (k < 256){
        int kk = k-128;
        if (g==0)      v = W_hh[(size_t)j*HD+kk];
        else if (g==1) v = W_hh[(size_t)(HD+j)*HD+kk];
        else if (g==3) v = W_hh[(size_t)(2*HD+j)*HD+kk];
    } else if (k < 272){
        if (g < 3){
            const float* wf = Wf + (size_t)(k-256)*HD;
            const float* wi = W_ih + (size_t)(g*HD+j)*HD;
            float acc=0.f;
            for (int m=0;m<HD;m++) acc += wf[m]*wi[m];
            v = acc;
        }
    } else if (k == 272){
        if (g < 3){
            const float* wi = W_ih + (size_t)(g*HD+j)*HD;
            float acc=0.f;
            for (int m=0;m<HD;m++) acc += bfv[m]*wi[m];
            v = acc;
        }
    } else if (k == 273){
        v = (g==0)? b_ih[j]+b_hh[j] : (g==1)? b_ih[HD+j]+b_hh[HD+j]
          : (g==2)? b_ih[2*HD+j] : b_hh[2*HD+j];
    }
    W2T[(size_t)c*AK + k] = f2b(v);
}

// ---- prep A0: h0 = nf@W_np+b_np ; hsum1 = nf_sum@W_np + deg*b_np ; statics -> A0 & A1 ----
__global__ void k_prep(const float* __restrict__ nf, const float* __restrict__ nf_sum,
                       const int* __restrict__ deg, const float* __restrict__ W_np,
                       const float* __restrict__ b_np, const float* __restrict__ ef_sum,
                       ushort* __restrict__ A0, ushort* __restrict__ A1){
    int idx = blockIdx.x*256 + threadIdx.x;  // NN*64
    int n = idx>>6, c2 = idx&63;
    int j = c2*2;
    const float* x = nf + (size_t)n*FD;
    const float* s = nf_sum + (size_t)n*FD;
    float d = (float)deg[n];
    float h0a = b_np[j], h0b = b_np[j+1];
    float hsa = d*b_np[j], hsb = d*b_np[j+1];
    #pragma unroll
    for (int k=0;k<FD;k++){
        float w0 = W_np[k*HD+j], w1 = W_np[k*HD+j+1];
        float xv = x[k], sv = s[k];
        h0a += xv*w0; h0b += xv*w1;
        hsa += sv*w0; hsb += sv*w1;
    }
    uint* a0 = (uint*)A0;
    a0[(size_t)n*AKU + 64 + c2] = pack2(h0a,h0b);
    a0[(size_t)n*AKU + c2]      = pack2(hsa,hsb);
    if (c2 < 32){
        int col = 256 + c2*2;
        float v0 = (col<272)? ef_sum[n*FD + (col-256)] : (col==272)? d : 0.f;
        float v1 = (col+1<272)? ef_sum[n*FD + (col+1-256)] : (col+1==273)? 1.f : 0.f;
        uint pv = pack2(v0,v1);
        a0[(size_t)n*AKU + 128 + c2] = pv;
        ((uint*)A1)[(size_t)n*AKU + 128 + c2] = pv;
    }
}

// ---- fused GEMM (K=320, interleaved gates) + LDS-staged GRU epilogue -> Anxt.h ----
__global__ __launch_bounds__(256) void k_fused(const ushort* __restrict__ A,
                                               const ushort* __restrict__ Bt,
                                               ushort* __restrict__ Anxt){
    __shared__ __align__(16) short LDS[128*128];   // 32KB: As[0:8192) Bs[8192:16384); epilogue: Gs = all
    short* As = LDS;
    short* Bs = LDS + 128*64;
    const int tid = threadIdx.x;
    const int lane = tid & 63, w = tid>>6;
    const int wm = w>>1, wn = w&1;
    const int n0 = blockIdx.x*128;     // gate-col block (grid.x = 4)
    const int m0 = blockIdx.y*128;
    f32x4 acc[4][4] = {};
    for (int kk=0; kk<5; ++kk){
        __syncthreads();
        #pragma unroll
        for (int i=0;i<4;i++){
            int id = tid + i*256;
            int row = id>>3, s = id&7;
            int phys = row*64 + ((s ^ (row&7))<<3);
            int ar = m0 + row; if (ar >= NN) ar = NN-1;
            *(int4*)&As[phys] = *(const int4*)(A + (size_t)ar*AK + kk*64 + s*8);
            *(int4*)&Bs[phys] = *(const int4*)(Bt + (size_t)(n0+row)*AK + kk*64 + s*8);
        }
        __syncthreads();
        #pragma unroll
        for (int ksel=0; ksel<2; ++ksel){
            bf16x8 af[4], bfr[4];
            #pragma unroll
            for (int t=0;t<4;t++){
                int arow = wm*64 + t*16 + (lane&15);
                int aslot = (ksel*4 + (lane>>4)) ^ (arow&7);
                af[t] = *(const bf16x8*)&As[arow*64 + aslot*8];
                int brow = wn*64 + t*16 + (lane&15);
                int bslot = (ksel*4 + (lane>>4)) ^ (brow&7);
                bfr[t] = *(const bf16x8*)&Bs[brow*64 + bslot*8];
            }
            #pragma unroll
            for (int mi=0;mi<4;mi++)
                #pragma unroll
                for (int ni=0;ni<4;ni++)
                    acc[mi][ni] = __builtin_amdgcn_mfma_f32_16x16x32_bf16(af[mi], bfr[ni], acc[mi][ni], 0,0,0);
        }
    }
    // dump gate tile to LDS (bf16), XOR-swizzled at 8B (4-gate) granularity
    __syncthreads();
    #pragma unroll
    for (int mi=0;mi<4;mi++){
        #pragma unroll
        for (int ni=0;ni<4;ni++){
            #pragma unroll
            for (int r=0;r<4;r++){
                int row = wm*64 + mi*16 + (lane>>4)*4 + r;
                int col = wn*64 + ni*16 + (lane&15);
                int pc = (col&3) | (((col>>2) ^ (row&7))<<2);
                LDS[row*128 + pc] = (short)f2b(acc[mi][ni][r]);
            }
        }
    }
    __syncthreads();
    // epilogue: thread -> (jl = tid&31, row group tid>>5); gates adjacent -> one 8B read
    {
        int jl = tid&31, rg = tid>>5;
        int j = (n0>>2) + jl;           // global hidden index
        #pragma unroll
        for (int rr=0; rr<16; ++rr){
            int row = rg*16 + rr;
            int n = m0 + row;
            if (n >= NN) continue;
            int pc = ((jl ^ (row&7))<<2);
            uint2 gv = *(const uint2*)&LDS[row*128 + pc];
            float xr = blo(gv.x), xz = bhi(gv.x);
            float xin = blo(gv.y), xhn = bhi(gv.y);
            float rv = sigm(xr), zv = sigm(xz);
            float nv = tanhf(xin + rv*xhn);
            float ho = b2f(A[(size_t)n*AK + 128 + j]);
            Anxt[(size_t)n*AK + 128 + j] = f2b((1.f-zv)*nv + zv*ho);
        }
    }
}

// ---- hsum[n] = sum over in-edges of h[src] (within same A buffer) ----
__global__ void k_gather(ushort* __restrict__ A, const int* __restrict__ offs,
                         const int* __restrict__ csr_src){
    int node = blockIdx.x*4 + (threadIdx.x>>6);
    int c2 = threadIdx.x & 63;
    int b = offs[node], e2 = offs[node+1];
    float a0 = 0.f, a1 = 0.f;
    const uint* hp = (const uint*)A;
    int i = b;
    for (; i + 8 <= e2; i += 8){
        int s0=csr_src[i],  s1=csr_src[i+1], s2=csr_src[i+2], s3=csr_src[i+3];
        int s4=csr_src[i+4],s5=csr_src[i+5], s6=csr_src[i+6], s7=csr_src[i+7];
        uint v0=hp[(size_t)s0*AKU+64+c2], v1=hp[(size_t)s1*AKU+64+c2],
             v2=hp[(size_t)s2*AKU+64+c2], v3=hp[(size_t)s3*AKU+64+c2],
             v4=hp[(size_t)s4*AKU+64+c2], v5=hp[(size_t)s5*AKU+64+c2],
             v6=hp[(size_t)s6*AKU+64+c2], v7=hp[(size_t)s7*AKU+64+c2];
        a0 += blo(v0)+blo(v1)+blo(v2)+blo(v3)+blo(v4)+blo(v5)+blo(v6)+blo(v7);
        a1 += bhi(v0)+bhi(v1)+bhi(v2)+bhi(v3)+bhi(v4)+bhi(v5)+bhi(v6)+bhi(v7);
    }
    if (i + 4 <= e2){
        int s0=csr_src[i],s1=csr_src[i+1],s2=csr_src[i+2],s3=csr_src[i+3];
        uint v0=hp[(size_t)s0*AKU+64+c2], v1=hp[(size_t)s1*AKU+64+c2],
             v2=hp[(size_t)s2*AKU+64+c2], v3=hp[(size_t)s3*AKU+64+c2];
        a0 += blo(v0)+blo(v1)+blo(v2)+blo(v3);
        a1 += bhi(v0)+bhi(v1)+bhi(v2)+bhi(v3);
        i += 4;
    }
    for (; i < e2; ++i){
        uint v = hp[(size_t)csr_src[i]*AKU+64+c2];
        a0 += blo(v); a1 += bhi(v);
    }
    ((uint*)A)[(size_t)node*AKU + c2] = pack2(a0,a1);
}

// ---- two-stage column sum of final h (no atomics) ----
__global__ void k_sum1(const ushort* __restrict__ A, float* __restrict__ partial){
    int bid = blockIdx.x, tid = threadIdx.x;
    int lane = tid&63, w2 = tid>>6;
    int nb = bid*64;
    float a0=0.f, a1=0.f;
    const uint* hp = (const uint*)A;
    #pragma unroll
    for (int r=w2; r<64; r+=4){
        int n = nb + r;
        if (n < NN){
            uint v = hp[(size_t)n*AKU + 64 + lane];
            a0 += blo(v); a1 += bhi(v);
        }
    }
    __shared__ float s0[4][64], s1[4][64];
    s0[w2][lane]=a0; s1[w2][lane]=a1;
    __syncthreads();
    if (w2==0){
        a0 = s0[0][lane]+s0[1][lane]+s0[2][lane]+s0[3][lane];
        a1 = s1[0][lane]+s1[1][lane]+s1[2][lane]+s1[3][lane];
        ((float2*)partial)[(size_t)bid*64 + lane] = make_float2(a0,a1);
    }
}
__global__ void k_sum2(const float* __restrict__ partial, float* __restrict__ gsum){
    int tid = threadIdx.x;
    int c = tid & 127, half = tid>>7;
    float a=0.f;
    for (int b=half; b<NSB; b+=2) a += partial[(size_t)b*128 + c];
    __shared__ float sh[2][128];
    sh[half][c]=a;
    __syncthreads();
    if (half==0) gsum[c] = sh[0][c]+sh[1][c];
}

// ---- tiny agents + value head, wave-parallel ----
__global__ void k_small(const float* __restrict__ ef, const int* __restrict__ paths,
                        const int* __restrict__ pmask, const float* __restrict__ pfeat,
                        const int* __restrict__ mmask, const int* __restrict__ smask,
                        const float* __restrict__ pspec,
                        const float* __restrict__ W_ep, const float* __restrict__ b_ep,
                        const float* __restrict__ W_path, const float* __restrict__ b_path,
                        const float* __restrict__ W_mod, const float* __restrict__ b_mod,
                        const float* __restrict__ c1w, const float* __restrict__ c1b,
                        const float* __restrict__ c2w, const float* __restrict__ c2b,
                        const float* __restrict__ W_val, const float* __restrict__ b_val,
                        const float* __restrict__ gsum, float* __restrict__ out){
    __shared__ float z[NPATH][HD];
    __shared__ float lf[NS];
    __shared__ float spec[NS];
    __shared__ float red[8];
    __shared__ float scal[3];
    __shared__ int   sel[3];
    __shared__ float maxsh;
    int tid = threadIdx.x, lane = tid&63, w = tid>>6;

    { // z[p][c] for 16 paths
        int pr = tid>>7, c = tid&127;
        #pragma unroll
        for (int pb=0; pb<4; pb++){
            int p = pb*4 + pr;
            float acc = 0.f;
            for (int l=0;l<PL;l++){
                int eid = paths[p*PL + l];
                const float* f = ef + (size_t)eid*FD;
                #pragma unroll
                for (int k=0;k<FD;k++) acc += f[k]*W_ep[k*HD + c];
            }
            z[p][c] = acc*0.125f + b_ep[c];
        }
    }
    __syncthreads();
    { // logits_p
        int p = tid>>5, sub = tid&31;
        float part = 0.f;
        #pragma unroll
        for (int c=sub;c<HD;c+=32) part += z[p][c]*W_path[c];
        #pragma unroll
        for (int d=16; d>=1; d>>=1) part += __shfl_xor(part, d);
        if (sub==0) lf[p] = (pmask[p]==0)? NEGV : part + b_path[0];
    }
    __syncthreads();
    if (w==0){
        float v = (lane<NPATH)? lf[lane] : -3.0e38f;
        float m = v;
        #pragma unroll
        for (int d=1; d<64; d<<=1) m = fmaxf(m, __shfl_xor(m, d));
        float e = (lane<NPATH)? expf(v-m) : 0.f;
        #pragma unroll
        for (int d=1; d<64; d<<=1) e += __shfl_xor(e, d);
        int idx = (lane<NPATH && v==m)? lane : (1<<30);
        #pragma unroll
        for (int d=1; d<64; d<<=1) idx = min(idx, __shfl_xor(idx, d));
        if (lane==0){ sel[0]=idx; scal[0] = -logf(e); }
    }
    __syncthreads();
    int pstar = sel[0];
    if (w < NM){
        float part = 0.f;
        #pragma unroll
        for (int c=lane;c<HD;c+=64) part += z[pstar][c]*W_mod[c*NM + w];
        if (lane<3) part += pfeat[pstar*3+lane]*W_mod[(HD+lane)*NM + w];
        #pragma unroll
        for (int d=1; d<64; d<<=1) part += __shfl_xor(part, d);
        if (lane==0) red[w] = (mmask[pstar*NM + w]==0)? NEGV : part + b_mod[w];
    } else if (w == 7){
        float part = gsum[lane]*W_val[lane] + gsum[lane+64]*W_val[lane+64];
        #pragma unroll
        for (int d=1; d<64; d<<=1) part += __shfl_xor(part, d);
        if (lane==0) scal[2] = part/(float)NN + b_val[0];
    }
    __syncthreads();
    if (w==0){
        float v = (lane<NM)? red[lane] : -3.0e38f;
        float m = v;
        #pragma unroll
        for (int d=1; d<64; d<<=1) m = fmaxf(m, __shfl_xor(m, d));
        float e = (lane<NM)? expf(v-m) : 0.f;
        #pragma unroll
        for (int d=1; d<64; d<<=1) e += __shfl_xor(e, d);
        int idx = (lane<NM && v==m)? lane : (1<<30);
        #pragma unroll
        for (int d=1; d<64; d<<=1) idx = min(idx, __shfl_xor(idx, d));
        if (lane==0){ sel[1]=idx; scal[1] = -logf(e); }
    }
    __syncthreads();
    int mstar = sel[1];
    if (tid < NS) spec[tid] = pspec[pstar*NS + tid];
    __syncthreads();
    float v = -3.0e38f;
    if (tid < NS){
        float acc = c2b[0];
        #pragma unroll
        for (int ch=0; ch<8; ch++){
            float a = c1b[ch];
            #pragma unroll
            for (int k=0;k<5;k++){
                int ss = tid + k - 2;
                if (ss>=0 && ss<NS) a += spec[ss]*c1w[ch*5+k];
            }
            a = fmaxf(a, 0.f);
            acc += a*c2w[ch];
        }
        v = (smask[pstar*NM*NS + mstar*NS + tid]==0) ? NEGV : acc;
    }
    float m = v;
    #pragma unroll
    for (int d=1; d<64; d<<=1) m = fmaxf(m, __shfl_xor(m, d));
    if (lane==0) red[w] = m;
    __syncthreads();
    if (tid==0){
        float mm = red[0];
        #pragma unroll
        for (int i=1;i<8;i++) mm = fmaxf(mm, red[i]);
        maxsh = mm; sel[2] = 1<<30;
    }
    __syncthreads();
    float M2 = maxsh;
    if (tid<NS && v==M2) atomicMin(&sel[2], tid);
    float e = (tid<NS)? expf(v-M2) : 0.f;
    #pragma unroll
    for (int d=1; d<64; d<<=1) e += __shfl_xor(e, d);
    if (lane==0) red[w] = e;
    __syncthreads();
    if (tid==0){
        float se = 0.f;
        #pragma unroll
        for (int i=0;i<8;i++) se += red[i];
        out[0] = (float)pstar;
        out[1] = (float)sel[2];
        out[2] = (float)mstar;
        out[3] = scal[0] + scal[1] - logf(se);
        out[4] = scal[2];
    }
}

extern "C" void kernel_launch(void* const* d_in, const int* in_sizes, int n_in,
                              void* d_out, int out_size, void* d_ws, size_t ws_size,
                              hipStream_t stream) {
    (void)in_sizes; (void)n_in; (void)out_size; (void)ws_size;
    const float* node_feat     = (const float*)d_in[0];
    const float* edge_feat     = (const float*)d_in[1];
    const int*   edge_index    = (const int*)d_in[2];
    const int*   paths         = (const int*)d_in[3];
    const int*   path_mask     = (const int*)d_in[4];
    const float* path_features = (const float*)d_in[5];
    const int*   mod_masks     = (const int*)d_in[6];
    const int*   spec_masks    = (const int*)d_in[7];
    const float* path_spectrum = (const float*)d_in[8];
    const float* W_np  = (const float*)d_in[9];
    const float* b_np  = (const float*)d_in[10];
    const float* W_ep  = (const float*)d_in[11];
    const float* b_ep  = (const float*)d_in[12];
    const float* W_msg = (const float*)d_in[13];
    const float* b_msg = (const float*)d_in[14];
    const float* W_ih  = (const float*)d_in[15];
    const float* b_ih  = (const float*)d_in[16];
    const float* W_hh  = (const float*)d_in[17];
    const float* b_hh  = (const float*)d_in[18];
    const float* W_path = (const float*)d_in[19];
    const float* b_path = (const float*)d_in[20];
    const float* W_mod  = (const float*)d_in[21];
    const float* b_mod  = (const float*)d_in[22];
    const float* c1w = (const float*)d_in[23];
    const float* c1b = (const float*)d_in[24];
    const float* c2w = (const float*)d_in[25];
    const float* c2b = (const float*)d_in[26];
    const float* W_val = (const float*)d_in[27];
    const float* b_val = (const float*)d_in[28];

    char* ws = (char*)d_ws;
    size_t off = 0;
    auto alloc = [&](size_t bytes)->char*{
        char* p = ws + off;
        off += (bytes + 255) & ~(size_t)255;
        return p;
    };
    int*    deg     = (int*)alloc((size_t)NN*4);
    int*    offs    = (int*)alloc((size_t)(NN+1)*4);
    int*    cursor  = (int*)alloc((size_t)NN*4);
    int*    bsum    = (int*)alloc((size_t)NB*4);
    int*    csr_src = (int*)alloc((size_t)NE*4);
    int*    csr_eid = (int*)alloc((size_t)NE*4);
    float*  ef_sum  = (float*)alloc((size_t)NN*FD*4);
    float*  nf_sum  = (float*)alloc((size_t)NN*FD*4);
    float*  Wf      = (float*)alloc((size_t)FD*HD*4);
    float*  bfv     = (float*)alloc((size_t)HD*4);
    ushort* W2T     = (ushort*)alloc((size_t)512*AK*2);
    ushort* A0      = (ushort*)alloc((size_t)NN*AK*2);
    ushort* A1      = (ushort*)alloc((size_t)NN*AK*2);
    float*  partial = (float*)alloc((size_t)NSB*HD*4);
    float*  gsum    = (float*)alloc((size_t)HD*4);

    hipMemsetAsync(deg, 0, (size_t)NN*4, stream);

    k_deg<<<(NE+255)/256, 256, 0, stream>>>(edge_index, deg);
    k_scan1<<<NB, 256, 0, stream>>>(deg, offs, bsum);
    k_scan2<<<1, 256, 0, stream>>>(bsum, offs);
    k_scan3<<<NB, 256, 0, stream>>>(bsum, offs, cursor);
    k_fill<<<(NE+255)/256, 256, 0, stream>>>(edge_index, cursor, csr_src, csr_eid);
    k_gat16<<<NN/4, 256, 0, stream>>>(csr_eid, csr_src, edge_feat, node_feat, offs, ef_sum, nf_sum);
    k_folds<<<9, 256, 0, stream>>>(W_ep, b_ep, W_msg, b_msg, Wf, bfv);
    k_wprep2<<<512, AK, 0, stream>>>(W_ih, W_hh, W_msg, Wf, bfv, b_ih, b_hh, W2T);
    k_prep<<<NN*64/256, 256, 0, stream>>>(node_feat, nf_sum, deg, W_np, b_np, ef_sum, A0, A1);

    const int MB = (NN+127)/128;   // 391
    // iter 1: A0 -> A1.h
    k_fused<<<dim3(4,MB), 256, 0, stream>>>(A0, W2T, A1);
    // iter 2: gather(A1) -> A0.h
    k_gather<<<NN/4, 256, 0, stream>>>(A1, offs, csr_src);
    k_fused<<<dim3(4,MB), 256, 0, stream>>>(A1, W2T, A0);
    // iter 3: gather(A0) -> A1.h
    k_gather<<<NN/4, 256, 0, stream>>>(A0, offs, csr_src);
    k_fused<<<dim3(4,MB), 256, 0, stream>>>(A0, W2T, A1);

    k_sum1<<<NSB, 256, 0, stream>>>(A1, partial);
    k_sum2<<<1, 256, 0, stream>>>(partial, gsum);
    k_small<<<1, 512, 0, stream>>>(edge_feat, paths, path_mask, path_features,
                                   mod_masks, spec_masks, path_spectrum,
                                   W_ep, b_ep, W_path, b_path, W_mod, b_mod,
                                   c1w, c1b, c2w, c2b, W_val, b_val,
                                   gsum, (float*)d_out);
}

// Round 7
// 413.479 us; speedup vs baseline: 1.2323x; 1.2323x over previous
//
#include <hip/hip_runtime.h>
#include <math.h>

#define NN 50000
#define NE 800000
#define HD 128
#define FD 16
#define NPATH 16
#define PL 8
#define NM 6
#define NS 320
#define NB 196   // ceil(NN/256)
#define NSB 782  // ceil(NN/64)
#define AK 320   // K for fused GEMM (hsum128 | h128 | ef16 | deg | 1 | pad)
#define AKU 160  // uints per A row
#define NEGV -1000000000.0f

typedef unsigned int uint;
typedef unsigned short ushort;
typedef short bf16x8 __attribute__((ext_vector_type(8)));
typedef float f32x4 __attribute__((ext_vector_type(4)));

__device__ __forceinline__ float sigm(float x){ return 1.0f/(1.0f+expf(-x)); }

__device__ __forceinline__ ushort f2b(float f){
    union{float f; uint u;} v; v.f=f;
    uint r = v.u + 0x7FFFu + ((v.u>>16)&1u);
    return (ushort)(r>>16);
}
__device__ __forceinline__ float b2f(ushort s){
    union{uint u; float f;} v; v.u = ((uint)s)<<16; return v.f;
}
__device__ __forceinline__ float blo(uint v){ return b2f((ushort)(v&0xFFFF)); }
__device__ __forceinline__ float bhi(uint v){ return b2f((ushort)(v>>16)); }
__device__ __forceinline__ uint pack2(float a, float b){ return (uint)f2b(a) | (((uint)f2b(b))<<16); }

// ---- degree histogram ----
__global__ void k_deg(const int* __restrict__ ei, int* __restrict__ deg){
    int e = blockIdx.x*256 + threadIdx.x;
    if (e >= NE) return;
    atomicAdd(&deg[ei[NE + e]], 1);
}

// ---- hierarchical exclusive scan ----
__global__ void k_scan1(const int* __restrict__ deg, int* __restrict__ offs, int* __restrict__ bsum){
    int tid = threadIdx.x, bid = blockIdx.x;
    int idx = bid*256 + tid;
    int v = (idx<NN) ? deg[idx] : 0;
    int lane = tid&63, w = tid>>6;
    int x = v;
    #pragma unroll
    for (int d=1; d<64; d<<=1){ int y = __shfl_up(x,d); if (lane>=d) x += y; }
    __shared__ int wsum[4];
    if (lane==63) wsum[w] = x;
    __syncthreads();
    int base = 0;
    #pragma unroll
    for (int j=0;j<4;j++) if (j<w) base += wsum[j];
    if (idx<NN) offs[idx] = base + x - v;
    if (tid==255) bsum[bid] = base + x;
}
__global__ void k_scan2(int* __restrict__ bsum, int* __restrict__ offs){
    int tid = threadIdx.x;
    int v = (tid<NB) ? bsum[tid] : 0;
    int lane = tid&63, w = tid>>6;
    int x = v;
    #pragma unroll
    for (int d=1; d<64; d<<=1){ int y = __shfl_up(x,d); if (lane>=d) x += y; }
    __shared__ int wsum[4];
    if (lane==63) wsum[w] = x;
    __syncthreads();
    int base = 0;
    #pragma unroll
    for (int j=0;j<4;j++) if (j<w) base += wsum[j];
    if (tid<NB) bsum[tid] = base + x - v;
    if (tid==255) offs[NN] = base + x;
}
__global__ void k_scan3(const int* __restrict__ bsum, int* __restrict__ offs, int* __restrict__ cursor){
    int idx = blockIdx.x*256 + threadIdx.x;
    if (idx>=NN) return;
    int o = offs[idx] + bsum[blockIdx.x];
    offs[idx]=o; cursor[idx]=o;
}

// ---- fill CSR with src node + edge id ----
__global__ void k_fill(const int* __restrict__ ei, int* __restrict__ cursor,
                       int* __restrict__ csr_src, int* __restrict__ csr_eid){
    int e = blockIdx.x*256 + threadIdx.x;
    if (e >= NE) return;
    int dst = ei[NE+e];
    int src = ei[e];
    int pos = atomicAdd(&cursor[dst], 1);
    csr_src[pos] = src;
    csr_eid[pos] = e;
}

// ---- per-node 16-wide sums of edge_feat (by eid) and node_feat (by src) ----
__global__ void k_gat16(const int* __restrict__ csr_eid, const int* __restrict__ csr_src,
                        const float* __restrict__ edge_feat, const float* __restrict__ nf,
                        const int* __restrict__ offs,
                        float* __restrict__ ef_sum, float* __restrict__ nf_sum){
    int node = blockIdx.x*4 + (threadIdx.x>>6);
    int lane = threadIdx.x & 63;
    int k = lane & 15, sub = lane >> 4;
    int b = offs[node], e2 = offs[node+1];
    float ae = 0.f, an = 0.f;
    int i = b + sub;
    for (; i + 4 < e2; i += 8){
        int e0 = csr_eid[i], e1 = csr_eid[i+4];
        int s0 = csr_src[i], s1 = csr_src[i+4];
        float f0 = edge_feat[(size_t)e0*FD + k];
        float g0 = nf[(size_t)s0*FD + k];
        float f1 = edge_feat[(size_t)e1*FD + k];
        float g1 = nf[(size_t)s1*FD + k];
        ae += f0 + f1; an += g0 + g1;
    }
    if (i < e2){
        int e0 = csr_eid[i]; int s0 = csr_src[i];
        ae += edge_feat[(size_t)e0*FD + k];
        an += nf[(size_t)s0*FD + k];
    }
    ae += __shfl_xor(ae, 16); ae += __shfl_xor(ae, 32);
    an += __shfl_xor(an, 16); an += __shfl_xor(an, 32);
    if (sub == 0){ ef_sum[node*FD + k] = ae; nf_sum[node*FD + k] = an; }
}

// ---- Wf = W_ep@W_e ; bfv = b_ep@W_e + b_msg ----
__global__ void k_folds(const float* __restrict__ W_ep, const float* __restrict__ b_ep,
                        const float* __restrict__ W_msg, const float* __restrict__ b_msg,
                        float* __restrict__ Wf, float* __restrict__ bfv){
    int o = blockIdx.x*256 + threadIdx.x;
    if (o < FD*HD){
        int k=o>>7, c=o&127;
        float acc=0.f;
        for (int m=0;m<HD;m++) acc += W_ep[k*HD+m]*W_msg[(HD+m)*HD+c];
        Wf[o]=acc;
    } else if (o < FD*HD+HD){
        int c=o-FD*HD;
        float acc=b_msg[c];
        for (int m=0;m<HD;m++) acc += b_ep[m]*W_msg[(HD+m)*HD+c];
        bfv[c]=acc;
    }
}

// ---- build folded mega-weight W2T[512][320], gate-blocked: col = g*128 + j ----
// gates: 0=r, 1=z, 2=gi_n, 3=gh_n. Biases folded into k=273 (constant-1 column).
__global__ void k_wprep2(const float* __restrict__ W_ih, const float* __restrict__ W_hh,
                         const float* __restrict__ W_msg, const float* __restrict__ Wf,
                         const float* __restrict__ bfv,
                         const float* __restrict__ b_ih, const float* __restrict__ b_hh,
                         ushort* __restrict__ W2T){
    int c = blockIdx.x;       // 0..511
    int k = threadIdx.x;      // 0..319
    int g = c>>7, j = c&127;
    float v = 0.f;
    if (k < 128){
        if (g < 3){   // hsum path: (W_h @ W_ih_g^T)
            const float* wm = W_msg + (size_t)k*HD;
            const float* wi = W_ih + (size_t)(g*HD+j)*HD;
        float acc=0.f;
            for (int m=0;m<HD;m++) acc += wm[m]*wi[m];
            v = acc;
        }
    } else if (k < 256){      // h path: W_hh gates (none for gi_n)
        int kk = k-128;
        if (g==0)      v = W_hh[(size_t)j*HD+kk];
        else if (g==1) v = W_hh[(size_t)(HD+j)*HD+kk];
        else if (g==3) v = W_hh[(size_t)(2*HD+j)*HD+kk];
    } else if (k < 272){      // ef_sum path
        if (g < 3){
            const float* wf = Wf + (size_t)(k-256)*HD;
            const float* wi = W_ih + (size_t)(g*HD+j)*HD;
            float acc=0.f;
            for (int m=0;m<HD;m++) acc += wf[m]*wi[m];
            v = acc;
        }
    } else if (k == 272){     // deg path
        if (g < 3){
            const float* wi = W_ih + (size_t)(g*HD+j)*HD;
            float acc=0.f;
            for (int m=0;m<HD;m++) acc += bfv[m]*wi[m];
            v = acc;
        }
    } else if (k == 273){     // constant-1: biases
        v = (g==0)? b_ih[j]+b_hh[j] : (g==1)? b_ih[HD+j]+b_hh[HD+j]
          : (g==2)? b_ih[2*HD+j] : b_hh[2*HD+j];
    }
    W2T[(size_t)c*AK + k] = f2b(v);
}

// ---- prep A0: h0 = nf@W_np+b_np ; hsum1 = nf_sum@W_np + deg*b_np ; statics -> A0 & A1 ----
__global__ void k_prep(const float* __restrict__ nf, const float* __restrict__ nf_sum,
                       const int* __restrict__ deg, const float* __restrict__ W_np,
                       const float* __restrict__ b_np, const float* __restrict__ ef_sum,
                       ushort* __restrict__ A0, ushort* __restrict__ A1){
    int idx = blockIdx.x*256 + threadIdx.x;  // NN*64
    int n = idx>>6, c2 = idx&63;
    int j = c2*2;
    const float* x = nf + (size_t)n*FD;
    const float* s = nf_sum + (size_t)n*FD;
    float d = (float)deg[n];
    float h0a = b_np[j], h0b = b_np[j+1];
    float hsa = d*b_np[j], hsb = d*b_np[j+1];
    #pragma unroll
    for (int k=0;k<FD;k++){
        float w0 = W_np[k*HD+j], w1 = W_np[k*HD+j+1];
        float xv = x[k], sv = s[k];
        h0a += xv*w0; h0b += xv*w1;
        hsa += sv*w0; hsb += sv*w1;
    }
    uint* a0 = (uint*)A0;
    a0[(size_t)n*AKU + 64 + c2] = pack2(h0a,h0b);
    a0[(size_t)n*AKU + c2]      = pack2(hsa,hsb);
    if (c2 < 32){
        int col = 256 + c2*2;
        float v0 = (col<272)? ef_sum[n*FD + (col-256)] : (col==272)? d : 0.f;
        float v1 = (col+1<272)? ef_sum[n*FD + (col+1-256)] : (col+1==273)? 1.f : 0.f;
        uint pv = pack2(v0,v1);
        a0[(size_t)n*AKU + 128 + c2] = pv;
        ((uint*)A1)[(size_t)n*AKU + 128 + c2] = pv;
    }
}

// ---- G[NN][512] = A[NN][320] @ W2T[512][320]^T, 128x128 tile, K=320 ----
// grid = dim3(4, MB): gate blocks fastest-varying -> A m-tile shared in L2
__global__ __launch_bounds__(256) void k_gemmG(const ushort* __restrict__ A,
                                               const ushort* __restrict__ Bt,
                                               ushort* __restrict__ G){
    __shared__ __align__(16) short As[128*64];
    __shared__ __align__(16) short Bs[128*64];
    const int tid = threadIdx.x;
    const int lane = tid & 63, w = tid>>6;
    const int wm = w>>1, wn = w&1;
    const int n0 = blockIdx.x*128, m0 = blockIdx.y*128;
    f32x4 acc[4][4] = {};
    for (int kk=0; kk<5; ++kk){
        __syncthreads();
        #pragma unroll
        for (int i=0;i<4;i++){
            int id = tid + i*256;
            int row = id>>3, s = id&7;
            int phys = row*64 + ((s ^ (row&7))<<3);
            int ar = m0 + row; if (ar >= NN) ar = NN-1;
            *(int4*)&As[phys] = *(const int4*)(A + (size_t)ar*AK + kk*64 + s*8);
            *(int4*)&Bs[phys] = *(const int4*)(Bt + (size_t)(n0+row)*AK + kk*64 + s*8);
        }
        __syncthreads();
        #pragma unroll
        for (int ksel=0; ksel<2; ++ksel){
            bf16x8 af[4], bfr[4];
            #pragma unroll
            for (int t=0;t<4;t++){
                int arow = wm*64 + t*16 + (lane&15);
                int aslot = (ksel*4 + (lane>>4)) ^ (arow&7);
                af[t] = *(const bf16x8*)&As[arow*64 + aslot*8];
                int brow = wn*64 + t*16 + (lane&15);
                int bslot = (ksel*4 + (lane>>4)) ^ (brow&7);
                bfr[t] = *(const bf16x8*)&Bs[brow*64 + bslot*8];
            }
            #pragma unroll
            for (int mi=0;mi<4;mi++)
                #pragma unroll
                for (int ni=0;ni<4;ni++)
                    acc[mi][ni] = __builtin_amdgcn_mfma_f32_16x16x32_bf16(af[mi], bfr[ni], acc[mi][ni], 0,0,0);
        }
    }
    #pragma unroll
    for (int mi=0;mi<4;mi++){
        #pragma unroll
        for (int r=0;r<4;r++){
            int row = m0 + wm*64 + mi*16 + (lane>>4)*4 + r;
            if (row >= NN) continue;
            #pragma unroll
            for (int ni=0;ni<4;ni++){
                int col = n0 + wn*64 + ni*16 + (lane&15);
                G[(size_t)row*512 + col] = f2b(acc[mi][ni][r]);
            }
        }
    }
}

// ---- GRU epilogue: G=[r|z|in|hn] (biases pre-folded) + A.h -> Anxt.h ----
__global__ void k_gruep(const ushort* __restrict__ G, const ushort* __restrict__ A,
                        ushort* __restrict__ Anxt){
    int idx = blockIdx.x*256 + threadIdx.x;   // NN*64
    int n = idx>>6, c2 = idx&63;
    const uint* g = (const uint*)G + (size_t)n*256;
    uint vr = g[c2], vz = g[64+c2], vin = g[128+c2], vhn = g[192+c2];
    uint vh = ((const uint*)A)[(size_t)n*AKU + 64 + c2];
    float r0 = sigm(blo(vr)), r1 = sigm(bhi(vr));
    float z0 = sigm(blo(vz)), z1 = sigm(bhi(vz));
    float n0 = tanhf(blo(vin) + r0*blo(vhn));
    float n1 = tanhf(bhi(vin) + r1*bhi(vhn));
    float h0 = (1.f-z0)*n0 + z0*blo(vh);
    float h1 = (1.f-z1)*n1 + z1*bhi(vh);
    ((uint*)Anxt)[(size_t)n*AKU + 64 + c2] = pack2(h0,h1);
}

// ---- hsum[n] = sum over in-edges of h[src] (within same A buffer) ----
__global__ void k_gather(ushort* __restrict__ A, const int* __restrict__ offs,
                         const int* __restrict__ csr_src){
    int node = blockIdx.x*4 + (threadIdx.x>>6);
    int c2 = threadIdx.x & 63;
    int b = offs[node], e2 = offs[node+1];
    float a0 = 0.f, a1 = 0.f;
    const uint* hp = (const uint*)A;
    int i = b;
    for (; i + 8 <= e2; i += 8){
        int s0=csr_src[i],  s1=csr_src[i+1], s2=csr_src[i+2], s3=csr_src[i+3];
        int s4=csr_src[i+4],s5=csr_src[i+5], s6=csr_src[i+6], s7=csr_src[i+7];
        uint v0=hp[(size_t)s0*AKU+64+c2], v1=hp[(size_t)s1*AKU+64+c2],
             v2=hp[(size_t)s2*AKU+64+c2], v3=hp[(size_t)s3*AKU+64+c2],
             v4=hp[(size_t)s4*AKU+64+c2], v5=hp[(size_t)s5*AKU+64+c2],
             v6=hp[(size_t)s6*AKU+64+c2], v7=hp[(size_t)s7*AKU+64+c2];
        a0 += blo(v0)+blo(v1)+blo(v2)+blo(v3)+blo(v4)+blo(v5)+blo(v6)+blo(v7);
        a1 += bhi(v0)+bhi(v1)+bhi(v2)+bhi(v3)+bhi(v4)+bhi(v5)+bhi(v6)+bhi(v7);
    }
    if (i + 4 <= e2){
        int s0=csr_src[i],s1=csr_src[i+1],s2=csr_src[i+2],s3=csr_src[i+3];
        uint v0=hp[(size_t)s0*AKU+64+c2], v1=hp[(size_t)s1*AKU+64+c2],
             v2=hp[(size_t)s2*AKU+64+c2], v3=hp[(size_t)s3*AKU+64+c2];
        a0 += blo(v0)+blo(v1)+blo(v2)+blo(v3);
        a1 += bhi(v0)+bhi(v1)+bhi(v2)+bhi(v3);
        i += 4;
    }
    for (; i < e2; ++i){
        uint v = hp[(size_t)csr_src[i]*AKU+64+c2];
        a0 += blo(v); a1 += bhi(v);
    }
    ((uint*)A)[(size_t)node*AKU + c2] = pack2(a0,a1);
}

// ---- two-stage column sum of final h (no atomics, fully parallel stage 2) ----
__global__ void k_sum1(const ushort* __restrict__ A, float* __restrict__ partial){
    int bid = blockIdx.x, tid = threadIdx.x;
    int lane = tid&63, w2 = tid>>6;
    int nb = bid*64;
    float a0=0.f, a1=0.f;
    const uint* hp = (const uint*)A;
    #pragma unroll
    for (int r=w2; r<64; r+=4){
        int n = nb + r;
        if (n < NN){
            uint v = hp[(size_t)n*AKU + 64 + lane];
            a0 += blo(v); a1 += bhi(v);
        }
    }
    __shared__ float s0[4][64], s1[4][64];
    s0[w2][lane]=a0; s1[w2][lane]=a1;
    __syncthreads();
    if (w2==0){
        a0 = s0[0][lane]+s0[1][lane]+s0[2][lane]+s0[3][lane];
        a1 = s1[0][lane]+s1[1][lane]+s1[2][lane]+s1[3][lane];
        ((float2*)partial)[(size_t)bid*64 + lane] = make_float2(a0,a1);
    }
}
// one block per column; threads cover rows in parallel (<=4 loads each)
__global__ void k_sum2(const float* __restrict__ partial, float* __restrict__ gsum){
    int c = blockIdx.x;          // 0..127
    int tid = threadIdx.x;       // 256
    int lane = tid&63, w = tid>>6;
    float a = 0.f;
    for (int b=tid; b<NSB; b+=256) a += partial[(size_t)b*128 + c];
    #pragma unroll
    for (int d=1; d<64; d<<=1) a += __shfl_xor(a, d);
    __shared__ float sh[4];
    if (lane==0) sh[w]=a;
    __syncthreads();
    if (tid==0) gsum[c] = sh[0]+sh[1]+sh[2]+sh[3];
}

// ---- tiny agents + value head, wave-parallel ----
__global__ void k_small(const float* __restrict__ ef, const int* __restrict__ paths,
                        const int* __restrict__ pmask, const float* __restrict__ pfeat,
                        const int* __restrict__ mmask, const int* __restrict__ smask,
                        const float* __restrict__ pspec,
                        const float* __restrict__ W_ep, const float* __restrict__ b_ep,
                        const float* __restrict__ W_path, const float* __restrict__ b_path,
                        const float* __restrict__ W_mod, const float* __restrict__ b_mod,
                        const float* __restrict__ c1w, const float* __restrict__ c1b,
                        const float* __restrict__ c2w, const float* __restrict__ c2b,
                        const float* __restrict__ W_val, const float* __restrict__ b_val,
                        const float* __restrict__ gsum, float* __restrict__ out){
    __shared__ float z[NPATH][HD];
    __shared__ float lf[NS];
    __shared__ float spec[NS];
    __shared__ float red[8];
    __shared__ float scal[3];
    __shared__ int   sel[3];
    __shared__ float maxsh;
    int tid = threadIdx.x, lane = tid&63, w = tid>>6;

    { // z[p][c] for 16 paths
        int pr = tid>>7, c = tid&127;
        #pragma unroll
        for (int pb=0; pb<4; pb++){
            int p = pb*4 + pr;
            float acc = 0.f;
            for (int l=0;l<PL;l++){
                int eid = paths[p*PL + l];
                const float* f = ef + (size_t)eid*FD;
                #pragma unroll
                for (int k=0;k<FD;k++) acc += f[k]*W_ep[k*HD + c];
            }
            z[p][c] = acc*0.125f + b_ep[c];
        }
    }
    __syncthreads();
    { // logits_p
        int p = tid>>5, sub = tid&31;
        float part = 0.f;
        #pragma unroll
        for (int c=sub;c<HD;c+=32) part += z[p][c]*W_path[c];
        #pragma unroll
        for (int d=16; d>=1; d>>=1) part += __shfl_xor(part, d);
        if (sub==0) lf[p] = (pmask[p]==0)? NEGV : part + b_path[0];
    }
    __syncthreads();
    if (w==0){
        float v = (lane<NPATH)? lf[lane] : -3.0e38f;
        float m = v;
        #pragma unroll
        for (int d=1; d<64; d<<=1) m = fmaxf(m, __shfl_xor(m, d));
        float e = (lane<NPATH)? expf(v-m) : 0.f;
        #pragma unroll
        for (int d=1; d<64; d<<=1) e += __shfl_xor(e, d);
        int idx = (lane<NPATH && v==m)? lane : (1<<30);
        #pragma unroll
        for (int d=1; d<64; d<<=1) idx = min(idx, __shfl_xor(idx, d));
        if (lane==0){ sel[0]=idx; scal[0] = -logf(e); }
    }
    __syncthreads();
    int pstar = sel[0];
    if (w < NM){
        float part = 0.f;
        #pragma unroll
        for (int c=lane;c<HD;c+=64) part += z[pstar][c]*W_mod[c*NM + w];
        if (lane<3) part += pfeat[pstar*3+lane]*W_mod[(HD+lane)*NM + w];
        #pragma unroll
        for (int d=1; d<64; d<<=1) part += __shfl_xor(part, d);
        if (lane==0) red[w] = (mmask[pstar*NM + w]==0)? NEGV : part + b_mod[w];
    } else if (w == 7){
        float part = gsum[lane]*W_val[lane] + gsum[lane+64]*W_val[lane+64];
        #pragma unroll
        for (int d=1; d<64; d<<=1) part += __shfl_xor(part, d);
        if (lane==0) scal[2] = part/(float)NN + b_val[0];
    }
    __syncthreads();
    if (w==0){
        float v = (lane<NM)? red[lane] : -3.0e38f;
        float m = v;
        #pragma unroll
        for (int d=1; d<64; d<<=1) m = fmaxf(m, __shfl_xor(m, d));
        float e = (lane<NM)? expf(v-m) : 0.f;
        #pragma unroll
        for (int d=1; d<64; d<<=1) e += __shfl_xor(e, d);
        int idx = (lane<NM && v==m)? lane : (1<<30);
        #pragma unroll
        for (int d=1; d<64; d<<=1) idx = min(idx, __shfl_xor(idx, d));
        if (lane==0){ sel[1]=idx; scal[1] = -logf(e); }
    }
    __syncthreads();
    int mstar = sel[1];
    if (tid < NS) spec[tid] = pspec[pstar*NS + tid];
    __syncthreads();
    float v = -3.0e38f;
    if (tid < NS){
        float acc = c2b[0];
        #pragma unroll
        for (int ch=0; ch<8; ch++){
            float a = c1b[ch];
            #pragma unroll
            for (int k=0;k<5;k++){
                int ss = tid + k - 2;
                if (ss>=0 && ss<NS) a += spec[ss]*c1w[ch*5+k];
            }
            a = fmaxf(a, 0.f);
            acc += a*c2w[ch];
        }
        v = (smask[pstar*NM*NS + mstar*NS + tid]==0) ? NEGV : acc;
    }
    float m = v;
    #pragma unroll
    for (int d=1; d<64; d<<=1) m = fmaxf(m, __shfl_xor(m, d));
    if (lane==0) red[w] = m;
    __syncthreads();
    if (tid==0){
        float mm = red[0];
        #pragma unroll
        for (int i=1;i<8;i++) mm = fmaxf(mm, red[i]);
        maxsh = mm; sel[2] = 1<<30;
    }
    __syncthreads();
    float M2 = maxsh;
    if (tid<NS && v==M2) atomicMin(&sel[2], tid);
    float e = (tid<NS)? expf(v-M2) : 0.f;
    #pragma unroll
    for (int d=1; d<64; d<<=1) e += __shfl_xor(e, d);
    if (lane==0) red[w] = e;
    __syncthreads();
    if (tid==0){
        float se = 0.f;
        #pragma unroll
        for (int i=0;i<8;i++) se += red[i];
        out[0] = (float)pstar;
        out[1] = (float)sel[2];
        out[2] = (float)mstar;
        out[3] = scal[0] + scal[1] - logf(se);
        out[4] = scal[2];
    }
}

extern "C" void kernel_launch(void* const* d_in, const int* in_sizes, int n_in,
                              void* d_out, int out_size, void* d_ws, size_t ws_size,
                              hipStream_t stream) {
    (void)in_sizes; (void)n_in; (void)out_size; (void)ws_size;
    const float* node_feat     = (const float*)d_in[0];
    const float* edge_feat     = (const float*)d_in[1];
    const int*   edge_index    = (const int*)d_in[2];
    const int*   paths         = (const int*)d_in[3];
    const int*   path_mask     = (const int*)d_in[4];
    const float* path_features = (const float*)d_in[5];
    const int*   mod_masks     = (const int*)d_in[6];
    const int*   spec_masks    = (const int*)d_in[7];
    const float* path_spectrum = (const float*)d_in[8];
    const float* W_np  = (const float*)d_in[9];
    const float* b_np  = (const float*)d_in[10];
    const float* W_ep  = (const float*)d_in[11];
    const float* b_ep  = (const float*)d_in[12];
    const float* W_msg = (const float*)d_in[13];
    const float* b_msg = (const float*)d_in[14];
    const float* W_ih  = (const float*)d_in[15];
    const float* b_ih  = (const float*)d_in[16];
    const float* W_hh  = (const float*)d_in[17];
    const float* b_hh  = (const float*)d_in[18];
    const float* W_path = (const float*)d_in[19];
    const float* b_path = (const float*)d_in[20];
    const float* W_mod  = (const float*)d_in[21];
    const float* b_mod  = (const float*)d_in[22];
    const float* c1w = (const float*)d_in[23];
    const float* c1b = (const float*)d_in[24];
    const float* c2w = (const float*)d_in[25];
    const float* c2b = (const float*)d_in[26];
    const float* W_val = (const float*)d_in[27];
    const float* b_val = (const float*)d_in[28];

    char* ws = (char*)d_ws;
    size_t off = 0;
    auto alloc = [&](size_t bytes)->char*{
        char* p = ws + off;
        off += (bytes + 255) & ~(size_t)255;
        return p;
    };
    int*    deg     = (int*)alloc((size_t)NN*4);
    int*    offs    = (int*)alloc((size_t)(NN+1)*4);
    int*    cursor  = (int*)alloc((size_t)NN*4);
    int*    bsum    = (int*)alloc((size_t)NB*4);
    int*    csr_src = (int*)alloc((size_t)NE*4);
    int*    csr_eid = (int*)alloc((size_t)NE*4);
    float*  ef_sum  = (float*)alloc((size_t)NN*FD*4);
    float*  nf_sum  = (float*)alloc((size_t)NN*FD*4);
    float*  Wf      = (float*)alloc((size_t)FD*HD*4);
    float*  bfv     = (float*)alloc((size_t)HD*4);
    ushort* W2T     = (ushort*)alloc((size_t)512*AK*2);
    ushort* A0      = (ushort*)alloc((size_t)NN*AK*2);
    ushort* A1      = (ushort*)alloc((size_t)NN*AK*2);
    ushort* G       = (ushort*)alloc((size_t)NN*512*2);
    float*  partial = (float*)alloc((size_t)NSB*HD*4);
    float*  gsum    = (float*)alloc((size_t)HD*4);

    hipMemsetAsync(deg, 0, (size_t)NN*4, stream);

    k_deg<<<(NE+255)/256, 256, 0, stream>>>(edge_index, deg);
    k_scan1<<<NB, 256, 0, stream>>>(deg, offs, bsum);
    k_scan2<<<1, 256, 0, stream>>>(bsum, offs);
    k_scan3<<<NB, 256, 0, stream>>>(bsum, offs, cursor);
    k_fill<<<(NE+255)/256, 256, 0, stream>>>(edge_index, cursor, csr_src, csr_eid);
    k_gat16<<<NN/4, 256, 0, stream>>>(csr_eid, csr_src, edge_feat, node_feat, offs, ef_sum, nf_sum);
    k_folds<<<9, 256, 0, stream>>>(W_ep, b_ep, W_msg, b_msg, Wf, bfv);
    k_wprep2<<<512, AK, 0, stream>>>(W_ih, W_hh, W_msg, Wf, bfv, b_ih, b_hh, W2T);
    k_prep<<<NN*64/256, 256, 0, stream>>>(node_feat, nf_sum, deg, W_np, b_np, ef_sum, A0, A1);

    const int MB = (NN+127)/128;   // 391
    // iter 1: A0 -> G -> A1.h
    k_gemmG<<<dim3(4,MB), 256, 0, stream>>>(A0, W2T, G);
    k_gruep<<<NN*64/256, 256, 0, stream>>>(G, A0, A1);
    // iter 2: gather(A1) -> G -> A0.h
    k_gather<<<NN/4, 256, 0, stream>>>(A1, offs, csr_src);
    k_gemmG<<<dim3(4,MB), 256, 0, stream>>>(A1, W2T, G);
    k_gruep<<<NN*64/256, 256, 0, stream>>>(G, A1, A0);
    // iter 3: gather(A0) -> G -> A1.h
    k_gather<<<NN/4, 256, 0, stream>>>(A0, offs, csr_src);
    k_gemmG<<<dim3(4,MB), 256, 0, stream>>>(A0, W2T, G);
    k_gruep<<<NN*64/256, 256, 0, stream>>>(G, A0, A1);

    k_sum1<<<NSB, 256, 0, stream>>>(A1, partial);
    k_sum2<<<HD, 256, 0, stream>>>(partial, gsum);
    k_small<<<1, 512, 0, stream>>>(edge_feat, paths, path_mask, path_features,
                                   mod_masks, spec_masks, path_spectrum,
                                   W_ep, b_ep, W_path, b_path, W_mod, b_mod,
                                   c1w, c1b, c2w, c2b, W_val, b_val,
                                   gsum, (float*)d_out);
}

// Round 8
// 406.781 us; speedup vs baseline: 1.2525x; 1.0165x over previous
//
#include <hip/hip_runtime.h>
#include <math.h>

#define NN 50000
#define NE 800000
#define HD 128
#define FD 16
#define NPATH 16
#define PL 8
#define NM 6
#define NS 320
#define NB 196   // ceil(NN/256)
#define NSB 782  // ceil(NN/64)
#define AK 320   // K for fused GEMM (hsum128 | h128 | ef16 | deg | 1 | pad)
#define AKU 160  // uints per A row
#define NEGV -1000000000.0f

typedef unsigned int uint;
typedef unsigned short ushort;
typedef short bf16x8 __attribute__((ext_vector_type(8)));
typedef float f32x4 __attribute__((ext_vector_type(4)));

__device__ __forceinline__ float sigm(float x){ return 1.0f/(1.0f+expf(-x)); }

__device__ __forceinline__ ushort f2b(float f){
    union{float f; uint u;} v; v.f=f;
    uint r = v.u + 0x7FFFu + ((v.u>>16)&1u);
    return (ushort)(r>>16);
}
__device__ __forceinline__ float b2f(ushort s){
    union{uint u; float f;} v; v.u = ((uint)s)<<16; return v.f;
}
__device__ __forceinline__ float blo(uint v){ return b2f((ushort)(v&0xFFFF)); }
__device__ __forceinline__ float bhi(uint v){ return b2f((ushort)(v>>16)); }
__device__ __forceinline__ uint pack2(float a, float b){ return (uint)f2b(a) | (((uint)f2b(b))<<16); }

// ---- degree histogram ----
__global__ void k_deg(const int* __restrict__ ei, int* __restrict__ deg){
    int e = blockIdx.x*256 + threadIdx.x;
    if (e >= NE) return;
    atomicAdd(&deg[ei[NE + e]], 1);
}

// ---- hierarchical exclusive scan ----
__global__ void k_scan1(const int* __restrict__ deg, int* __restrict__ offs, int* __restrict__ bsum){
    int tid = threadIdx.x, bid = blockIdx.x;
    int idx = bid*256 + tid;
    int v = (idx<NN) ? deg[idx] : 0;
    int lane = tid&63, w = tid>>6;
    int x = v;
    #pragma unroll
    for (int d=1; d<64; d<<=1){ int y = __shfl_up(x,d); if (lane>=d) x += y; }
    __shared__ int wsum[4];
    if (lane==63) wsum[w] = x;
    __syncthreads();
    int base = 0;
    #pragma unroll
    for (int j=0;j<4;j++) if (j<w) base += wsum[j];
    if (idx<NN) offs[idx] = base + x - v;
    if (tid==255) bsum[bid] = base + x;
}
__global__ void k_scan2(int* __restrict__ bsum, int* __restrict__ offs){
    int tid = threadIdx.x;
    int v = (tid<NB) ? bsum[tid] : 0;
    int lane = tid&63, w = tid>>6;
    int x = v;
    #pragma unroll
    for (int d=1; d<64; d<<=1){ int y = __shfl_up(x,d); if (lane>=d) x += y; }
    __shared__ int wsum[4];
    if (lane==63) wsum[w] = x;
    __syncthreads();
    int base = 0;
    #pragma unroll
    for (int j=0;j<4;j++) if (j<w) base += wsum[j];
    if (tid<NB) bsum[tid] = base + x - v;
    if (tid==255) offs[NN] = base + x;
}
__global__ void k_scan3(const int* __restrict__ bsum, int* __restrict__ offs, int* __restrict__ cursor){
    int idx = blockIdx.x*256 + threadIdx.x;
    if (idx>=NN) return;
    int o = offs[idx] + bsum[blockIdx.x];
    offs[idx]=o; cursor[idx]=o;
}

// ---- fill CSR: packed (src, eid) single 8B scattered write ----
__global__ void k_fill(const int* __restrict__ ei, int* __restrict__ cursor,
                       int2* __restrict__ csr2){
    int e = blockIdx.x*256 + threadIdx.x;
    if (e >= NE) return;
    int dst = ei[NE+e];
    int src = ei[e];
    int pos = atomicAdd(&cursor[dst], 1);
    csr2[pos] = make_int2(src, e);
}

// ---- per-node 16-wide sums of edge_feat (by eid) and node_feat (by src) ----
__global__ void k_gat16(const int2* __restrict__ csr2,
                        const float* __restrict__ edge_feat, const float* __restrict__ nf,
                        const int* __restrict__ offs,
                        float* __restrict__ ef_sum, float* __restrict__ nf_sum){
    int node = blockIdx.x*4 + (threadIdx.x>>6);
    int lane = threadIdx.x & 63;
    int k = lane & 15, sub = lane >> 4;
    int b = offs[node], e2 = offs[node+1];
    float ae = 0.f, an = 0.f;
    int i = b + sub;
    for (; i + 4 < e2; i += 8){
        int2 p0 = csr2[i], p1 = csr2[i+4];
        float f0 = edge_feat[(size_t)p0.y*FD + k];
        float g0 = nf[(size_t)p0.x*FD + k];
        float f1 = edge_feat[(size_t)p1.y*FD + k];
        float g1 = nf[(size_t)p1.x*FD + k];
        ae += f0 + f1; an += g0 + g1;
    }
    if (i < e2){
        int2 p0 = csr2[i];
        ae += edge_feat[(size_t)p0.y*FD + k];
        an += nf[(size_t)p0.x*FD + k];
    }
    ae += __shfl_xor(ae, 16); ae += __shfl_xor(ae, 32);
    an += __shfl_xor(an, 16); an += __shfl_xor(an, 32);
    if (sub == 0){ ef_sum[node*FD + k] = ae; nf_sum[node*FD + k] = an; }
}

// ---- Wf = W_ep@W_e ; bfv = b_ep@W_e + b_msg ----
__global__ void k_folds(const float* __restrict__ W_ep, const float* __restrict__ b_ep,
                        const float* __restrict__ W_msg, const float* __restrict__ b_msg,
                        float* __restrict__ Wf, float* __restrict__ bfv){
    int o = blockIdx.x*256 + threadIdx.x;
    if (o < FD*HD){
        int k=o>>7, c=o&127;
        float acc=0.f;
        for (int m=0;m<HD;m++) acc += W_ep[k*HD+m]*W_msg[(HD+m)*HD+c];
        Wf[o]=acc;
    } else if (o < FD*HD+HD){
        int c=o-FD*HD;
        float acc=b_msg[c];
        for (int m=0;m<HD;m++) acc += b_ep[m]*W_msg[(HD+m)*HD+c];
        bfv[c]=acc;
    }
}

// ---- build folded mega-weight W2T[512][320], gate-blocked: col = g*128 + j ----
// gates: 0=r, 1=z, 2=gi_n, 3=gh_n. Biases folded into k=273 (constant-1 column).
// Structured zeros: g<3 -> k in [128,256) only via W_hh (g2 zero there);
//                   g3  -> only k in [128,256) and k==273 nonzero.
__global__ void k_wprep2(const float* __restrict__ W_ih, const float* __restrict__ W_hh,
                         const float* __restrict__ W_msg, const float* __restrict__ Wf,
                         const float* __restrict__ bfv,
                         const float* __restrict__ b_ih, const float* __restrict__ b_hh,
                         ushort* __restrict__ W2T){
    int c = blockIdx.x;       // 0..511
    int k = threadIdx.x;      // 0..319
    int g = c>>7, j = c&127;
    float v = 0.f;
    if (k < 128){
        if (g < 3){   // hsum path: (W_h @ W_ih_g^T)
            const float* wm = W_msg + (size_t)k*HD;
            const float* wi = W_ih + (size_t)(g*HD+j)*HD;
            float acc=0.f;
            for (int m=0;m<HD;m++) acc += wm[m]*wi[m];
            v = acc;
        }
    } else if (k < 256){      // h path: W_hh gates (none for gi_n)
        int kk = k-128;
        if (g==0)      v = W_hh[(size_t)j*HD+kk];
        else if (g==1) v = W_hh[(size_t)(HD+j)*HD+kk];
        else if (g==3) v = W_hh[(size_t)(2*HD+j)*HD+kk];
    } else if (k < 272){      // ef_sum path
        if (g < 3){
            const float* wf = Wf + (size_t)(k-256)*HD;
            const float* wi = W_ih + (size_t)(g*HD+j)*HD;
            float acc=0.f;
            for (int m=0;m<HD;m++) acc += wf[m]*wi[m];
            v = acc;
        }
    } else if (k == 272){     // deg path
        if (g < 3){
            const float* wi = W_ih + (size_t)(g*HD+j)*HD;
            float acc=0.f;
            for (int m=0;m<HD;m++) acc += bfv[m]*wi[m];
            v = acc;
        }
    } else if (k == 273){     // constant-1: biases
        v = (g==0)? b_ih[j]+b_hh[j] : (g==1)? b_ih[HD+j]+b_hh[HD+j]
          : (g==2)? b_ih[2*HD+j] : b_hh[2*HD+j];
    }
    W2T[(size_t)c*AK + k] = f2b(v);
}

// ---- prep A0: h0 = nf@W_np+b_np ; hsum1 = nf_sum@W_np + deg*b_np ; statics -> A0 & A1 ----
__global__ void k_prep(const float* __restrict__ nf, const float* __restrict__ nf_sum,
                       const int* __restrict__ deg, const float* __restrict__ W_np,
                       const float* __restrict__ b_np, const float* __restrict__ ef_sum,
                       ushort* __restrict__ A0, ushort* __restrict__ A1){
    int idx = blockIdx.x*256 + threadIdx.x;  // NN*64
    int n = idx>>6, c2 = idx&63;
    int j = c2*2;
    const float* x = nf + (size_t)n*FD;
    const float* s = nf_sum + (size_t)n*FD;
    float d = (float)deg[n];
    float h0a = b_np[j], h0b = b_np[j+1];
    float hsa = d*b_np[j], hsb = d*b_np[j+1];
    #pragma unroll
    for (int k=0;k<FD;k++){
        float w0 = W_np[k*HD+j], w1 = W_np[k*HD+j+1];
        float xv = x[k], sv = s[k];
        h0a += xv*w0; h0b += xv*w1;
        hsa += sv*w0; hsb += sv*w1;
    }
    uint* a0 = (uint*)A0;
    a0[(size_t)n*AKU + 64 + c2] = pack2(h0a,h0b);
    a0[(size_t)n*AKU + c2]      = pack2(hsa,hsb);
    if (c2 < 32){
        int col = 256 + c2*2;
        float v0 = (col<272)? ef_sum[n*FD + (col-256)] : (col==272)? d : 0.f;
        float v1 = (col+1<272)? ef_sum[n*FD + (col+1-256)] : (col+1==273)? 1.f : 0.f;
        uint pv = pack2(v0,v1);
        a0[(size_t)n*AKU + 128 + c2] = pv;
        ((uint*)A1)[(size_t)n*AKU + 128 + c2] = pv;
    }
}

// ---- G[NN][512] = A[NN][320] @ W2T[512][320]^T, 128x128 tile, K=320 ----
// grid = dim3(4, MB). K-step skip per gate: g2 -> {0,1,4}, g3 -> {2,3,4} (structured zeros)
__global__ __launch_bounds__(256) void k_gemmG(const ushort* __restrict__ A,
                                               const ushort* __restrict__ Bt,
                                               ushort* __restrict__ G){
    __shared__ __align__(16) short As[128*64];
    __shared__ __align__(16) short Bs[128*64];
    const int tid = threadIdx.x;
    const int lane = tid & 63, w = tid>>6;
    const int wm = w>>1, wn = w&1;
    const int n0 = blockIdx.x*128, m0 = blockIdx.y*128;
    const int g = n0>>7;
    const int nsteps = (g>=2)? 3 : 5;
    f32x4 acc[4][4] = {};
    for (int si=0; si<nsteps; ++si){
        int kk = (g<2)? si : (g==2 ? ((si<2)? si : 4) : (si+2));   // g2:{0,1,4} g3:{2,3,4}
        __syncthreads();
        #pragma unroll
        for (int i=0;i<4;i++){
            int id = tid + i*256;
            int row = id>>3, s = id&7;
            int phys = row*64 + ((s ^ (row&7))<<3);
            int ar = m0 + row; if (ar >= NN) ar = NN-1;
            *(int4*)&As[phys] = *(const int4*)(A + (size_t)ar*AK + kk*64 + s*8);
            *(int4*)&Bs[phys] = *(const int4*)(Bt + (size_t)(n0+row)*AK + kk*64 + s*8);
        }
        __syncthreads();
        #pragma unroll
        for (int ksel=0; ksel<2; ++ksel){
            bf16x8 af[4], bfr[4];
            #pragma unroll
            for (int t=0;t<4;t++){
                int arow = wm*64 + t*16 + (lane&15);
                int aslot = (ksel*4 + (lane>>4)) ^ (arow&7);
                af[t] = *(const bf16x8*)&As[arow*64 + aslot*8];
                int brow = wn*64 + t*16 + (lane&15);
                int bslot = (ksel*4 + (lane>>4)) ^ (brow&7);
                bfr[t] = *(const bf16x8*)&Bs[brow*64 + bslot*8];
            }
            #pragma unroll
            for (int mi=0;mi<4;mi++)
                #pragma unroll
                for (int ni=0;ni<4;ni++)
                    acc[mi][ni] = __builtin_amdgcn_mfma_f32_16x16x32_bf16(af[mi], bfr[ni], acc[mi][ni], 0,0,0);
        }
    }
    #pragma unroll
    for (int mi=0;mi<4;mi++){
        #pragma unroll
        for (int r=0;r<4;r++){
            int row = m0 + wm*64 + mi*16 + (lane>>4)*4 + r;
            if (row >= NN) continue;
            #pragma unroll
            for (int ni=0;ni<4;ni++){
                int col = n0 + wn*64 + ni*16 + (lane&15);
                G[(size_t)row*512 + col] = f2b(acc[mi][ni][r]);
            }
        }
    }
}

// ---- GRU epilogue: G=[r|z|in|hn] (biases pre-folded) + A.h -> Anxt.h ----
__global__ void k_gruep(const ushort* __restrict__ G, const ushort* __restrict__ A,
                        ushort* __restrict__ Anxt){
    int idx = blockIdx.x*256 + threadIdx.x;   // NN*64
    int n = idx>>6, c2 = idx&63;
    const uint* g = (const uint*)G + (size_t)n*256;
    uint vr = g[c2], vz = g[64+c2], vin = g[128+c2], vhn = g[192+c2];
    uint vh = ((const uint*)A)[(size_t)n*AKU + 64 + c2];
    float r0 = sigm(blo(vr)), r1 = sigm(bhi(vr));
    float z0 = sigm(blo(vz)), z1 = sigm(bhi(vz));
    float n0 = tanhf(blo(vin) + r0*blo(vhn));
    float n1 = tanhf(bhi(vin) + r1*bhi(vhn));
    float h0 = (1.f-z0)*n0 + z0*blo(vh);
    float h1 = (1.f-z1)*n1 + z1*bhi(vh);
    ((uint*)Anxt)[(size_t)n*AKU + 64 + c2] = pack2(h0,h1);
}

// ---- hsum[n] = sum over in-edges of h[src] (within same A buffer) ----
__global__ void k_gather(ushort* __restrict__ A, const int* __restrict__ offs,
                         const int2* __restrict__ csr2){
    int node = blockIdx.x*4 + (threadIdx.x>>6);
    int c2 = threadIdx.x & 63;
    int b = offs[node], e2 = offs[node+1];
    float a0 = 0.f, a1 = 0.f;
    const uint* hp = (const uint*)A;
    int i = b;
    for (; i + 8 <= e2; i += 8){
        int s0=csr2[i].x,  s1=csr2[i+1].x, s2=csr2[i+2].x, s3=csr2[i+3].x;
        int s4=csr2[i+4].x,s5=csr2[i+5].x, s6=csr2[i+6].x, s7=csr2[i+7].x;
        uint v0=hp[(size_t)s0*AKU+64+c2], v1=hp[(size_t)s1*AKU+64+c2],
             v2=hp[(size_t)s2*AKU+64+c2], v3=hp[(size_t)s3*AKU+64+c2],
             v4=hp[(size_t)s4*AKU+64+c2], v5=hp[(size_t)s5*AKU+64+c2],
             v6=hp[(size_t)s6*AKU+64+c2], v7=hp[(size_t)s7*AKU+64+c2];
        a0 += blo(v0)+blo(v1)+blo(v2)+blo(v3)+blo(v4)+blo(v5)+blo(v6)+blo(v7);
        a1 += bhi(v0)+bhi(v1)+bhi(v2)+bhi(v3)+bhi(v4)+bhi(v5)+bhi(v6)+bhi(v7);
    }
    if (i + 4 <= e2){
        int s0=csr2[i].x,s1=csr2[i+1].x,s2=csr2[i+2].x,s3=csr2[i+3].x;
        uint v0=hp[(size_t)s0*AKU+64+c2], v1=hp[(size_t)s1*AKU+64+c2],
             v2=hp[(size_t)s2*AKU+64+c2], v3=hp[(size_t)s3*AKU+64+c2];
        a0 += blo(v0)+blo(v1)+blo(v2)+blo(v3);
        a1 += bhi(v0)+bhi(v1)+bhi(v2)+bhi(v3);
        i += 4;
    }
    for (; i < e2; ++i){
        uint v = hp[(size_t)csr2[i].x*AKU+64+c2];
        a0 += blo(v); a1 += bhi(v);
    }
    ((uint*)A)[(size_t)node*AKU + c2] = pack2(a0,a1);
}

// ---- two-stage column sum of final h (no atomics, fully parallel stage 2) ----
__global__ void k_sum1(const ushort* __restrict__ A, float* __restrict__ partial){
    int bid = blockIdx.x, tid = threadIdx.x;
    int lane = tid&63, w2 = tid>>6;
    int nb = bid*64;
    float a0=0.f, a1=0.f;
    const uint* hp = (const uint*)A;
    #pragma unroll
    for (int r=w2; r<64; r+=4){
        int n = nb + r;
        if (n < NN){
            uint v = hp[(size_t)n*AKU + 64 + lane];
            a0 += blo(v); a1 += bhi(v);
        }
    }
    __shared__ float s0[4][64], s1[4][64];
    s0[w2][lane]=a0; s1[w2][lane]=a1;
    __syncthreads();
    if (w2==0){
        a0 = s0[0][lane]+s0[1][lane]+s0[2][lane]+s0[3][lane];
        a1 = s1[0][lane]+s1[1][lane]+s1[2][lane]+s1[3][lane];
        ((float2*)partial)[(size_t)bid*64 + lane] = make_float2(a0,a1);
    }
}
// one block per column; threads cover rows in parallel (<=4 loads each)
__global__ void k_sum2(const float* __restrict__ partial, float* __restrict__ gsum){
    int c = blockIdx.x;          // 0..127
    int tid = threadIdx.x;       // 256
    int lane = tid&63, w = tid>>6;
    float a = 0.f;
    for (int b=tid; b<NSB; b+=256) a += partial[(size_t)b*128 + c];
    #pragma unroll
    for (int d=1; d<64; d<<=1) a += __shfl_xor(a, d);
    __shared__ float sh[4];
    if (lane==0) sh[w]=a;
    __syncthreads();
    if (tid==0) gsum[c] = sh[0]+sh[1]+sh[2]+sh[3];
}

// ---- tiny agents + value head, wave-parallel ----
__global__ void k_small(const float* __restrict__ ef, const int* __restrict__ paths,
                        const int* __restrict__ pmask, const float* __restrict__ pfeat,
                        const int* __restrict__ mmask, const int* __restrict__ smask,
                        const float* __restrict__ pspec,
                        const float* __restrict__ W_ep, const float* __restrict__ b_ep,
                        const float* __restrict__ W_path, const float* __restrict__ b_path,
                        const float* __restrict__ W_mod, const float* __restrict__ b_mod,
                        const float* __restrict__ c1w, const float* __restrict__ c1b,
                        const float* __restrict__ c2w, const float* __restrict__ c2b,
                        const float* __restrict__ W_val, const float* __restrict__ b_val,
                        const float* __restrict__ gsum, float* __restrict__ out){
    __shared__ float z[NPATH][HD];
    __shared__ float lf[NS];
    __shared__ float spec[NS];
    __shared__ float red[8];
    __shared__ float scal[3];
    __shared__ int   sel[3];
    __shared__ float maxsh;
    int tid = threadIdx.x, lane = tid&63, w = tid>>6;

    { // z[p][c] for 16 paths
        int pr = tid>>7, c = tid&127;
        #pragma unroll
        for (int pb=0; pb<4; pb++){
            int p = pb*4 + pr;
            float acc = 0.f;
            for (int l=0;l<PL;l++){
                int eid = paths[p*PL + l];
                const float* f = ef + (size_t)eid*FD;
                #pragma unroll
                for (int k=0;k<FD;k++) acc += f[k]*W_ep[k*HD + c];
            }
            z[p][c] = acc*0.125f + b_ep[c];
        }
    }
    __syncthreads();
    { // logits_p
        int p = tid>>5, sub = tid&31;
        float part = 0.f;
        #pragma unroll
        for (int c=sub;c<HD;c+=32) part += z[p][c]*W_path[c];
        #pragma unroll
        for (int d=16; d>=1; d>>=1) part += __shfl_xor(part, d);
        if (sub==0) lf[p] = (pmask[p]==0)? NEGV : part + b_path[0];
    }
    __syncthreads();
    if (w==0){
        float v = (lane<NPATH)? lf[lane] : -3.0e38f;
        float m = v;
        #pragma unroll
        for (int d=1; d<64; d<<=1) m = fmaxf(m, __shfl_xor(m, d));
        float e = (lane<NPATH)? expf(v-m) : 0.f;
        #pragma unroll
        for (int d=1; d<64; d<<=1) e += __shfl_xor(e, d);
        int idx = (lane<NPATH && v==m)? lane : (1<<30);
        #pragma unroll
        for (int d=1; d<64; d<<=1) idx = min(idx, __shfl_xor(idx, d));
        if (lane==0){ sel[0]=idx; scal[0] = -logf(e); }
    }
    __syncthreads();
    int pstar = sel[0];
    if (w < NM){
        float part = 0.f;
        #pragma unroll
        for (int c=lane;c<HD;c+=64) part += z[pstar][c]*W_mod[c*NM + w];
        if (lane<3) part += pfeat[pstar*3+lane]*W_mod[(HD+lane)*NM + w];
        #pragma unroll
        for (int d=1; d<64; d<<=1) part += __shfl_xor(part, d);
        if (lane==0) red[w] = (mmask[pstar*NM + w]==0)? NEGV : part + b_mod[w];
    } else if (w == 7){
        float part = gsum[lane]*W_val[lane] + gsum[lane+64]*W_val[lane+64];
        #pragma unroll
        for (int d=1; d<64; d<<=1) part += __shfl_xor(part, d);
        if (lane==0) scal[2] = part/(float)NN + b_val[0];
    }
    __syncthreads();
    if (w==0){
        float v = (lane<NM)? red[lane] : -3.0e38f;
        float m = v;
        #pragma unroll
        for (int d=1; d<64; d<<=1) m = fmaxf(m, __shfl_xor(m, d));
        float e = (lane<NM)? expf(v-m) : 0.f;
        #pragma unroll
        for (int d=1; d<64; d<<=1) e += __shfl_xor(e, d);
        int idx = (lane<NM && v==m)? lane : (1<<30);
        #pragma unroll
        for (int d=1; d<64; d<<=1) idx = min(idx, __shfl_xor(idx, d));
        if (lane==0){ sel[1]=idx; scal[1] = -logf(e); }
    }
    __syncthreads();
    int mstar = sel[1];
    if (tid < NS) spec[tid] = pspec[pstar*NS + tid];
    __syncthreads();
    float v = -3.0e38f;
    if (tid < NS){
        float acc = c2b[0];
        #pragma unroll
        for (int ch=0; ch<8; ch++){
            float a = c1b[ch];
            #pragma unroll
            for (int k=0;k<5;k++){
                int ss = tid + k - 2;
                if (ss>=0 && ss<NS) a += spec[ss]*c1w[ch*5+k];
            }
            a = fmaxf(a, 0.f);
            acc += a*c2w[ch];
        }
        v = (smask[pstar*NM*NS + mstar*NS + tid]==0) ? NEGV : acc;
    }
    float m = v;
    #pragma unroll
    for (int d=1; d<64; d<<=1) m = fmaxf(m, __shfl_xor(m, d));
    if (lane==0) red[w] = m;
    __syncthreads();
    if (tid==0){
        float mm = red[0];
        #pragma unroll
        for (int i=1;i<8;i++) mm = fmaxf(mm, red[i]);
        maxsh = mm; sel[2] = 1<<30;
    }
    __syncthreads();
    float M2 = maxsh;
    if (tid<NS && v==M2) atomicMin(&sel[2], tid);
    float e = (tid<NS)? expf(v-M2) : 0.f;
    #pragma unroll
    for (int d=1; d<64; d<<=1) e += __shfl_xor(e, d);
    if (lane==0) red[w] = e;
    __syncthreads();
    if (tid==0){
        float se = 0.f;
        #pragma unroll
        for (int i=0;i<8;i++) se += red[i];
        out[0] = (float)pstar;
        out[1] = (float)sel[2];
        out[2] = (float)mstar;
        out[3] = scal[0] + scal[1] - logf(se);
        out[4] = scal[2];
    }
}

extern "C" void kernel_launch(void* const* d_in, const int* in_sizes, int n_in,
                              void* d_out, int out_size, void* d_ws, size_t ws_size,
                              hipStream_t stream) {
    (void)in_sizes; (void)n_in; (void)out_size; (void)ws_size;
    const float* node_feat     = (const float*)d_in[0];
    const float* edge_feat     = (const float*)d_in[1];
    const int*   edge_index    = (const int*)d_in[2];
    const int*   paths         = (const int*)d_in[3];
    const int*   path_mask     = (const int*)d_in[4];
    const float* path_features = (const float*)d_in[5];
    const int*   mod_masks     = (const int*)d_in[6];
    const int*   spec_masks    = (const int*)d_in[7];
    const float* path_spectrum = (const float*)d_in[8];
    const float* W_np  = (const float*)d_in[9];
    const float* b_np  = (const float*)d_in[10];
    const float* W_ep  = (const float*)d_in[11];
    const float* b_ep  = (const float*)d_in[12];
    const float* W_msg = (const float*)d_in[13];
    const float* b_msg = (const float*)d_in[14];
    const float* W_ih  = (const float*)d_in[15];
    const float* b_ih  = (const float*)d_in[16];
    const float* W_hh  = (const float*)d_in[17];
    const float* b_hh  = (const float*)d_in[18];
    const float* W_path = (const float*)d_in[19];
    const float* b_path = (const float*)d_in[20];
    const float* W_mod  = (const float*)d_in[21];
    const float* b_mod  = (const float*)d_in[22];
    const float* c1w = (const float*)d_in[23];
    const float* c1b = (const float*)d_in[24];
    const float* c2w = (const float*)d_in[25];
    const float* c2b = (const float*)d_in[26];
    const float* W_val = (const float*)d_in[27];
    const float* b_val = (const float*)d_in[28];

    char* ws = (char*)d_ws;
    size_t off = 0;
    auto alloc = [&](size_t bytes)->char*{
        char* p = ws + off;
        off += (bytes + 255) & ~(size_t)255;
        return p;
    };
    int*    deg     = (int*)alloc((size_t)NN*4);
    int*    offs    = (int*)alloc((size_t)(NN+1)*4);
    int*    cursor  = (int*)alloc((size_t)NN*4);
    int*    bsum    = (int*)alloc((size_t)NB*4);
    int2*   csr2    = (int2*)alloc((size_t)NE*8);
    float*  ef_sum  = (float*)alloc((size_t)NN*FD*4);
    float*  nf_sum  = (float*)alloc((size_t)NN*FD*4);
    float*  Wf      = (float*)alloc((size_t)FD*HD*4);
    float*  bfv     = (float*)alloc((size_t)HD*4);
    ushort* W2T     = (ushort*)alloc((size_t)512*AK*2);
    ushort* A0      = (ushort*)alloc((size_t)NN*AK*2);
    ushort* A1      = (ushort*)alloc((size_t)NN*AK*2);
    ushort* G       = (ushort*)alloc((size_t)NN*512*2);
    float*  partial = (float*)alloc((size_t)NSB*HD*4);
    float*  gsum    = (float*)alloc((size_t)HD*4);

    hipMemsetAsync(deg, 0, (size_t)NN*4, stream);

    k_deg<<<(NE+255)/256, 256, 0, stream>>>(edge_index, deg);
    k_scan1<<<NB, 256, 0, stream>>>(deg, offs, bsum);
    k_scan2<<<1, 256, 0, stream>>>(bsum, offs);
    k_scan3<<<NB, 256, 0, stream>>>(bsum, offs, cursor);
    k_fill<<<(NE+255)/256, 256, 0, stream>>>(edge_index, cursor, csr2);
    k_gat16<<<NN/4, 256, 0, stream>>>(csr2, edge_feat, node_feat, offs, ef_sum, nf_sum);
    k_folds<<<9, 256, 0, stream>>>(W_ep, b_ep, W_msg, b_msg, Wf, bfv);
    k_wprep2<<<512, AK, 0, stream>>>(W_ih, W_hh, W_msg, Wf, bfv, b_ih, b_hh, W2T);
    k_prep<<<NN*64/256, 256, 0, stream>>>(node_feat, nf_sum, deg, W_np, b_np, ef_sum, A0, A1);

    const int MB = (NN+127)/128;   // 391
    // iter 1: A0 -> G -> A1.h
    k_gemmG<<<dim3(4,MB), 256, 0, stream>>>(A0, W2T, G);
    k_gruep<<<NN*64/256, 256, 0, stream>>>(G, A0, A1);
    // iter 2: gather(A1) -> G -> A0.h
    k_gather<<<NN/4, 256, 0, stream>>>(A1, offs, csr2);
    k_gemmG<<<dim3(4,MB), 256, 0, stream>>>(A1, W2T, G);
    k_gruep<<<NN*64/256, 256, 0, stream>>>(G, A1, A0);
    // iter 3: gather(A0) -> G -> A1.h
    k_gather<<<NN/4, 256, 0, stream>>>(A0, offs, csr2);
    k_gemmG<<<dim3(4,MB), 256, 0, stream>>>(A0, W2T, G);
    k_gruep<<<NN*64/256, 256, 0, stream>>>(G, A0, A1);

    k_sum1<<<NSB, 256, 0, stream>>>(A1, partial);
    k_sum2<<<HD, 256, 0, stream>>>(partial, gsum);
    k_small<<<1, 512, 0, stream>>>(edge_feat, paths, path_mask, path_features,
                                   mod_masks, spec_masks, path_spectrum,
                                   W_ep, b_ep, W_path, b_path, W_mod, b_mod,
                                   c1w, c1b, c2w, c2b, W_val, b_val,
                                   gsum, (float*)d_out);
}

// Round 9
// 384.046 us; speedup vs baseline: 1.3267x; 1.0592x over previous
//
#include <hip/hip_runtime.h>
#include <math.h>

#define NN 50000
#define NE 800000
#define HD 128
#define FD 16
#define NPATH 16
#define PL 8
#define NM 6
#define NS 320
#define NB 196    // ceil(NN/256)
#define NSB 782   // ceil(NN/64)
#define AK 320    // K for fused GEMM (hsum128 | h128 | ef16 | deg | 1 | pad)
#define AKU 160   // uints per A row
#define EPB 2048  // edges per histogram/scatter block
#define NBLK 391  // ceil(NE/EPB)
#define NBKT 196  // buckets = dst>>8
#define NEGV -1000000000.0f

typedef unsigned int uint;
typedef unsigned short ushort;
typedef short bf16x8 __attribute__((ext_vector_type(8)));
typedef float f32x4 __attribute__((ext_vector_type(4)));

__device__ __forceinline__ float sigm(float x){ return 1.0f/(1.0f+expf(-x)); }

__device__ __forceinline__ ushort f2b(float f){
    union{float f; uint u;} v; v.f=f;
    uint r = v.u + 0x7FFFu + ((v.u>>16)&1u);
    return (ushort)(r>>16);
}
__device__ __forceinline__ float b2f(ushort s){
    union{uint u; float f;} v; v.u = ((uint)s)<<16; return v.f;
}
__device__ __forceinline__ float blo(uint v){ return b2f((ushort)(v&0xFFFF)); }
__device__ __forceinline__ float bhi(uint v){ return b2f((ushort)(v>>16)); }
__device__ __forceinline__ uint pack2(float a, float b){ return (uint)f2b(a) | (((uint)f2b(b))<<16); }

// ---- degree histogram ----
__global__ void k_deg(const int* __restrict__ ei, int* __restrict__ deg){
    int e = blockIdx.x*256 + threadIdx.x;
    if (e >= NE) return;
    atomicAdd(&deg[ei[NE + e]], 1);
}

// ---- hierarchical exclusive scan over deg -> offs ----
__global__ void k_scan1(const int* __restrict__ deg, int* __restrict__ offs, int* __restrict__ bsum){
    int tid = threadIdx.x, bid = blockIdx.x;
    int idx = bid*256 + tid;
    int v = (idx<NN) ? deg[idx] : 0;
    int lane = tid&63, w = tid>>6;
    int x = v;
    #pragma unroll
    for (int d=1; d<64; d<<=1){ int y = __shfl_up(x,d); if (lane>=d) x += y; }
    __shared__ int wsum[4];
    if (lane==63) wsum[w] = x;
    __syncthreads();
    int base = 0;
    #pragma unroll
    for (int j=0;j<4;j++) if (j<w) base += wsum[j];
    if (idx<NN) offs[idx] = base + x - v;
    if (tid==255) bsum[bid] = base + x;
}
__global__ void k_scan2(int* __restrict__ bsum, int* __restrict__ offs){
    int tid = threadIdx.x;
    int v = (tid<NB) ? bsum[tid] : 0;
    int lane = tid&63, w = tid>>6;
    int x = v;
    #pragma unroll
    for (int d=1; d<64; d<<=1){ int y = __shfl_up(x,d); if (lane>=d) x += y; }
    __shared__ int wsum[4];
    if (lane==63) wsum[w] = x;
    __syncthreads();
    int base = 0;
    #pragma unroll
    for (int j=0;j<4;j++) if (j<w) base += wsum[j];
    if (tid<NB) bsum[tid] = base + x - v;
    if (tid==255) offs[NN] = base + x;
}
__global__ void k_scan3(const int* __restrict__ bsum, int* __restrict__ offs){
    int idx = blockIdx.x*256 + threadIdx.x;
    if (idx>=NN) return;
    offs[idx] += bsum[blockIdx.x];
}

// ---- counting sort phase 1: per-block bucket histogram ----
__global__ void k_hist(const int* __restrict__ ei, int* __restrict__ C){
    __shared__ int h[NBKT];
    int tid = threadIdx.x, blk = blockIdx.x;
    if (tid < NBKT) h[tid] = 0;
    __syncthreads();
    int e0 = blk*EPB;
    for (int i=tid; i<EPB; i+=256){
        int e = e0+i;
        if (e < NE) atomicAdd(&h[ei[NE+e]>>8], 1);
    }
    __syncthreads();
    if (tid < NBKT) C[blk*NBKT + tid] = h[tid];
}

// ---- phase 2: column-wise exclusive scan of C + bucket base from offs ----
__global__ void k_cscan(int* __restrict__ C, const int* __restrict__ offs){
    int b = blockIdx.x*4 + (threadIdx.x>>6);
    int lane = threadIdx.x & 63;
    if (b >= NBKT) return;
    int base = offs[b<<8];
    int carry = 0;
    for (int c=0; c<7; ++c){
        int i = c*64 + lane;
        int v = (i<NBLK)? C[i*NBKT + b] : 0;
        int x = v;
        #pragma unroll
        for (int d=1; d<64; d<<=1){ int y = __shfl_up(x,d); if (lane>=d) x += y; }
        if (i<NBLK) C[i*NBKT + b] = base + carry + (x - v);
        carry += __shfl(x, 63);
    }
}

// ---- phase 3: scatter edges into bucket-ordered array (sequential streams) ----
__global__ void k_scatA(const int* __restrict__ ei, const int* __restrict__ C,
                        int2* __restrict__ bkt2){
    __shared__ int cur[NBKT];
    __shared__ int cbase[NBKT];
    int tid = threadIdx.x, blk = blockIdx.x;
    if (tid < NBKT){ cur[tid] = 0; cbase[tid] = C[blk*NBKT + tid]; }
    __syncthreads();
    int e0 = blk*EPB;
    for (int i=tid; i<EPB; i+=256){
        int e = e0+i;
        if (e >= NE) break;
        int dst = ei[NE+e];
        int bkt = dst>>8;
        int r = atomicAdd(&cur[bkt], 1);
        bkt2[cbase[bkt] + r] = make_int2(dst, e);
    }
}

// ---- phase 4: per-bucket exact per-dst placement (single-CU 32KB window) ----
__global__ void k_scatB(const int* __restrict__ ei, const int2* __restrict__ bkt2,
                        const int* __restrict__ offs, int2* __restrict__ csr2){
    __shared__ int cur[256];
    int b = blockIdx.x, tid = threadIdx.x;
    int d0 = b<<8;
    {
        int idx = d0 + tid;
        cur[tid] = (idx<NN)? offs[idx] : 0;
    }
    __syncthreads();
    int lo = offs[d0];
    int hi = (d0+256 <= NN)? offs[d0+256] : offs[NN];
    for (int i=lo+tid; i<hi; i+=256){
        int2 p = bkt2[i];
        int pos = atomicAdd(&cur[p.x & 255], 1);
        csr2[pos] = make_int2(ei[p.y], p.y);
    }
}

// ---- per-node 16-wide sums of edge_feat (by eid) and node_feat (by src) ----
__global__ void k_gat16(const int2* __restrict__ csr2,
                        const float* __restrict__ edge_feat, const float* __restrict__ nf,
                        const int* __restrict__ offs,
                        float* __restrict__ ef_sum, float* __restrict__ nf_sum){
    int node = blockIdx.x*4 + (threadIdx.x>>6);
    int lane = threadIdx.x & 63;
    int k = lane & 15, sub = lane >> 4;
    int b = offs[node], e2 = offs[node+1];
    float ae = 0.f, an = 0.f;
    int i = b + sub;
    for (; i + 4 < e2; i += 8){
        int2 p0 = csr2[i], p1 = csr2[i+4];
        float f0 = edge_feat[(size_t)p0.y*FD + k];
        float g0 = nf[(size_t)p0.x*FD + k];
        float f1 = edge_feat[(size_t)p1.y*FD + k];
        float g1 = nf[(size_t)p1.x*FD + k];
        ae += f0 + f1; an += g0 + g1;
    }
    if (i < e2){
        int2 p0 = csr2[i];
        ae += edge_feat[(size_t)p0.y*FD + k];
        an += nf[(size_t)p0.x*FD + k];
    }
    ae += __shfl_xor(ae, 16); ae += __shfl_xor(ae, 32);
    an += __shfl_xor(an, 16); an += __shfl_xor(an, 32);
    if (sub == 0){ ef_sum[node*FD + k] = ae; nf_sum[node*FD + k] = an; }
}

// ---- Wf = W_ep@W_e ; bfv = b_ep@W_e + b_msg ----
__global__ void k_folds(const float* __restrict__ W_ep, const float* __restrict__ b_ep,
                        const float* __restrict__ W_msg, const float* __restrict__ b_msg,
                        float* __restrict__ Wf, float* __restrict__ bfv){
    int o = blockIdx.x*256 + threadIdx.x;
    if (o < FD*HD){
        int k=o>>7, c=o&127;
        float acc=0.f;
        for (int m=0;m<HD;m++) acc += W_ep[k*HD+m]*W_msg[(HD+m)*HD+c];
        Wf[o]=acc;
    } else if (o < FD*HD+HD){
        int c=o-FD*HD;
        float acc=b_msg[c];
        for (int m=0;m<HD;m++) acc += b_ep[m]*W_msg[(HD+m)*HD+c];
        bfv[c]=acc;
    }
}

// ---- build folded mega-weight W2T[512][320], gate-blocked: col = g*128 + j ----
__global__ void k_wprep2(const float* __restrict__ W_ih, const float* __restrict__ W_hh,
                         const float* __restrict__ W_msg, const float* __restrict__ Wf,
                         const float* __restrict__ bfv,
                         const float* __restrict__ b_ih, const float* __restrict__ b_hh,
                         ushort* __restrict__ W2T){
    int c = blockIdx.x;       // 0..511
    int k = threadIdx.x;      // 0..319
    int g = c>>7, j = c&127;
    float v = 0.f;
    if (k < 128){
        if (g < 3){   // hsum path: (W_h @ W_ih_g^T)
            const float* wm = W_msg + (size_t)k*HD;
            const float* wi = W_ih + (size_t)(g*HD+j)*HD;
            float acc=0.f;
            for (int m=0;m<HD;m++) acc += wm[m]*wi[m];
            v = acc;
        }
    } else if (k < 256){      // h path: W_hh gates (none for gi_n)
        int kk = k-128;
        if (g==0)      v = W_hh[(size_t)j*HD+kk];
        else if (g==1) v = W_hh[(size_t)(HD+j)*HD+kk];
        else if (g==3) v = W_hh[(size_t)(2*HD+j)*HD+kk];
    } else if (k < 272){      // ef_sum path
        if (g < 3){
            const float* wf = Wf + (size_t)(k-256)*HD;
            const float* wi = W_ih + (size_t)(g*HD+j)*HD;
            float acc=0.f;
            for (int m=0;m<HD;m++) acc += wf[m]*wi[m];
            v = acc;
        }
    } else if (k == 272){     // deg path
        if (g < 3){
            const float* wi = W_ih + (size_t)(g*HD+j)*HD;
            float acc=0.f;
            for (int m=0;m<HD;m++) acc += bfv[m]*wi[m];
            v = acc;
        }
    } else if (k == 273){     // constant-1: biases
        v = (g==0)? b_ih[j]+b_hh[j] : (g==1)? b_ih[HD+j]+b_hh[HD+j]
          : (g==2)? b_ih[2*HD+j] : b_hh[2*HD+j];
    }
    W2T[(size_t)c*AK + k] = f2b(v);
}

// ---- prep A0: h0 = nf@W_np+b_np ; hsum1 = nf_sum@W_np + deg*b_np ; statics -> A0 & A1 ----
__global__ void k_prep(const float* __restrict__ nf, const float* __restrict__ nf_sum,
                       const int* __restrict__ deg, const float* __restrict__ W_np,
                       const float* __restrict__ b_np, const float* __restrict__ ef_sum,
                       ushort* __restrict__ A0, ushort* __restrict__ A1){
    int idx = blockIdx.x*256 + threadIdx.x;  // NN*64
    int n = idx>>6, c2 = idx&63;
    int j = c2*2;
    const float* x = nf + (size_t)n*FD;
    const float* s = nf_sum + (size_t)n*FD;
    float d = (float)deg[n];
    float h0a = b_np[j], h0b = b_np[j+1];
    float hsa = d*b_np[j], hsb = d*b_np[j+1];
    #pragma unroll
    for (int k=0;k<FD;k++){
        float w0 = W_np[k*HD+j], w1 = W_np[k*HD+j+1];
        float xv = x[k], sv = s[k];
        h0a += xv*w0; h0b += xv*w1;
        hsa += sv*w0; hsb += sv*w1;
    }
    uint* a0 = (uint*)A0;
    a0[(size_t)n*AKU + 64 + c2] = pack2(h0a,h0b);
    a0[(size_t)n*AKU + c2]      = pack2(hsa,hsb);
    if (c2 < 32){
        int col = 256 + c2*2;
        float v0 = (col<272)? ef_sum[n*FD + (col-256)] : (col==272)? d : 0.f;
        float v1 = (col+1<272)? ef_sum[n*FD + (col+1-256)] : (col+1==273)? 1.f : 0.f;
        uint pv = pack2(v0,v1);
        a0[(size_t)n*AKU + 128 + c2] = pv;
        ((uint*)A1)[(size_t)n*AKU + 128 + c2] = pv;
    }
}

// ---- G[NN][512] = A[NN][320] @ W2T[512][320]^T, 128x128 tile, K=320 ----
// grid = dim3(4, MB). K-step skip per gate: g2 -> {0,1,4}, g3 -> {2,3,4} (structured zeros)
__global__ __launch_bounds__(256) void k_gemmG(const ushort* __restrict__ A,
                                               const ushort* __restrict__ Bt,
                                               ushort* __restrict__ G){
    __shared__ __align__(16) short As[128*64];
    __shared__ __align__(16) short Bs[128*64];
    const int tid = threadIdx.x;
    const int lane = tid & 63, w = tid>>6;
    const int wm = w>>1, wn = w&1;
    const int n0 = blockIdx.x*128, m0 = blockIdx.y*128;
    const int g = n0>>7;
    const int nsteps = (g>=2)? 3 : 5;
    f32x4 acc[4][4] = {};
    for (int si=0; si<nsteps; ++si){
        int kk = (g<2)? si : (g==2 ? ((si<2)? si : 4) : (si+2));   // g2:{0,1,4} g3:{2,3,4}
        __syncthreads();
        #pragma unroll
        for (int i=0;i<4;i++){
            int id = tid + i*256;
            int row = id>>3, s = id&7;
            int phys = row*64 + ((s ^ (row&7))<<3);
            int ar = m0 + row; if (ar >= NN) ar = NN-1;
            *(int4*)&As[phys] = *(const int4*)(A + (size_t)ar*AK + kk*64 + s*8);
            *(int4*)&Bs[phys] = *(const int4*)(Bt + (size_t)(n0+row)*AK + kk*64 + s*8);
        }
        __syncthreads();
        #pragma unroll
        for (int ksel=0; ksel<2; ++ksel){
            bf16x8 af[4], bfr[4];
            #pragma unroll
            for (int t=0;t<4;t++){
                int arow = wm*64 + t*16 + (lane&15);
                int aslot = (ksel*4 + (lane>>4)) ^ (arow&7);
                af[t] = *(const bf16x8*)&As[arow*64 + aslot*8];
                int brow = wn*64 + t*16 + (lane&15);
                int bslot = (ksel*4 + (lane>>4)) ^ (brow&7);
                bfr[t] = *(const bf16x8*)&Bs[brow*64 + bslot*8];
            }
            #pragma unroll
            for (int mi=0;mi<4;mi++)
                #pragma unroll
                for (int ni=0;ni<4;ni++)
                    acc[mi][ni] = __builtin_amdgcn_mfma_f32_16x16x32_bf16(af[mi], bfr[ni], acc[mi][ni], 0,0,0);
        }
    }
    #pragma unroll
    for (int mi=0;mi<4;mi++){
        #pragma unroll
        for (int r=0;r<4;r++){
            int row = m0 + wm*64 + mi*16 + (lane>>4)*4 + r;
            if (row >= NN) continue;
            #pragma unroll
            for (int ni=0;ni<4;ni++){
                int col = n0 + wn*64 + ni*16 + (lane&15);
                G[(size_t)row*512 + col] = f2b(acc[mi][ni][r]);
            }
        }
    }
}

// ---- GRU epilogue: G=[r|z|in|hn] (biases pre-folded) + A.h -> Anxt.h ----
__global__ void k_gruep(const ushort* __restrict__ G, const ushort* __restrict__ A,
                        ushort* __restrict__ Anxt){
    int idx = blockIdx.x*256 + threadIdx.x;   // NN*64
    int n = idx>>6, c2 = idx&63;
    const uint* g = (const uint*)G + (size_t)n*256;
    uint vr = g[c2], vz = g[64+c2], vin = g[128+c2], vhn = g[192+c2];
    uint vh = ((const uint*)A)[(size_t)n*AKU + 64 + c2];
    float r0 = sigm(blo(vr)), r1 = sigm(bhi(vr));
    float z0 = sigm(blo(vz)), z1 = sigm(bhi(vz));
    float n0 = tanhf(blo(vin) + r0*blo(vhn));
    float n1 = tanhf(bhi(vin) + r1*bhi(vhn));
    float h0 = (1.f-z0)*n0 + z0*blo(vh);
    float h1 = (1.f-z1)*n1 + z1*bhi(vh);
    ((uint*)Anxt)[(size_t)n*AKU + 64 + c2] = pack2(h0,h1);
}

// ---- hsum[n] = sum over in-edges of h[src] (within same A buffer) ----
__global__ void k_gather(ushort* __restrict__ A, const int* __restrict__ offs,
                         const int2* __restrict__ csr2){
    int node = blockIdx.x*4 + (threadIdx.x>>6);
    int c2 = threadIdx.x & 63;
    int b = offs[node], e2 = offs[node+1];
    float a0 = 0.f, a1 = 0.f;
    const uint* hp = (const uint*)A;
    int i = b;
    for (; i + 8 <= e2; i += 8){
        int s0=csr2[i].x,  s1=csr2[i+1].x, s2=csr2[i+2].x, s3=csr2[i+3].x;
        int s4=csr2[i+4].x,s5=csr2[i+5].x, s6=csr2[i+6].x, s7=csr2[i+7].x;
        uint v0=hp[(size_t)s0*AKU+64+c2], v1=hp[(size_t)s1*AKU+64+c2],
             v2=hp[(size_t)s2*AKU+64+c2], v3=hp[(size_t)s3*AKU+64+c2],
             v4=hp[(size_t)s4*AKU+64+c2], v5=hp[(size_t)s5*AKU+64+c2],
             v6=hp[(size_t)s6*AKU+64+c2], v7=hp[(size_t)s7*AKU+64+c2];
        a0 += blo(v0)+blo(v1)+blo(v2)+blo(v3)+blo(v4)+blo(v5)+blo(v6)+blo(v7);
        a1 += bhi(v0)+bhi(v1)+bhi(v2)+bhi(v3)+bhi(v4)+bhi(v5)+bhi(v6)+bhi(v7);
    }
    if (i + 4 <= e2){
        int s0=csr2[i].x,s1=csr2[i+1].x,s2=csr2[i+2].x,s3=csr2[i+3].x;
        uint v0=hp[(size_t)s0*AKU+64+c2], v1=hp[(size_t)s1*AKU+64+c2],
             v2=hp[(size_t)s2*AKU+64+c2], v3=hp[(size_t)s3*AKU+64+c2];
        a0 += blo(v0)+blo(v1)+blo(v2)+blo(v3);
        a1 += bhi(v0)+bhi(v1)+bhi(v2)+bhi(v3);
        i += 4;
    }
    for (; i < e2; ++i){
        uint v = hp[(size_t)csr2[i].x*AKU+64+c2];
        a0 += blo(v); a1 += bhi(v);
    }
    ((uint*)A)[(size_t)node*AKU + c2] = pack2(a0,a1);
}

// ---- two-stage column sum of final h (no atomics, fully parallel stage 2) ----
__global__ void k_sum1(const ushort* __restrict__ A, float* __restrict__ partial){
    int bid = blockIdx.x, tid = threadIdx.x;
    int lane = tid&63, w2 = tid>>6;
    int nb = bid*64;
    float a0=0.f, a1=0.f;
    const uint* hp = (const uint*)A;
    #pragma unroll
    for (int r=w2; r<64; r+=4){
        int n = nb + r;
        if (n < NN){
            uint v = hp[(size_t)n*AKU + 64 + lane];
            a0 += blo(v); a1 += bhi(v);
        }
    }
    __shared__ float s0[4][64], s1[4][64];
    s0[w2][lane]=a0; s1[w2][lane]=a1;
    __syncthreads();
    if (w2==0){
        a0 = s0[0][lane]+s0[1][lane]+s0[2][lane]+s0[3][lane];
        a1 = s1[0][lane]+s1[1][lane]+s1[2][lane]+s1[3][lane];
        ((float2*)partial)[(size_t)bid*64 + lane] = make_float2(a0,a1);
    }
}
__global__ void k_sum2(const float* __restrict__ partial, float* __restrict__ gsum){
    int c = blockIdx.x;          // 0..127
    int tid = threadIdx.x;       // 256
    int lane = tid&63, w = tid>>6;
    float a = 0.f;
    for (int b=tid; b<NSB; b+=256) a += partial[(size_t)b*128 + c];
    #pragma unroll
    for (int d=1; d<64; d<<=1) a += __shfl_xor(a, d);
    __shared__ float sh[4];
    if (lane==0) sh[w]=a;
    __syncthreads();
    if (tid==0) gsum[c] = sh[0]+sh[1]+sh[2]+sh[3];
}

// ---- tiny agents + value head, wave-parallel ----
__global__ void k_small(const float* __restrict__ ef, const int* __restrict__ paths,
                        const int* __restrict__ pmask, const float* __restrict__ pfeat,
                        const int* __restrict__ mmask, const int* __restrict__ smask,
                        const float* __restrict__ pspec,
                        const float* __restrict__ W_ep, const float* __restrict__ b_ep,
                        const float* __restrict__ W_path, const float* __restrict__ b_path,
                        const float* __restrict__ W_mod, const float* __restrict__ b_mod,
                        const float* __restrict__ c1w, const float* __restrict__ c1b,
                        const float* __restrict__ c2w, const float* __restrict__ c2b,
                        const float* __restrict__ W_val, const float* __restrict__ b_val,
                        const float* __restrict__ gsum, float* __restrict__ out){
    __shared__ float z[NPATH][HD];
    __shared__ float lf[NS];
    __shared__ float spec[NS];
    __shared__ float red[8];
    __shared__ float scal[3];
    __shared__ int   sel[3];
    __shared__ float maxsh;
    int tid = threadIdx.x, lane = tid&63, w = tid>>6;

    { // z[p][c] for 16 paths
        int pr = tid>>7, c = tid&127;
        #pragma unroll
        for (int pb=0; pb<4; pb++){
            int p = pb*4 + pr;
            float acc = 0.f;
            for (int l=0;l<PL;l++){
                int eid = paths[p*PL + l];
                const float* f = ef + (size_t)eid*FD;
                #pragma unroll
                for (int k=0;k<FD;k++) acc += f[k]*W_ep[k*HD + c];
            }
            z[p][c] = acc*0.125f + b_ep[c];
        }
    }
    __syncthreads();
    { // logits_p
        int p = tid>>5, sub = tid&31;
        float part = 0.f;
        #pragma unroll
        for (int c=sub;c<HD;c+=32) part += z[p][c]*W_path[c];
        #pragma unroll
        for (int d=16; d>=1; d>>=1) part += __shfl_xor(part, d);
        if (sub==0) lf[p] = (pmask[p]==0)? NEGV : part + b_path[0];
    }
    __syncthreads();
    if (w==0){
        float v = (lane<NPATH)? lf[lane] : -3.0e38f;
        float m = v;
        #pragma unroll
        for (int d=1; d<64; d<<=1) m = fmaxf(m, __shfl_xor(m, d));
        float e = (lane<NPATH)? expf(v-m) : 0.f;
        #pragma unroll
        for (int d=1; d<64; d<<=1) e += __shfl_xor(e, d);
        int idx = (lane<NPATH && v==m)? lane : (1<<30);
        #pragma unroll
        for (int d=1; d<64; d<<=1) idx = min(idx, __shfl_xor(idx, d));
        if (lane==0){ sel[0]=idx; scal[0] = -logf(e); }
    }
    __syncthreads();
    int pstar = sel[0];
    if (w < NM){
        float part = 0.f;
        #pragma unroll
        for (int c=lane;c<HD;c+=64) part += z[pstar][c]*W_mod[c*NM + w];
        if (lane<3) part += pfeat[pstar*3+lane]*W_mod[(HD+lane)*NM + w];
        #pragma unroll
        for (int d=1; d<64; d<<=1) part += __shfl_xor(part, d);
        if (lane==0) red[w] = (mmask[pstar*NM + w]==0)? NEGV : part + b_mod[w];
    } else if (w == 7){
        float part = gsum[lane]*W_val[lane] + gsum[lane+64]*W_val[lane+64];
        #pragma unroll
        for (int d=1; d<64; d<<=1) part += __shfl_xor(part, d);
        if (lane==0) scal[2] = part/(float)NN + b_val[0];
    }
    __syncthreads();
    if (w==0){
        float v = (lane<NM)? red[lane] : -3.0e38f;
        float m = v;
        #pragma unroll
        for (int d=1; d<64; d<<=1) m = fmaxf(m, __shfl_xor(m, d));
        float e = (lane<NM)? expf(v-m) : 0.f;
        #pragma unroll
        for (int d=1; d<64; d<<=1) e += __shfl_xor(e, d);
        int idx = (lane<NM && v==m)? lane : (1<<30);
        #pragma unroll
        for (int d=1; d<64; d<<=1) idx = min(idx, __shfl_xor(idx, d));
        if (lane==0){ sel[1]=idx; scal[1] = -logf(e); }
    }
    __syncthreads();
    int mstar = sel[1];
    if (tid < NS) spec[tid] = pspec[pstar*NS + tid];
    __syncthreads();
    float v = -3.0e38f;
    if (tid < NS){
        float acc = c2b[0];
        #pragma unroll
        for (int ch=0; ch<8; ch++){
            float a = c1b[ch];
            #pragma unroll
            for (int k=0;k<5;k++){
                int ss = tid + k - 2;
                if (ss>=0 && ss<NS) a += spec[ss]*c1w[ch*5+k];
            }
            a = fmaxf(a, 0.f);
            acc += a*c2w[ch];
        }
        v = (smask[pstar*NM*NS + mstar*NS + tid]==0) ? NEGV : acc;
    }
    float m = v;
    #pragma unroll
    for (int d=1; d<64; d<<=1) m = fmaxf(m, __shfl_xor(m, d));
    if (lane==0) red[w] = m;
    __syncthreads();
    if (tid==0){
        float mm = red[0];
        #pragma unroll
        for (int i=1;i<8;i++) mm = fmaxf(mm, red[i]);
        maxsh = mm; sel[2] = 1<<30;
    }
    __syncthreads();
    float M2 = maxsh;
    if (tid<NS && v==M2) atomicMin(&sel[2], tid);
    float e = (tid<NS)? expf(v-M2) : 0.f;
    #pragma unroll
    for (int d=1; d<64; d<<=1) e += __shfl_xor(e, d);
    if (lane==0) red[w] = e;
    __syncthreads();
    if (tid==0){
        float se = 0.f;
        #pragma unroll
        for (int i=0;i<8;i++) se += red[i];
        out[0] = (float)pstar;
        out[1] = (float)sel[2];
        out[2] = (float)mstar;
        out[3] = scal[0] + scal[1] - logf(se);
        out[4] = scal[2];
    }
}

extern "C" void kernel_launch(void* const* d_in, const int* in_sizes, int n_in,
                              void* d_out, int out_size, void* d_ws, size_t ws_size,
                              hipStream_t stream) {
    (void)in_sizes; (void)n_in; (void)out_size; (void)ws_size;
    const float* node_feat     = (const float*)d_in[0];
    const float* edge_feat     = (const float*)d_in[1];
    const int*   edge_index    = (const int*)d_in[2];
    const int*   paths         = (const int*)d_in[3];
    const int*   path_mask     = (const int*)d_in[4];
    const float* path_features = (const float*)d_in[5];
    const int*   mod_masks     = (const int*)d_in[6];
    const int*   spec_masks    = (const int*)d_in[7];
    const float* path_spectrum = (const float*)d_in[8];
    const float* W_np  = (const float*)d_in[9];
    const float* b_np  = (const float*)d_in[10];
    const float* W_ep  = (const float*)d_in[11];
    const float* b_ep  = (const float*)d_in[12];
    const float* W_msg = (const float*)d_in[13];
    const float* b_msg = (const float*)d_in[14];
    const float* W_ih  = (const float*)d_in[15];
    const float* b_ih  = (const float*)d_in[16];
    const float* W_hh  = (const float*)d_in[17];
    const float* b_hh  = (const float*)d_in[18];
    const float* W_path = (const float*)d_in[19];
    const float* b_path = (const float*)d_in[20];
    const float* W_mod  = (const float*)d_in[21];
    const float* b_mod  = (const float*)d_in[22];
    const float* c1w = (const float*)d_in[23];
    const float* c1b = (const float*)d_in[24];
    const float* c2w = (const float*)d_in[25];
    const float* c2b = (const float*)d_in[26];
    const float* W_val = (const float*)d_in[27];
    const float* b_val = (const float*)d_in[28];

    char* ws = (char*)d_ws;
    size_t off = 0;
    auto alloc = [&](size_t bytes)->char*{
        char* p = ws + off;
        off += (bytes + 255) & ~(size_t)255;
        return p;
    };
    int*    deg     = (int*)alloc((size_t)NN*4);
    int*    offs    = (int*)alloc((size_t)(NN+1)*4);
    int*    bsum    = (int*)alloc((size_t)NB*4);
    int*    Cmat    = (int*)alloc((size_t)NBLK*NBKT*4);
    int2*   bkt2    = (int2*)alloc((size_t)NE*8);
    int2*   csr2    = (int2*)alloc((size_t)NE*8);
    float*  ef_sum  = (float*)alloc((size_t)NN*FD*4);
    float*  nf_sum  = (float*)alloc((size_t)NN*FD*4);
    float*  Wf      = (float*)alloc((size_t)FD*HD*4);
    float*  bfv     = (float*)alloc((size_t)HD*4);
    ushort* W2T     = (ushort*)alloc((size_t)512*AK*2);
    ushort* A0      = (ushort*)alloc((size_t)NN*AK*2);
    ushort* A1      = (ushort*)alloc((size_t)NN*AK*2);
    ushort* G       = (ushort*)alloc((size_t)NN*512*2);
    float*  partial = (float*)alloc((size_t)NSB*HD*4);
    float*  gsum    = (float*)alloc((size_t)HD*4);

    hipMemsetAsync(deg, 0, (size_t)NN*4, stream);

    k_deg<<<(NE+255)/256, 256, 0, stream>>>(edge_index, deg);
    k_scan1<<<NB, 256, 0, stream>>>(deg, offs, bsum);
    k_scan2<<<1, 256, 0, stream>>>(bsum, offs);
    k_scan3<<<NB, 256, 0, stream>>>(bsum, offs);
    k_hist<<<NBLK, 256, 0, stream>>>(edge_index, Cmat);
    k_cscan<<<(NBKT+3)/4, 256, 0, stream>>>(Cmat, offs);
    k_scatA<<<NBLK, 256, 0, stream>>>(edge_index, Cmat, bkt2);
    k_scatB<<<NBKT, 256, 0, stream>>>(edge_index, bkt2, offs, csr2);
    k_gat16<<<NN/4, 256, 0, stream>>>(csr2, edge_feat, node_feat, offs, ef_sum, nf_sum);
    k_folds<<<9, 256, 0, stream>>>(W_ep, b_ep, W_msg, b_msg, Wf, bfv);
    k_wprep2<<<512, AK, 0, stream>>>(W_ih, W_hh, W_msg, Wf, bfv, b_ih, b_hh, W2T);
    k_prep<<<NN*64/256, 256, 0, stream>>>(node_feat, nf_sum, deg, W_np, b_np, ef_sum, A0, A1);

    const int MB = (NN+127)/128;   // 391
    // iter 1: A0 -> G -> A1.h
    k_gemmG<<<dim3(4,MB), 256, 0, stream>>>(A0, W2T, G);
    k_gruep<<<NN*64/256, 256, 0, stream>>>(G, A0, A1);
    // iter 2: gather(A1) -> G -> A0.h
    k_gather<<<NN/4, 256, 0, stream>>>(A1, offs, csr2);
    k_gemmG<<<dim3(4,MB), 256, 0, stream>>>(A1, W2T, G);
    k_gruep<<<NN*64/256, 256, 0, stream>>>(G, A1, A0);
    // iter 3: gather(A0) -> G -> A1.h
    k_gather<<<NN/4, 256, 0, stream>>>(A0, offs, csr2);
    k_gemmG<<<dim3(4,MB), 256, 0, stream>>>(A0, W2T, G);
    k_gruep<<<NN*64/256, 256, 0, stream>>>(G, A0, A1);

    k_sum1<<<NSB, 256, 0, stream>>>(A1, partial);
    k_sum2<<<HD, 256, 0, stream>>>(partial, gsum);
    k_small<<<1, 512, 0, stream>>>(edge_feat, paths, path_mask, path_features,
                                   mod_masks, spec_masks, path_spectrum,
                                   W_ep, b_ep, W_path, b_path, W_mod, b_mod,
                                   c1w, c1b, c2w, c2b, W_val, b_val,
                                   gsum, (float*)d_out);
}

// Round 10
// 366.763 us; speedup vs baseline: 1.3892x; 1.0471x over previous
//
#include <hip/hip_runtime.h>
#include <math.h>

#define NN 50000
#define NE 800000
#define HD 128
#define FD 16
#define NPATH 16
#define PL 8
#define NM 6
#define NS 320
#define NB 196    // ceil(NN/256)
#define NSB 782   // ceil(NN/64)
#define AK 320    // K for iters 2-3 GEMM (hsum128 | h128 | ef16 | deg | 1 | pad)
#define AKU 160   // uints per A row
#define AK1 64    // K for iter-1 GEMM (nf16 | nfsum16 | ef16 | deg | 1 | pad)
#define EPB 2048  // edges per histogram/scatter block
#define NBLK 391  // ceil(NE/EPB)
#define NBKT 196  // buckets = dst>>8
#define NEGV -1000000000.0f

typedef unsigned int uint;
typedef unsigned short ushort;
typedef short bf16x8 __attribute__((ext_vector_type(8)));
typedef float f32x4 __attribute__((ext_vector_type(4)));

__device__ __forceinline__ float sigm(float x){ return 1.0f/(1.0f+expf(-x)); }

__device__ __forceinline__ ushort f2b(float f){
    union{float f; uint u;} v; v.f=f;
    uint r = v.u + 0x7FFFu + ((v.u>>16)&1u);
    return (ushort)(r>>16);
}
__device__ __forceinline__ float b2f(ushort s){
    union{uint u; float f;} v; v.u = ((uint)s)<<16; return v.f;
}
__device__ __forceinline__ float blo(uint v){ return b2f((ushort)(v&0xFFFF)); }
__device__ __forceinline__ float bhi(uint v){ return b2f((ushort)(v>>16)); }
__device__ __forceinline__ uint pack2(float a, float b){ return (uint)f2b(a) | (((uint)f2b(b))<<16); }

// ---- degree histogram ----
__global__ void k_deg(const int* __restrict__ ei, int* __restrict__ deg){
    int e = blockIdx.x*256 + threadIdx.x;
    if (e >= NE) return;
    atomicAdd(&deg[ei[NE + e]], 1);
}

// ---- hierarchical exclusive scan over deg -> offs ----
__global__ void k_scan1(const int* __restrict__ deg, int* __restrict__ offs, int* __restrict__ bsum){
    int tid = threadIdx.x, bid = blockIdx.x;
    int idx = bid*256 + tid;
    int v = (idx<NN) ? deg[idx] : 0;
    int lane = tid&63, w = tid>>6;
    int x = v;
    #pragma unroll
    for (int d=1; d<64; d<<=1){ int y = __shfl_up(x,d); if (lane>=d) x += y; }
    __shared__ int wsum[4];
    if (lane==63) wsum[w] = x;
    __syncthreads();
    int base = 0;
    #pragma unroll
    for (int j=0;j<4;j++) if (j<w) base += wsum[j];
    if (idx<NN) offs[idx] = base + x - v;
    if (tid==255) bsum[bid] = base + x;
}
__global__ void k_scan2(int* __restrict__ bsum, int* __restrict__ offs){
    int tid = threadIdx.x;
    int v = (tid<NB) ? bsum[tid] : 0;
    int lane = tid&63, w = tid>>6;
    int x = v;
    #pragma unroll
    for (int d=1; d<64; d<<=1){ int y = __shfl_up(x,d); if (lane>=d) x += y; }
    __shared__ int wsum[4];
    if (lane==63) wsum[w] = x;
    __syncthreads();
    int base = 0;
    #pragma unroll
    for (int j=0;j<4;j++) if (j<w) base += wsum[j];
    if (tid<NB) bsum[tid] = base + x - v;
    if (tid==255) offs[NN] = base + x;
}
__global__ void k_scan3(const int* __restrict__ bsum, int* __restrict__ offs){
    int idx = blockIdx.x*256 + threadIdx.x;
    if (idx>=NN) return;
    offs[idx] += bsum[blockIdx.x];
}

// ---- counting sort phase 1: per-block bucket histogram ----
__global__ void k_hist(const int* __restrict__ ei, int* __restrict__ C){
    __shared__ int h[NBKT];
    int tid = threadIdx.x, blk = blockIdx.x;
    if (tid < NBKT) h[tid] = 0;
    __syncthreads();
    int e0 = blk*EPB;
    for (int i=tid; i<EPB; i+=256){
        int e = e0+i;
        if (e < NE) atomicAdd(&h[ei[NE+e]>>8], 1);
    }
    __syncthreads();
    if (tid < NBKT) C[blk*NBKT + tid] = h[tid];
}

// ---- phase 2: column-wise exclusive scan of C + bucket base from offs ----
__global__ void k_cscan(int* __restrict__ C, const int* __restrict__ offs){
    int b = blockIdx.x*4 + (threadIdx.x>>6);
    int lane = threadIdx.x & 63;
    if (b >= NBKT) return;
    int base = offs[b<<8];
    int carry = 0;
    for (int c=0; c<7; ++c){
        int i = c*64 + lane;
        int v = (i<NBLK)? C[i*NBKT + b] : 0;
        int x = v;
        #pragma unroll
        for (int d=1; d<64; d<<=1){ int y = __shfl_up(x,d); if (lane>=d) x += y; }
        if (i<NBLK) C[i*NBKT + b] = base + carry + (x - v);
        carry += __shfl(x, 63);
    }
}

// ---- phase 3: scatter edges into bucket-ordered array (sequential streams) ----
__global__ void k_scatA(const int* __restrict__ ei, const int* __restrict__ C,
                        int2* __restrict__ bkt2){
    __shared__ int cur[NBKT];
    __shared__ int cbase[NBKT];
    int tid = threadIdx.x, blk = blockIdx.x;
    if (tid < NBKT){ cur[tid] = 0; cbase[tid] = C[blk*NBKT + tid]; }
    __syncthreads();
    int e0 = blk*EPB;
    for (int i=tid; i<EPB; i+=256){
        int e = e0+i;
        if (e >= NE) break;
        int dst = ei[NE+e];
        int bkt = dst>>8;
        int r = atomicAdd(&cur[bkt], 1);
        bkt2[cbase[bkt] + r] = make_int2(dst, e);
    }
}

// ---- phase 4: per-bucket exact per-dst placement (single-CU 32KB window) ----
__global__ void k_scatB(const int* __restrict__ ei, const int2* __restrict__ bkt2,
                        const int* __restrict__ offs, int2* __restrict__ csr2){
    __shared__ int cur[256];
    int b = blockIdx.x, tid = threadIdx.x;
    int d0 = b<<8;
    {
        int idx = d0 + tid;
        cur[tid] = (idx<NN)? offs[idx] : 0;
    }
    __syncthreads();
    int lo = offs[d0];
    int hi = (d0+256 <= NN)? offs[d0+256] : offs[NN];
    for (int i=lo+tid; i<hi; i+=256){
        int2 p = bkt2[i];
        int pos = atomicAdd(&cur[p.x & 255], 1);
        csr2[pos] = make_int2(ei[p.y], p.y);
    }
}

// ---- per-node 16-wide sums of edge_feat (by eid) and node_feat (by src) ----
__global__ void k_gat16(const int2* __restrict__ csr2,
                        const float* __restrict__ edge_feat, const float* __restrict__ nf,
                        const int* __restrict__ offs,
                        float* __restrict__ ef_sum, float* __restrict__ nf_sum){
    int node = blockIdx.x*4 + (threadIdx.x>>6);
    int lane = threadIdx.x & 63;
    int k = lane & 15, sub = lane >> 4;
    int b = offs[node], e2 = offs[node+1];
    float ae = 0.f, an = 0.f;
    int i = b + sub;
    for (; i + 4 < e2; i += 8){
        int2 p0 = csr2[i], p1 = csr2[i+4];
        float f0 = edge_feat[(size_t)p0.y*FD + k];
        float g0 = nf[(size_t)p0.x*FD + k];
        float f1 = edge_feat[(size_t)p1.y*FD + k];
        float g1 = nf[(size_t)p1.x*FD + k];
        ae += f0 + f1; an += g0 + g1;
    }
    if (i < e2){
        int2 p0 = csr2[i];
        ae += edge_feat[(size_t)p0.y*FD + k];
        an += nf[(size_t)p0.x*FD + k];
    }
    ae += __shfl_xor(ae, 16); ae += __shfl_xor(ae, 32);
    an += __shfl_xor(an, 16); an += __shfl_xor(an, 32);
    if (sub == 0){ ef_sum[node*FD + k] = ae; nf_sum[node*FD + k] = an; }
}

// ---- Wf = W_ep@W_e ; bfv = b_ep@W_e + b_msg ----
__global__ void k_folds(const float* __restrict__ W_ep, const float* __restrict__ b_ep,
                        const float* __restrict__ W_msg, const float* __restrict__ b_msg,
                        float* __restrict__ Wf, float* __restrict__ bfv){
    int o = blockIdx.x*256 + threadIdx.x;
    if (o < FD*HD){
        int k=o>>7, c=o&127;
        float acc=0.f;
        for (int m=0;m<HD;m++) acc += W_ep[k*HD+m]*W_msg[(HD+m)*HD+c];
        Wf[o]=acc;
    } else if (o < FD*HD+HD){
        int c=o-FD*HD;
        float acc=b_msg[c];
        for (int m=0;m<HD;m++) acc += b_ep[m]*W_msg[(HD+m)*HD+c];
        bfv[c]=acc;
    }
}

// ---- build folded mega-weight W2T[512][320], gate-blocked: col = g*128 + j ----
// Also emits fp32 copy of k<128 block (Wt32) for the iter-1 fold.
__global__ void k_wprep2(const float* __restrict__ W_ih, const float* __restrict__ W_hh,
                         const float* __restrict__ W_msg, const float* __restrict__ Wf,
                         const float* __restrict__ bfv,
                         const float* __restrict__ b_ih, const float* __restrict__ b_hh,
                         ushort* __restrict__ W2T, float* __restrict__ Wt32){
    int c = blockIdx.x;       // 0..511
    int k = threadIdx.x;      // 0..319
    int g = c>>7, j = c&127;
    float v = 0.f;
    if (k < 128){
        float acc = 0.f;
        if (g < 3){   // hsum path: (W_h @ W_ih_g^T)
            const float* wm = W_msg + (size_t)k*HD;
            const float* wi = W_ih + (size_t)(g*HD+j)*HD;
            for (int m=0;m<HD;m++) acc += wm[m]*wi[m];
        }
        Wt32[(size_t)c*HD + k] = acc;
        v = acc;
    } else if (k < 256){      // h path: W_hh gates (none for gi_n)
        int kk = k-128;
        if (g==0)      v = W_hh[(size_t)j*HD+kk];
        else if (g==1) v = W_hh[(size_t)(HD+j)*HD+kk];
        else if (g==3) v = W_hh[(size_t)(2*HD+j)*HD+kk];
    } else if (k < 272){      // ef_sum path
        if (g < 3){
            const float* wf = Wf + (size_t)(k-256)*HD;
            const float* wi = W_ih + (size_t)(g*HD+j)*HD;
            float acc=0.f;
            for (int m=0;m<HD;m++) acc += wf[m]*wi[m];
            v = acc;
        }
    } else if (k == 272){     // deg path
        if (g < 3){
            const float* wi = W_ih + (size_t)(g*HD+j)*HD;
            float acc=0.f;
            for (int m=0;m<HD;m++) acc += bfv[m]*wi[m];
            v = acc;
        }
    } else if (k == 273){     // constant-1: biases
        v = (g==0)? b_ih[j]+b_hh[j] : (g==1)? b_ih[HD+j]+b_hh[HD+j]
          : (g==2)? b_ih[2*HD+j] : b_hh[2*HD+j];
    }
    W2T[(size_t)c*AK + k] = f2b(v);
}

// ---- iter-1 weight W1T[512][64]: cols [nf16|nfsum16|ef16|deg|1|pad], W_np folded in ----
__global__ void k_wprep1(const float* __restrict__ W_np, const float* __restrict__ b_np,
                         const float* __restrict__ W_hh, const float* __restrict__ Wt32,
                         const ushort* __restrict__ W2T, ushort* __restrict__ W1T){
    int c = blockIdx.x;       // 0..511
    int k = threadIdx.x;      // 0..63
    int g = c>>7, j = c&127;
    float v = 0.f;
    if (k < 16){              // nf path: W_np @ W_hh_g^T  (g2 has no h-term)
        if (g != 2){
            int gp = (g==3)? 2 : g;
            const float* wh = W_hh + (size_t)(gp*HD + j)*HD;
            const float* wn = W_np + (size_t)k*HD;
            float acc=0.f;
            for (int m=0;m<HD;m++) acc += wn[m]*wh[m];
            v = acc;
        }
    } else if (k < 32){       // nf_sum path: W_np @ t_g (t = W_h@W_ih_g^T, zero for g3)
        const float* wt = Wt32 + (size_t)c*HD;
        const float* wn = W_np + (size_t)(k-16)*HD;
        float acc=0.f;
        for (int m=0;m<HD;m++) acc += wn[m]*wt[m];
        v = acc;
    } else if (k < 48){       // ef_sum path: copy from W2T
        v = b2f(W2T[(size_t)c*AK + 256 + (k-32)]);
    } else if (k == 48){      // deg: b_np@t_g + old deg col
        float acc = b2f(W2T[(size_t)c*AK + 272]);
        const float* wt = Wt32 + (size_t)c*HD;
        for (int m=0;m<HD;m++) acc += b_np[m]*wt[m];
        v = acc;
    } else if (k == 49){      // const-1: old biases + b_np@W_hh_g^T (h0's bias part)
        float acc = b2f(W2T[(size_t)c*AK + 273]);
        if (g != 2){
            int gp = (g==3)? 2 : g;
            const float* wh = W_hh + (size_t)(gp*HD + j)*HD;
            for (int m=0;m<HD;m++) acc += b_np[m]*wh[m];
        }
        v = acc;
    }
    W1T[(size_t)c*AK1 + k] = f2b(v);
}

// ---- light prep: A1prep[NN][64] = [nf|nfsum|ef|deg|1|0], statics into A ----
__global__ void k_prep2(const float* __restrict__ nf, const float* __restrict__ nf_sum,
                        const float* __restrict__ ef_sum, const int* __restrict__ deg,
                        ushort* __restrict__ A1p, ushort* __restrict__ A){
    int idx = blockIdx.x*256 + threadIdx.x;   // NN*32
    int n = idx>>5, c2 = idx&31;
    int k = c2*2, k1 = k+1;
    float d = (float)deg[n];
    float v0 = (k<16)? nf[n*FD+k] : (k<32)? nf_sum[n*FD+k-16] : (k<48)? ef_sum[n*FD+k-32]
             : (k==48)? d : 0.f;
    float v1 = (k1<16)? nf[n*FD+k1] : (k1<32)? nf_sum[n*FD+k1-16] : (k1<48)? ef_sum[n*FD+k1-32]
             : (k1==49)? 1.f : 0.f;
    ((uint*)A1p)[(size_t)n*32 + c2] = pack2(v0,v1);
    int col = 256 + k;
    float s0 = (col<272)? ef_sum[n*FD + col-256] : (col==272)? d : 0.f;
    float s1 = (col+1<272)? ef_sum[n*FD + col+1-256] : (col+1==273)? 1.f : 0.f;
    ((uint*)A)[(size_t)n*AKU + 128 + c2] = pack2(s0,s1);
}

// ---- G = A @ Bt^T, 128x128 tile. IT1: K=64 single step; else K=320 with gate skip ----
template<bool IT1>
__global__ __launch_bounds__(256) void k_gemmG(const ushort* __restrict__ A,
                                               const ushort* __restrict__ Bt,
                                               ushort* __restrict__ G){
    __shared__ __align__(16) short As[128*64];
    __shared__ __align__(16) short Bs[128*64];
    const int tid = threadIdx.x;
    const int lane = tid & 63, w = tid>>6;
    const int wm = w>>1, wn = w&1;
    const int n0 = blockIdx.x*128, m0 = blockIdx.y*128;
    const int AKA = IT1 ? AK1 : AK;
    const int g = n0>>7;
    const int nsteps = IT1 ? 1 : ((g>=2)? 3 : 5);
    f32x4 acc[4][4] = {};
    for (int si=0; si<nsteps; ++si){
        int kk = IT1 ? 0 : ((g<2)? si : (g==2 ? ((si<2)? si : 4) : (si+2)));
        __syncthreads();
        #pragma unroll
        for (int i=0;i<4;i++){
            int id = tid + i*256;
            int row = id>>3, s = id&7;
            int phys = row*64 + ((s ^ (row&7))<<3);
            int ar = m0 + row; if (ar >= NN) ar = NN-1;
            *(int4*)&As[phys] = *(const int4*)(A + (size_t)ar*AKA + kk*64 + s*8);
            *(int4*)&Bs[phys] = *(const int4*)(Bt + (size_t)(n0+row)*AKA + kk*64 + s*8);
        }
        __syncthreads();
        #pragma unroll
        for (int ksel=0; ksel<2; ++ksel){
            bf16x8 af[4], bfr[4];
            #pragma unroll
            for (int t=0;t<4;t++){
                int arow = wm*64 + t*16 + (lane&15);
                int aslot = (ksel*4 + (lane>>4)) ^ (arow&7);
                af[t] = *(const bf16x8*)&As[arow*64 + aslot*8];
                int brow = wn*64 + t*16 + (lane&15);
                int bslot = (ksel*4 + (lane>>4)) ^ (brow&7);
                bfr[t] = *(const bf16x8*)&Bs[brow*64 + bslot*8];
            }
            #pragma unroll
            for (int mi=0;mi<4;mi++)
                #pragma unroll
                for (int ni=0;ni<4;ni++)
                    acc[mi][ni] = __builtin_amdgcn_mfma_f32_16x16x32_bf16(af[mi], bfr[ni], acc[mi][ni], 0,0,0);
        }
    }
    #pragma unroll
    for (int mi=0;mi<4;mi++){
        #pragma unroll
        for (int r=0;r<4;r++){
            int row = m0 + wm*64 + mi*16 + (lane>>4)*4 + r;
            if (row >= NN) continue;
            #pragma unroll
            for (int ni=0;ni<4;ni++){
                int col = n0 + wn*64 + ni*16 + (lane&15);
                G[(size_t)row*512 + col] = f2b(acc[mi][ni][r]);
            }
        }
    }
}

// ---- GRU epilogue iters 2-3: in-place h update ----
__global__ void k_gruep(const ushort* __restrict__ G, ushort* __restrict__ A){
    int idx = blockIdx.x*256 + threadIdx.x;   // NN*64
    int n = idx>>6, c2 = idx&63;
    const uint* g = (const uint*)G + (size_t)n*256;
    uint vr = g[c2], vz = g[64+c2], vin = g[128+c2], vhn = g[192+c2];
    uint vh = ((const uint*)A)[(size_t)n*AKU + 64 + c2];
    float r0 = sigm(blo(vr)), r1 = sigm(bhi(vr));
    float z0 = sigm(blo(vz)), z1 = sigm(bhi(vz));
    float n0 = tanhf(blo(vin) + r0*blo(vhn));
    float n1 = tanhf(bhi(vin) + r1*bhi(vhn));
    float h0 = (1.f-z0)*n0 + z0*blo(vh);
    float h1 = (1.f-z1)*n1 + z1*bhi(vh);
    ((uint*)A)[(size_t)n*AKU + 64 + c2] = pack2(h0,h1);
}

// ---- GRU epilogue iter 1: h0 computed inline from nf ----
__global__ void k_gruep1(const ushort* __restrict__ G, const float* __restrict__ nf,
                         const float* __restrict__ W_np, const float* __restrict__ b_np,
                         ushort* __restrict__ A){
    int idx = blockIdx.x*256 + threadIdx.x;   // NN*64
    int n = idx>>6, c2 = idx&63;
    int j = c2*2;
    const uint* g = (const uint*)G + (size_t)n*256;
    uint vr = g[c2], vz = g[64+c2], vin = g[128+c2], vhn = g[192+c2];
    const float* x = nf + (size_t)n*FD;
    float h0a = b_np[j], h0b = b_np[j+1];
    #pragma unroll
    for (int k=0;k<FD;k++){ float xv=x[k]; h0a += xv*W_np[k*HD+j]; h0b += xv*W_np[k*HD+j+1]; }
    float r0 = sigm(blo(vr)), r1 = sigm(bhi(vr));
    float z0 = sigm(blo(vz)), z1 = sigm(bhi(vz));
    float n0 = tanhf(blo(vin) + r0*blo(vhn));
    float n1 = tanhf(bhi(vin) + r1*bhi(vhn));
    ((uint*)A)[(size_t)n*AKU + 64 + c2] = pack2((1.f-z0)*n0 + z0*h0a, (1.f-z1)*n1 + z1*h0b);
}

// ---- hsum[n] = sum over in-edges of h[src] (within same A buffer) ----
__global__ void k_gather(ushort* __restrict__ A, const int* __restrict__ offs,
                         const int2* __restrict__ csr2){
    int node = blockIdx.x*4 + (threadIdx.x>>6);
    int c2 = threadIdx.x & 63;
    int b = offs[node], e2 = offs[node+1];
    float a0 = 0.f, a1 = 0.f;
    const uint* hp = (const uint*)A;
    int i = b;
    for (; i + 8 <= e2; i += 8){
        int s0=csr2[i].x,  s1=csr2[i+1].x, s2=csr2[i+2].x, s3=csr2[i+3].x;
        int s4=csr2[i+4].x,s5=csr2[i+5].x, s6=csr2[i+6].x, s7=csr2[i+7].x;
        uint v0=hp[(size_t)s0*AKU+64+c2], v1=hp[(size_t)s1*AKU+64+c2],
             v2=hp[(size_t)s2*AKU+64+c2], v3=hp[(size_t)s3*AKU+64+c2],
             v4=hp[(size_t)s4*AKU+64+c2], v5=hp[(size_t)s5*AKU+64+c2],
             v6=hp[(size_t)s6*AKU+64+c2], v7=hp[(size_t)s7*AKU+64+c2];
        a0 += blo(v0)+blo(v1)+blo(v2)+blo(v3)+blo(v4)+blo(v5)+blo(v6)+blo(v7);
        a1 += bhi(v0)+bhi(v1)+bhi(v2)+bhi(v3)+bhi(v4)+bhi(v5)+bhi(v6)+bhi(v7);
    }
    if (i + 4 <= e2){
        int s0=csr2[i].x,s1=csr2[i+1].x,s2=csr2[i+2].x,s3=csr2[i+3].x;
        uint v0=hp[(size_t)s0*AKU+64+c2], v1=hp[(size_t)s1*AKU+64+c2],
             v2=hp[(size_t)s2*AKU+64+c2], v3=hp[(size_t)s3*AKU+64+c2];
        a0 += blo(v0)+blo(v1)+blo(v2)+blo(v3);
        a1 += bhi(v0)+bhi(v1)+bhi(v2)+bhi(v3);
        i += 4;
    }
    for (; i < e2; ++i){
        uint v = hp[(size_t)csr2[i].x*AKU+64+c2];
        a0 += blo(v); a1 += bhi(v);
    }
    ((uint*)A)[(size_t)node*AKU + c2] = pack2(a0,a1);
}

// ---- two-stage column sum of final h ----
__global__ void k_sum1(const ushort* __restrict__ A, float* __restrict__ partial){
    int bid = blockIdx.x, tid = threadIdx.x;
    int lane = tid&63, w2 = tid>>6;
    int nb = bid*64;
    float a0=0.f, a1=0.f;
    const uint* hp = (const uint*)A;
    #pragma unroll
    for (int r=w2; r<64; r+=4){
        int n = nb + r;
        if (n < NN){
            uint v = hp[(size_t)n*AKU + 64 + lane];
            a0 += blo(v); a1 += bhi(v);
        }
    }
    __shared__ float s0[4][64], s1[4][64];
    s0[w2][lane]=a0; s1[w2][lane]=a1;
    __syncthreads();
    if (w2==0){
        a0 = s0[0][lane]+s0[1][lane]+s0[2][lane]+s0[3][lane];
        a1 = s1[0][lane]+s1[1][lane]+s1[2][lane]+s1[3][lane];
        ((float2*)partial)[(size_t)bid*64 + lane] = make_float2(a0,a1);
    }
}
__global__ void k_sum2(const float* __restrict__ partial, float* __restrict__ gsum){
    int c = blockIdx.x;          // 0..127
    int tid = threadIdx.x;       // 256
    int lane = tid&63, w = tid>>6;
    float a = 0.f;
    for (int b=tid; b<NSB; b+=256) a += partial[(size_t)b*128 + c];
    #pragma unroll
    for (int d=1; d<64; d<<=1) a += __shfl_xor(a, d);
    __shared__ float sh[4];
    if (lane==0) sh[w]=a;
    __syncthreads();
    if (tid==0) gsum[c] = sh[0]+sh[1]+sh[2]+sh[3];
}

// ---- tiny agents + value head, wave-parallel ----
__global__ void k_small(const float* __restrict__ ef, const int* __restrict__ paths,
                        const int* __restrict__ pmask, const float* __restrict__ pfeat,
                        const int* __restrict__ mmask, const int* __restrict__ smask,
                        const float* __restrict__ pspec,
                        const float* __restrict__ W_ep, const float* __restrict__ b_ep,
                        const float* __restrict__ W_path, const float* __restrict__ b_path,
                        const float* __restrict__ W_mod, const float* __restrict__ b_mod,
                        const float* __restrict__ c1w, const float* __restrict__ c1b,
                        const float* __restrict__ c2w, const float* __restrict__ c2b,
                        const float* __restrict__ W_val, const float* __restrict__ b_val,
                        const float* __restrict__ gsum, float* __restrict__ out){
    __shared__ float z[NPATH][HD];
    __shared__ float lf[NS];
    __shared__ float spec[NS];
    __shared__ float red[8];
    __shared__ float scal[3];
    __shared__ int   sel[3];
    __shared__ float maxsh;
    int tid = threadIdx.x, lane = tid&63, w = tid>>6;

    { // z[p][c] for 16 paths
        int pr = tid>>7, c = tid&127;
        #pragma unroll
        for (int pb=0; pb<4; pb++){
            int p = pb*4 + pr;
            float acc = 0.f;
            for (int l=0;l<PL;l++){
                int eid = paths[p*PL + l];
                const float* f = ef + (size_t)eid*FD;
                #pragma unroll
                for (int k=0;k<FD;k++) acc += f[k]*W_ep[k*HD + c];
            }
            z[p][c] = acc*0.125f + b_ep[c];
        }
    }
    __syncthreads();
    { // logits_p
        int p = tid>>5, sub = tid&31;
        float part = 0.f;
        #pragma unroll
        for (int c=sub;c<HD;c+=32) part += z[p][c]*W_path[c];
        #pragma unroll
        for (int d=16; d>=1; d>>=1) part += __shfl_xor(part, d);
        if (sub==0) lf[p] = (pmask[p]==0)? NEGV : part + b_path[0];
    }
    __syncthreads();
    if (w==0){
        float v = (lane<NPATH)? lf[lane] : -3.0e38f;
        float m = v;
        #pragma unroll
        for (int d=1; d<64; d<<=1) m = fmaxf(m, __shfl_xor(m, d));
        float e = (lane<NPATH)? expf(v-m) : 0.f;
        #pragma unroll
        for (int d=1; d<64; d<<=1) e += __shfl_xor(e, d);
        int idx = (lane<NPATH && v==m)? lane : (1<<30);
        #pragma unroll
        for (int d=1; d<64; d<<=1) idx = min(idx, __shfl_xor(idx, d));
        if (lane==0){ sel[0]=idx; scal[0] = -logf(e); }
    }
    __syncthreads();
    int pstar = sel[0];
    if (w < NM){
        float part = 0.f;
        #pragma unroll
        for (int c=lane;c<HD;c+=64) part += z[pstar][c]*W_mod[c*NM + w];
        if (lane<3) part += pfeat[pstar*3+lane]*W_mod[(HD+lane)*NM + w];
        #pragma unroll
        for (int d=1; d<64; d<<=1) part += __shfl_xor(part, d);
        if (lane==0) red[w] = (mmask[pstar*NM + w]==0)? NEGV : part + b_mod[w];
    } else if (w == 7){
        float part = gsum[lane]*W_val[lane] + gsum[lane+64]*W_val[lane+64];
        #pragma unroll
        for (int d=1; d<64; d<<=1) part += __shfl_xor(part, d);
        if (lane==0) scal[2] = part/(float)NN + b_val[0];
    }
    __syncthreads();
    if (w==0){
        float v = (lane<NM)? red[lane] : -3.0e38f;
        float m = v;
        #pragma unroll
        for (int d=1; d<64; d<<=1) m = fmaxf(m, __shfl_xor(m, d));
        float e = (lane<NM)? expf(v-m) : 0.f;
        #pragma unroll
        for (int d=1; d<64; d<<=1) e += __shfl_xor(e, d);
        int idx = (lane<NM && v==m)? lane : (1<<30);
        #pragma unroll
        for (int d=1; d<64; d<<=1) idx = min(idx, __shfl_xor(idx, d));
        if (lane==0){ sel[1]=idx; scal[1] = -logf(e); }
    }
    __syncthreads();
    int mstar = sel[1];
    if (tid < NS) spec[tid] = pspec[pstar*NS + tid];
    __syncthreads();
    float v = -3.0e38f;
    if (tid < NS){
        float acc = c2b[0];
        #pragma unroll
        for (int ch=0; ch<8; ch++){
            float a = c1b[ch];
            #pragma unroll
            for (int k=0;k<5;k++){
                int ss = tid + k - 2;
                if (ss>=0 && ss<NS) a += spec[ss]*c1w[ch*5+k];
            }
            a = fmaxf(a, 0.f);
            acc += a*c2w[ch];
        }
        v = (smask[pstar*NM*NS + mstar*NS + tid]==0) ? NEGV : acc;
    }
    float m = v;
    #pragma unroll
    for (int d=1; d<64; d<<=1) m = fmaxf(m, __shfl_xor(m, d));
    if (lane==0) red[w] = m;
    __syncthreads();
    if (tid==0){
        float mm = red[0];
        #pragma unroll
        for (int i=1;i<8;i++) mm = fmaxf(mm, red[i]);
        maxsh = mm; sel[2] = 1<<30;
    }
    __syncthreads();
    float M2 = maxsh;
    if (tid<NS && v==M2) atomicMin(&sel[2], tid);
    float e = (tid<NS)? expf(v-M2) : 0.f;
    #pragma unroll
    for (int d=1; d<64; d<<=1) e += __shfl_xor(e, d);
    if (lane==0) red[w] = e;
    __syncthreads();
    if (tid==0){
        float se = 0.f;
        #pragma unroll
        for (int i=0;i<8;i++) se += red[i];
        out[0] = (float)pstar;
        out[1] = (float)sel[2];
        out[2] = (float)mstar;
        out[3] = scal[0] + scal[1] - logf(se);
        out[4] = scal[2];
    }
}

extern "C" void kernel_launch(void* const* d_in, const int* in_sizes, int n_in,
                              void* d_out, int out_size, void* d_ws, size_t ws_size,
                              hipStream_t stream) {
    (void)in_sizes; (void)n_in; (void)out_size; (void)ws_size;
    const float* node_feat     = (const float*)d_in[0];
    const float* edge_feat     = (const float*)d_in[1];
    const int*   edge_index    = (const int*)d_in[2];
    const int*   paths         = (const int*)d_in[3];
    const int*   path_mask     = (const int*)d_in[4];
    const float* path_features = (const float*)d_in[5];
    const int*   mod_masks     = (const int*)d_in[6];
    const int*   spec_masks    = (const int*)d_in[7];
    const float* path_spectrum = (const float*)d_in[8];
    const float* W_np  = (const float*)d_in[9];
    const float* b_np  = (const float*)d_in[10];
    const float* W_ep  = (const float*)d_in[11];
    const float* b_ep  = (const float*)d_in[12];
    const float* W_msg = (const float*)d_in[13];
    const float* b_msg = (const float*)d_in[14];
    const float* W_ih  = (const float*)d_in[15];
    const float* b_ih  = (const float*)d_in[16];
    const float* W_hh  = (const float*)d_in[17];
    const float* b_hh  = (const float*)d_in[18];
    const float* W_path = (const float*)d_in[19];
    const float* b_path = (const float*)d_in[20];
    const float* W_mod  = (const float*)d_in[21];
    const float* b_mod  = (const float*)d_in[22];
    const float* c1w = (const float*)d_in[23];
    const float* c1b = (const float*)d_in[24];
    const float* c2w = (const float*)d_in[25];
    const float* c2b = (const float*)d_in[26];
    const float* W_val = (const float*)d_in[27];
    const float* b_val = (const float*)d_in[28];

    char* ws = (char*)d_ws;
    size_t off = 0;
    auto alloc = [&](size_t bytes)->char*{
        char* p = ws + off;
        off += (bytes + 255) & ~(size_t)255;
        return p;
    };
    int*    deg     = (int*)alloc((size_t)NN*4);
    int*    offs    = (int*)alloc((size_t)(NN+1)*4);
    int*    bsum    = (int*)alloc((size_t)NB*4);
    int*    Cmat    = (int*)alloc((size_t)NBLK*NBKT*4);
    int2*   bkt2    = (int2*)alloc((size_t)NE*8);
    int2*   csr2    = (int2*)alloc((size_t)NE*8);
    float*  ef_sum  = (float*)alloc((size_t)NN*FD*4);
    float*  nf_sum  = (float*)alloc((size_t)NN*FD*4);
    float*  Wf      = (float*)alloc((size_t)FD*HD*4);
    float*  bfv     = (float*)alloc((size_t)HD*4);
    ushort* W2T     = (ushort*)alloc((size_t)512*AK*2);
    float*  Wt32    = (float*)alloc((size_t)512*HD*4);
    ushort* W1T     = (ushort*)alloc((size_t)512*AK1*2);
    ushort* A       = (ushort*)alloc((size_t)NN*AK*2);
    ushort* A1p     = (ushort*)alloc((size_t)NN*AK1*2);
    ushort* G       = (ushort*)alloc((size_t)NN*512*2);
    float*  partial = (float*)alloc((size_t)NSB*HD*4);
    float*  gsum    = (float*)alloc((size_t)HD*4);

    hipMemsetAsync(deg, 0, (size_t)NN*4, stream);

    k_deg<<<(NE+255)/256, 256, 0, stream>>>(edge_index, deg);
    k_scan1<<<NB, 256, 0, stream>>>(deg, offs, bsum);
    k_scan2<<<1, 256, 0, stream>>>(bsum, offs);
    k_scan3<<<NB, 256, 0, stream>>>(bsum, offs);
    k_hist<<<NBLK, 256, 0, stream>>>(edge_index, Cmat);
    k_cscan<<<(NBKT+3)/4, 256, 0, stream>>>(Cmat, offs);
    k_scatA<<<NBLK, 256, 0, stream>>>(edge_index, Cmat, bkt2);
    k_scatB<<<NBKT, 256, 0, stream>>>(edge_index, bkt2, offs, csr2);
    k_gat16<<<NN/4, 256, 0, stream>>>(csr2, edge_feat, node_feat, offs, ef_sum, nf_sum);
    k_folds<<<9, 256, 0, stream>>>(W_ep, b_ep, W_msg, b_msg, Wf, bfv);
    k_wprep2<<<512, AK, 0, stream>>>(W_ih, W_hh, W_msg, Wf, bfv, b_ih, b_hh, W2T, Wt32);
    k_wprep1<<<512, AK1, 0, stream>>>(W_np, b_np, W_hh, Wt32, W2T, W1T);
    k_prep2<<<NN*32/256, 256, 0, stream>>>(node_feat, nf_sum, ef_sum, deg, A1p, A);

    const int MB = (NN+127)/128;   // 391
    // iter 1: A1prep (K=64) -> G -> A.h (h0 inline)
    k_gemmG<true><<<dim3(4,MB), 256, 0, stream>>>(A1p, W1T, G);
    k_gruep1<<<NN*64/256, 256, 0, stream>>>(G, node_feat, W_np, b_np, A);
    // iter 2: gather -> G -> A.h (in place)
    k_gather<<<NN/4, 256, 0, stream>>>(A, offs, csr2);
    k_gemmG<false><<<dim3(4,MB), 256, 0, stream>>>(A, W2T, G);
    k_gruep<<<NN*64/256, 256, 0, stream>>>(G, A);
    // iter 3
    k_gather<<<NN/4, 256, 0, stream>>>(A, offs, csr2);
    k_gemmG<false><<<dim3(4,MB), 256, 0, stream>>>(A, W2T, G);
    k_gruep<<<NN*64/256, 256, 0, stream>>>(G, A);

    k_sum1<<<NSB, 256, 0, stream>>>(A, partial);
    k_sum2<<<HD, 256, 0, stream>>>(partial, gsum);
    k_small<<<1, 512, 0, stream>>>(edge_feat, paths, path_mask, path_features,
                                   mod_masks, spec_masks, path_spectrum,
                                   W_ep, b_ep, W_path, b_path, W_mod, b_mod,
                                   c1w, c1b, c2w, c2b, W_val, b_val,
                                   gsum, (float*)d_out);
}

// Round 11
// 338.195 us; speedup vs baseline: 1.5066x; 1.0845x over previous
//
#include <hip/hip_runtime.h>
#include <math.h>

#define NN 50000
#define NE 800000
#define HD 128
#define FD 16
#define NPATH 16
#define PL 8
#define NM 6
#define NS 320
#define NB 196    // ceil(NN/256)
#define NSB 782   // ceil(NN/64)
#define AK 320    // K for iters 2-3 GEMM (hsum128 | h128 | ef16 | deg | 1 | pad)
#define AKU 160   // uints per A row
#define AK1 64    // K for iter-1 GEMM (nf16 | nfsum16 | ef16 | deg | 1 | pad)
#define EPB 2048  // edges per histogram/scatter block
#define NBLK 391  // ceil(NE/EPB)
#define NBKT 196  // buckets = dst>>8
#define NEGV -1000000000.0f

typedef unsigned int uint;
typedef unsigned short ushort;
typedef short bf16x8 __attribute__((ext_vector_type(8)));
typedef float f32x4 __attribute__((ext_vector_type(4)));

__device__ __forceinline__ float sigm(float x){ return 1.0f/(1.0f+expf(-x)); }

__device__ __forceinline__ ushort f2b(float f){
    union{float f; uint u;} v; v.f=f;
    uint r = v.u + 0x7FFFu + ((v.u>>16)&1u);
    return (ushort)(r>>16);
}
__device__ __forceinline__ float b2f(ushort s){
    union{uint u; float f;} v; v.u = ((uint)s)<<16; return v.f;
}
__device__ __forceinline__ float blo(uint v){ return b2f((ushort)(v&0xFFFF)); }
__device__ __forceinline__ float bhi(uint v){ return b2f((ushort)(v>>16)); }
__device__ __forceinline__ uint pack2(float a, float b){ return (uint)f2b(a) | (((uint)f2b(b))<<16); }

// ---- degree histogram ----
__global__ void k_deg(const int* __restrict__ ei, int* __restrict__ deg){
    int e = blockIdx.x*256 + threadIdx.x;
    if (e >= NE) return;
    atomicAdd(&deg[ei[NE + e]], 1);
}

// ---- hierarchical exclusive scan over deg -> offs ----
__global__ void k_scan1(const int* __restrict__ deg, int* __restrict__ offs, int* __restrict__ bsum){
    int tid = threadIdx.x, bid = blockIdx.x;
    int idx = bid*256 + tid;
    int v = (idx<NN) ? deg[idx] : 0;
    int lane = tid&63, w = tid>>6;
    int x = v;
    #pragma unroll
    for (int d=1; d<64; d<<=1){ int y = __shfl_up(x,d); if (lane>=d) x += y; }
    __shared__ int wsum[4];
    if (lane==63) wsum[w] = x;
    __syncthreads();
    int base = 0;
    #pragma unroll
    for (int j=0;j<4;j++) if (j<w) base += wsum[j];
    if (idx<NN) offs[idx] = base + x - v;
    if (tid==255) bsum[bid] = base + x;
}
__global__ void k_scan2(int* __restrict__ bsum, int* __restrict__ offs){
    int tid = threadIdx.x;
    int v = (tid<NB) ? bsum[tid] : 0;
    int lane = tid&63, w = tid>>6;
    int x = v;
    #pragma unroll
    for (int d=1; d<64; d<<=1){ int y = __shfl_up(x,d); if (lane>=d) x += y; }
    __shared__ int wsum[4];
    if (lane==63) wsum[w] = x;
    __syncthreads();
    int base = 0;
    #pragma unroll
    for (int j=0;j<4;j++) if (j<w) base += wsum[j];
    if (tid<NB) bsum[tid] = base + x - v;
    if (tid==255) offs[NN] = base + x;
}
__global__ void k_scan3(const int* __restrict__ bsum, int* __restrict__ offs){
    int idx = blockIdx.x*256 + threadIdx.x;
    if (idx>=NN) return;
    offs[idx] += bsum[blockIdx.x];
}

// ---- counting sort phase 1: per-block bucket histogram ----
__global__ void k_hist(const int* __restrict__ ei, int* __restrict__ C){
    __shared__ int h[NBKT];
    int tid = threadIdx.x, blk = blockIdx.x;
    if (tid < NBKT) h[tid] = 0;
    __syncthreads();
    int e0 = blk*EPB;
    for (int i=tid; i<EPB; i+=256){
        int e = e0+i;
        if (e < NE) atomicAdd(&h[ei[NE+e]>>8], 1);
    }
    __syncthreads();
    if (tid < NBKT) C[blk*NBKT + tid] = h[tid];
}

// ---- phase 2: column-wise exclusive scan of C + bucket base from offs ----
__global__ void k_cscan(int* __restrict__ C, const int* __restrict__ offs){
    int b = blockIdx.x*4 + (threadIdx.x>>6);
    int lane = threadIdx.x & 63;
    if (b >= NBKT) return;
    int base = offs[b<<8];
    int carry = 0;
    for (int c=0; c<7; ++c){
        int i = c*64 + lane;
        int v = (i<NBLK)? C[i*NBKT + b] : 0;
        int x = v;
        #pragma unroll
        for (int d=1; d<64; d<<=1){ int y = __shfl_up(x,d); if (lane>=d) x += y; }
        if (i<NBLK) C[i*NBKT + b] = base + carry + (x - v);
        carry += __shfl(x, 63);
    }
}

// ---- phase 3: scatter edges into bucket-ordered array (sequential streams) ----
__global__ void k_scatA(const int* __restrict__ ei, const int* __restrict__ C,
                        int2* __restrict__ bkt2){
    __shared__ int cur[NBKT];
    __shared__ int cbase[NBKT];
    int tid = threadIdx.x, blk = blockIdx.x;
    if (tid < NBKT){ cur[tid] = 0; cbase[tid] = C[blk*NBKT + tid]; }
    __syncthreads();
    int e0 = blk*EPB;
    for (int i=tid; i<EPB; i+=256){
        int e = e0+i;
        if (e >= NE) break;
        int dst = ei[NE+e];
        int bkt = dst>>8;
        int r = atomicAdd(&cur[bkt], 1);
        bkt2[cbase[bkt] + r] = make_int2(dst, e);
    }
}

// ---- phase 4: per-bucket exact per-dst placement (single-CU 32KB window) ----
__global__ void k_scatB(const int* __restrict__ ei, const int2* __restrict__ bkt2,
                        const int* __restrict__ offs, int2* __restrict__ csr2){
    __shared__ int cur[256];
    int b = blockIdx.x, tid = threadIdx.x;
    int d0 = b<<8;
    {
        int idx = d0 + tid;
        cur[tid] = (idx<NN)? offs[idx] : 0;
    }
    __syncthreads();
    int lo = offs[d0];
    int hi = (d0+256 <= NN)? offs[d0+256] : offs[NN];
    for (int i=lo+tid; i<hi; i+=256){
        int2 p = bkt2[i];
        int pos = atomicAdd(&cur[p.x & 255], 1);
        csr2[pos] = make_int2(ei[p.y], p.y);
    }
}

// ---- per-node 16-wide sums of edge_feat (by eid) and node_feat (by src) ----
__global__ void k_gat16(const int2* __restrict__ csr2,
                        const float* __restrict__ edge_feat, const float* __restrict__ nf,
                        const int* __restrict__ offs,
                        float* __restrict__ ef_sum, float* __restrict__ nf_sum){
    int node = blockIdx.x*4 + (threadIdx.x>>6);
    int lane = threadIdx.x & 63;
    int k = lane & 15, sub = lane >> 4;
    int b = offs[node], e2 = offs[node+1];
    float ae = 0.f, an = 0.f;
    int i = b + sub;
    for (; i + 4 < e2; i += 8){
        int2 p0 = csr2[i], p1 = csr2[i+4];
        float f0 = edge_feat[(size_t)p0.y*FD + k];
        float g0 = nf[(size_t)p0.x*FD + k];
        float f1 = edge_feat[(size_t)p1.y*FD + k];
        float g1 = nf[(size_t)p1.x*FD + k];
        ae += f0 + f1; an += g0 + g1;
    }
    if (i < e2){
        int2 p0 = csr2[i];
        ae += edge_feat[(size_t)p0.y*FD + k];
        an += nf[(size_t)p0.x*FD + k];
    }
    ae += __shfl_xor(ae, 16); ae += __shfl_xor(ae, 32);
    an += __shfl_xor(an, 16); an += __shfl_xor(an, 32);
    if (sub == 0){ ef_sum[node*FD + k] = ae; nf_sum[node*FD + k] = an; }
}

// ---- Wf = W_ep@W_e ; bfv = b_ep@W_e + b_msg ----
__global__ void k_folds(const float* __restrict__ W_ep, const float* __restrict__ b_ep,
                        const float* __restrict__ W_msg, const float* __restrict__ b_msg,
                        float* __restrict__ Wf, float* __restrict__ bfv){
    int o = blockIdx.x*256 + threadIdx.x;
    if (o < FD*HD){
        int k=o>>7, c=o&127;
        float acc=0.f;
        for (int m=0;m<HD;m++) acc += W_ep[k*HD+m]*W_msg[(HD+m)*HD+c];
        Wf[o]=acc;
    } else if (o < FD*HD+HD){
        int c=o-FD*HD;
        float acc=b_msg[c];
        for (int m=0;m<HD;m++) acc += b_ep[m]*W_msg[(HD+m)*HD+c];
        bfv[c]=acc;
    }
}

// ---- build folded mega-weight W2T[512][320], col-INTERLEAVED gates: col = 4*j + g ----
// gates: 0=r, 1=z, 2=gi_n, 3=gh_n. Biases folded into k=273 (constant-1 column).
__global__ void k_wprep2(const float* __restrict__ W_ih, const float* __restrict__ W_hh,
                         const float* __restrict__ W_msg, const float* __restrict__ Wf,
                         const float* __restrict__ bfv,
                         const float* __restrict__ b_ih, const float* __restrict__ b_hh,
                         ushort* __restrict__ W2T, float* __restrict__ Wt32){
    int c = blockIdx.x;       // 0..511
    int k = threadIdx.x;      // 0..319
    int j = c>>2, g = c&3;
    float v = 0.f;
    if (k < 128){
        float acc = 0.f;
        if (g < 3){   // hsum path: (W_h @ W_ih_g^T)
            const float* wm = W_msg + (size_t)k*HD;
            const float* wi = W_ih + (size_t)(g*HD+j)*HD;
            for (int m=0;m<HD;m++) acc += wm[m]*wi[m];
        }
        Wt32[(size_t)c*HD + k] = acc;
        v = acc;
    } else if (k < 256){      // h path: W_hh gates (none for gi_n)
        int kk = k-128;
        if (g==0)      v = W_hh[(size_t)j*HD+kk];
        else if (g==1) v = W_hh[(size_t)(HD+j)*HD+kk];
        else if (g==3) v = W_hh[(size_t)(2*HD+j)*HD+kk];
    } else if (k < 272){      // ef_sum path
        if (g < 3){
            const float* wf = Wf + (size_t)(k-256)*HD;
            const float* wi = W_ih + (size_t)(g*HD+j)*HD;
            float acc=0.f;
            for (int m=0;m<HD;m++) acc += wf[m]*wi[m];
            v = acc;
        }
    } else if (k == 272){     // deg path
        if (g < 3){
            const float* wi = W_ih + (size_t)(g*HD+j)*HD;
            float acc=0.f;
            for (int m=0;m<HD;m++) acc += bfv[m]*wi[m];
            v = acc;
        }
    } else if (k == 273){     // constant-1: biases
        v = (g==0)? b_ih[j]+b_hh[j] : (g==1)? b_ih[HD+j]+b_hh[HD+j]
          : (g==2)? b_ih[2*HD+j] : b_hh[2*HD+j];
    }
    W2T[(size_t)c*AK + k] = f2b(v);
}

// ---- iter-1 weight W1T[512][64]: cols [nf16|nfsum16|ef16|deg|1|pad], W_np folded in ----
__global__ void k_wprep1(const float* __restrict__ W_np, const float* __restrict__ b_np,
                         const float* __restrict__ W_hh, const float* __restrict__ Wt32,
                         const ushort* __restrict__ W2T, ushort* __restrict__ W1T){
    int c = blockIdx.x;       // 0..511
    int k = threadIdx.x;      // 0..63
    int j = c>>2, g = c&3;
    float v = 0.f;
    if (k < 16){              // nf path: W_np @ W_hh_g^T  (g2 has no h-term)
        if (g != 2){
            int gp = (g==3)? 2 : g;
            const float* wh = W_hh + (size_t)(gp*HD + j)*HD;
            const float* wn = W_np + (size_t)k*HD;
            float acc=0.f;
            for (int m=0;m<HD;m++) acc += wn[m]*wh[m];
            v = acc;
        }
    } else if (k < 32){       // nf_sum path: W_np @ t_c (t = W_h@W_ih_g^T, zero for g3)
        const float* wt = Wt32 + (size_t)c*HD;
        const float* wn = W_np + (size_t)(k-16)*HD;
        float acc=0.f;
        for (int m=0;m<HD;m++) acc += wn[m]*wt[m];
        v = acc;
    } else if (k < 48){       // ef_sum path: copy from W2T
        v = b2f(W2T[(size_t)c*AK + 256 + (k-32)]);
    } else if (k == 48){      // deg: b_np@t_c + old deg col
        float acc = b2f(W2T[(size_t)c*AK + 272]);
        const float* wt = Wt32 + (size_t)c*HD;
        for (int m=0;m<HD;m++) acc += b_np[m]*wt[m];
        v = acc;
    } else if (k == 49){      // const-1: old biases + b_np@W_hh_g^T (h0's bias part)
        float acc = b2f(W2T[(size_t)c*AK + 273]);
        if (g != 2){
            int gp = (g==3)? 2 : g;
            const float* wh = W_hh + (size_t)(gp*HD + j)*HD;
            for (int m=0;m<HD;m++) acc += b_np[m]*wh[m];
        }
        v = acc;
    }
    W1T[(size_t)c*AK1 + k] = f2b(v);
}

// ---- light prep: A1prep[NN][64] = [nf|nfsum|ef|deg|1|0], statics into A ----
__global__ void k_prep2(const float* __restrict__ nf, const float* __restrict__ nf_sum,
                        const float* __restrict__ ef_sum, const int* __restrict__ deg,
                        ushort* __restrict__ A1p, ushort* __restrict__ A){
    int idx = blockIdx.x*256 + threadIdx.x;   // NN*32
    int n = idx>>5, c2 = idx&31;
    int k = c2*2, k1 = k+1;
    float d = (float)deg[n];
    float v0 = (k<16)? nf[n*FD+k] : (k<32)? nf_sum[n*FD+k-16] : (k<48)? ef_sum[n*FD+k-32]
             : (k==48)? d : 0.f;
    float v1 = (k1<16)? nf[n*FD+k1] : (k1<32)? nf_sum[n*FD+k1-16] : (k1<48)? ef_sum[n*FD+k1-32]
             : (k1==49)? 1.f : 0.f;
    ((uint*)A1p)[(size_t)n*32 + c2] = pack2(v0,v1);
    int col = 256 + k;
    float s0 = (col<272)? ef_sum[n*FD + col-256] : (col==272)? d : 0.f;
    float s1 = (col+1<272)? ef_sum[n*FD + col+1-256] : (col+1==273)? 1.f : 0.f;
    ((uint*)A)[(size_t)n*AKU + 128 + c2] = pack2(s0,s1);
}

// ---- fused GEMM + GRU epilogue (interleaved gates col=4j+g) -> in-place h in A ----
// IT1: Asrc=A1p (K=64, 1 step), h_old computed inline from nf. Else: Asrc=A (K=320, 5 steps).
template<bool IT1>
__global__ __launch_bounds__(256) void k_fused(const ushort* __restrict__ Asrc,
                                               const ushort* __restrict__ Bt,
                                               const float* __restrict__ nf,
                                               const float* __restrict__ W_np,
                                               const float* __restrict__ b_np,
                                               ushort* __restrict__ Ah){
    __shared__ __align__(16) short LDS[128*128];   // 32KB: As[0:8192) Bs[8192:16384); epilogue: gate tile
    __shared__ float Wnp_s[FD][32];                // 2KB, iter-1 only
    short* As = LDS;
    short* Bs = LDS + 128*64;
    const int tid = threadIdx.x;
    const int lane = tid & 63, w = tid>>6;
    const int wm = w>>1, wn = w&1;
    const int n0 = blockIdx.x*128, m0 = blockIdx.y*128;
    const int jbase = n0>>2;                       // 32 j-cols per block
    const int AKA = IT1 ? AK1 : AK;
    if (IT1){
        for (int i=tid; i<FD*32; i+=256){
            int kk=i>>5, jj=i&31;
            Wnp_s[kk][jj] = W_np[kk*HD + jbase + jj];
        }
    }
    f32x4 acc[4][4] = {};
    const int nsteps = IT1 ? 1 : 5;
    for (int kk=0; kk<nsteps; ++kk){
        __syncthreads();
        #pragma unroll
        for (int i=0;i<4;i++){
            int id = tid + i*256;
            int row = id>>3, s = id&7;
            int phys = row*64 + ((s ^ (row&7))<<3);
            int ar = m0 + row; if (ar >= NN) ar = NN-1;
            *(int4*)&As[phys] = *(const int4*)(Asrc + (size_t)ar*AKA + kk*64 + s*8);
            *(int4*)&Bs[phys] = *(const int4*)(Bt + (size_t)(n0+row)*AKA + kk*64 + s*8);
        }
        __syncthreads();
        #pragma unroll
        for (int ksel=0; ksel<2; ++ksel){
            bf16x8 af[4], bfr[4];
            #pragma unroll
            for (int t=0;t<4;t++){
                int arow = wm*64 + t*16 + (lane&15);
                int aslot = (ksel*4 + (lane>>4)) ^ (arow&7);
                af[t] = *(const bf16x8*)&As[arow*64 + aslot*8];
                int brow = wn*64 + t*16 + (lane&15);
                int bslot = (ksel*4 + (lane>>4)) ^ (brow&7);
                bfr[t] = *(const bf16x8*)&Bs[brow*64 + bslot*8];
            }
            #pragma unroll
            for (int mi=0;mi<4;mi++)
                #pragma unroll
                for (int ni=0;ni<4;ni++)
                    acc[mi][ni] = __builtin_amdgcn_mfma_f32_16x16x32_bf16(af[mi], bfr[ni], acc[mi][ni], 0,0,0);
        }
    }
    // dump gate tile to LDS (bf16), XOR swizzle at 8B (gate-quad) granularity
    __syncthreads();
    #pragma unroll
    for (int mi=0;mi<4;mi++){
        #pragma unroll
        for (int ni=0;ni<4;ni++){
            #pragma unroll
            for (int r=0;r<4;r++){
                int row = wm*64 + mi*16 + (lane>>4)*4 + r;
                int col = wn*64 + ni*16 + (lane&15);
                int pc = (col&3) | (((col>>2) ^ (row&7))<<2);
                LDS[row*128 + pc] = (short)f2b(acc[mi][ni][r]);
            }
        }
    }
    __syncthreads();
    // epilogue: thread -> (jp = tid&15 [j-pair], rg = tid>>4 [8 rows each])
    {
        int jp = tid&15, rg = tid>>4;
        int jg = jbase + jp*2;                      // global j of first of pair
        #pragma unroll
        for (int rr=0; rr<8; ++rr){
            int row = rg*8 + rr;
            int n = m0 + row;
            if (n >= NN) continue;
            uint2 g0 = *(const uint2*)&LDS[row*128 + (((jp*2)   ^ (row&7))<<2)];
            uint2 g1 = *(const uint2*)&LDS[row*128 + (((jp*2+1) ^ (row&7))<<2)];
            float ha, hb;
            if constexpr (IT1){
                const float* x = nf + (size_t)n*FD;
                float a = b_np[jg], b = b_np[jg+1];
                #pragma unroll
                for (int k=0;k<FD;k++){
                    float xv = x[k];
                    a += xv*Wnp_s[k][jp*2];
                    b += xv*Wnp_s[k][jp*2+1];
                }
                ha = a; hb = b;
            } else {
                uint vh = ((const uint*)Ah)[(size_t)n*AKU + 64 + (n0>>3) + jp];
                ha = blo(vh); hb = bhi(vh);
            }
            float r0 = sigm(blo(g0.x)), z0 = sigm(bhi(g0.x));
            float nn0 = tanhf(blo(g0.y) + r0*bhi(g0.y));
            float r1 = sigm(blo(g1.x)), z1 = sigm(bhi(g1.x));
            float nn1 = tanhf(blo(g1.y) + r1*bhi(g1.y));
            float h0 = (1.f-z0)*nn0 + z0*ha;
            float h1 = (1.f-z1)*nn1 + z1*hb;
            ((uint*)Ah)[(size_t)n*AKU + 64 + (n0>>3) + jp] = pack2(h0,h1);
        }
    }
}

// ---- hsum[n] = sum over in-edges of h[src] (within same A buffer) ----
__global__ void k_gather(ushort* __restrict__ A, const int* __restrict__ offs,
                         const int2* __restrict__ csr2){
    int node = blockIdx.x*4 + (threadIdx.x>>6);
    int c2 = threadIdx.x & 63;
    int b = offs[node], e2 = offs[node+1];
    float a0 = 0.f, a1 = 0.f;
    const uint* hp = (const uint*)A;
    int i = b;
    for (; i + 8 <= e2; i += 8){
        int s0=csr2[i].x,  s1=csr2[i+1].x, s2=csr2[i+2].x, s3=csr2[i+3].x;
        int s4=csr2[i+4].x,s5=csr2[i+5].x, s6=csr2[i+6].x, s7=csr2[i+7].x;
        uint v0=hp[(size_t)s0*AKU+64+c2], v1=hp[(size_t)s1*AKU+64+c2],
             v2=hp[(size_t)s2*AKU+64+c2], v3=hp[(size_t)s3*AKU+64+c2],
             v4=hp[(size_t)s4*AKU+64+c2], v5=hp[(size_t)s5*AKU+64+c2],
             v6=hp[(size_t)s6*AKU+64+c2], v7=hp[(size_t)s7*AKU+64+c2];
        a0 += blo(v0)+blo(v1)+blo(v2)+blo(v3)+blo(v4)+blo(v5)+blo(v6)+blo(v7);
        a1 += bhi(v0)+bhi(v1)+bhi(v2)+bhi(v3)+bhi(v4)+bhi(v5)+bhi(v6)+bhi(v7);
    }
    if (i + 4 <= e2){
        int s0=csr2[i].x,s1=csr2[i+1].x,s2=csr2[i+2].x,s3=csr2[i+3].x;
        uint v0=hp[(size_t)s0*AKU+64+c2], v1=hp[(size_t)s1*AKU+64+c2],
             v2=hp[(size_t)s2*AKU+64+c2], v3=hp[(size_t)s3*AKU+64+c2];
        a0 += blo(v0)+blo(v1)+blo(v2)+blo(v3);
        a1 += bhi(v0)+bhi(v1)+bhi(v2)+bhi(v3);
        i += 4;
    }
    for (; i < e2; ++i){
        uint v = hp[(size_t)csr2[i].x*AKU+64+c2];
        a0 += blo(v); a1 += bhi(v);
    }
    ((uint*)A)[(size_t)node*AKU + c2] = pack2(a0,a1);
}

// ---- two-stage column sum of final h ----
__global__ void k_sum1(const ushort* __restrict__ A, float* __restrict__ partial){
    int bid = blockIdx.x, tid = threadIdx.x;
    int lane = tid&63, w2 = tid>>6;
    int nb = bid*64;
    float a0=0.f, a1=0.f;
    const uint* hp = (const uint*)A;
    #pragma unroll
    for (int r=w2; r<64; r+=4){
        int n = nb + r;
        if (n < NN){
            uint v = hp[(size_t)n*AKU + 64 + lane];
            a0 += blo(v); a1 += bhi(v);
        }
    }
    __shared__ float s0[4][64], s1[4][64];
    s0[w2][lane]=a0; s1[w2][lane]=a1;
    __syncthreads();
    if (w2==0){
        a0 = s0[0][lane]+s0[1][lane]+s0[2][lane]+s0[3][lane];
        a1 = s1[0][lane]+s1[1][lane]+s1[2][lane]+s1[3][lane];
        ((float2*)partial)[(size_t)bid*64 + lane] = make_float2(a0,a1);
    }
}
__global__ void k_sum2(const float* __restrict__ partial, float* __restrict__ gsum){
    int c = blockIdx.x;          // 0..127
    int tid = threadIdx.x;       // 256
    int lane = tid&63, w = tid>>6;
    float a = 0.f;
    for (int b=tid; b<NSB; b+=256) a += partial[(size_t)b*128 + c];
    #pragma unroll
    for (int d=1; d<64; d<<=1) a += __shfl_xor(a, d);
    __shared__ float sh[4];
    if (lane==0) sh[w]=a;
    __syncthreads();
    if (tid==0) gsum[c] = sh[0]+sh[1]+sh[2]+sh[3];
}

// ---- tiny agents + value head, LDS-staged z + wave-parallel reductions ----
__global__ void k_small(const float* __restrict__ ef, const int* __restrict__ paths,
                        const int* __restrict__ pmask, const float* __restrict__ pfeat,
                        const int* __restrict__ mmask, const int* __restrict__ smask,
                        const float* __restrict__ pspec,
                        const float* __restrict__ W_ep, const float* __restrict__ b_ep,
                        const float* __restrict__ W_path, const float* __restrict__ b_path,
                        const float* __restrict__ W_mod, const float* __restrict__ b_mod,
                        const float* __restrict__ c1w, const float* __restrict__ c1b,
                        const float* __restrict__ c2w, const float* __restrict__ c2b,
                        const float* __restrict__ W_val, const float* __restrict__ b_val,
                        const float* __restrict__ gsum, float* __restrict__ out){
    __shared__ float Wep_s[FD][HD];   // 8KB
    __shared__ float esum[NPATH][FD]; // 1KB
    __shared__ float z[NPATH][HD];
    __shared__ float lf[NS];
    __shared__ float spec[NS];
    __shared__ float red[8];
    __shared__ float scal[3];
    __shared__ int   sel[3];
    __shared__ float maxsh;
    int tid = threadIdx.x, lane = tid&63, w = tid>>6;

    for (int i=tid; i<FD*HD; i+=512) Wep_s[i>>7][i&127] = W_ep[i];
    if (tid < NPATH*FD){
        int p = tid>>4, k = tid&15;
        float a = 0.f;
        #pragma unroll
        for (int l=0;l<PL;l++){
            int eid = paths[p*PL + l];
            a += ef[(size_t)eid*FD + k];
        }
        esum[p][k] = a*0.125f;
    }
    __syncthreads();
    #pragma unroll
    for (int i=tid; i<NPATH*HD; i+=512){
        int p = i>>7, c = i&127;
        float a = b_ep[c];
        #pragma unroll
        for (int k=0;k<FD;k++) a += esum[p][k]*Wep_s[k][c];
        z[p][c] = a;
    }
    __syncthreads();
    { // logits_p
        int p = tid>>5, sub = tid&31;
        float part = 0.f;
        #pragma unroll
        for (int c=sub;c<HD;c+=32) part += z[p][c]*W_path[c];
        #pragma unroll
        for (int d=16; d>=1; d>>=1) part += __shfl_xor(part, d);
        if (sub==0) lf[p] = (pmask[p]==0)? NEGV : part + b_path[0];
    }
    __syncthreads();
    if (w==0){
        float v = (lane<NPATH)? lf[lane] : -3.0e38f;
        float m = v;
        #pragma unroll
        for (int d=1; d<64; d<<=1) m = fmaxf(m, __shfl_xor(m, d));
        float e = (lane<NPATH)? expf(v-m) : 0.f;
        #pragma unroll
        for (int d=1; d<64; d<<=1) e += __shfl_xor(e, d);
        int idx = (lane<NPATH && v==m)? lane : (1<<30);
        #pragma unroll
        for (int d=1; d<64; d<<=1) idx = min(idx, __shfl_xor(idx, d));
        if (lane==0){ sel[0]=idx; scal[0] = -logf(e); }
    }
    __syncthreads();
    int pstar = sel[0];
    if (w < NM){
        float part = 0.f;
        #pragma unroll
        for (int c=lane;c<HD;c+=64) part += z[pstar][c]*W_mod[c*NM + w];
        if (lane<3) part += pfeat[pstar*3+lane]*W_mod[(HD+lane)*NM + w];
        #pragma unroll
        for (int d=1; d<64; d<<=1) part += __shfl_xor(part, d);
        if (lane==0) red[w] = (mmask[pstar*NM + w]==0)? NEGV : part + b_mod[w];
    } else if (w == 7){
        float part = gsum[lane]*W_val[lane] + gsum[lane+64]*W_val[lane+64];
        #pragma unroll
        for (int d=1; d<64; d<<=1) part += __shfl_xor(part, d);
        if (lane==0) scal[2] = part/(float)NN + b_val[0];
    }
    __syncthreads();
    if (w==0){
        float v = (lane<NM)? red[lane] : -3.0e38f;
        float m = v;
        #pragma unroll
        for (int d=1; d<64; d<<=1) m = fmaxf(m, __shfl_xor(m, d));
        float e = (lane<NM)? expf(v-m) : 0.f;
        #pragma unroll
        for (int d=1; d<64; d<<=1) e += __shfl_xor(e, d);
        int idx = (lane<NM && v==m)? lane : (1<<30);
        #pragma unroll
        for (int d=1; d<64; d<<=1) idx = min(idx, __shfl_xor(idx, d));
        if (lane==0){ sel[1]=idx; scal[1] = -logf(e); }
    }
    __syncthreads();
    int mstar = sel[1];
    if (tid < NS) spec[tid] = pspec[pstar*NS + tid];
    __syncthreads();
    float v = -3.0e38f;
    if (tid < NS){
        float acc = c2b[0];
        #pragma unroll
        for (int ch=0; ch<8; ch++){
            float a = c1b[ch];
            #pragma unroll
            for (int k=0;k<5;k++){
                int ss = tid + k - 2;
                if (ss>=0 && ss<NS) a += spec[ss]*c1w[ch*5+k];
            }
            a = fmaxf(a, 0.f);
            acc += a*c2w[ch];
        }
        v = (smask[pstar*NM*NS + mstar*NS + tid]==0) ? NEGV : acc;
    }
    float m = v;
    #pragma unroll
    for (int d=1; d<64; d<<=1) m = fmaxf(m, __shfl_xor(m, d));
    if (lane==0) red[w] = m;
    __syncthreads();
    if (tid==0){
        float mm = red[0];
        #pragma unroll
        for (int i=1;i<8;i++) mm = fmaxf(mm, red[i]);
        maxsh = mm; sel[2] = 1<<30;
    }
    __syncthreads();
    float M2 = maxsh;
    if (tid<NS && v==M2) atomicMin(&sel[2], tid);
    float e = (tid<NS)? expf(v-M2) : 0.f;
    #pragma unroll
    for (int d=1; d<64; d<<=1) e += __shfl_xor(e, d);
    if (lane==0) red[w] = e;
    __syncthreads();
    if (tid==0){
        float se = 0.f;
        #pragma unroll
        for (int i=0;i<8;i++) se += red[i];
        out[0] = (float)pstar;
        out[1] = (float)sel[2];
        out[2] = (float)mstar;
        out[3] = scal[0] + scal[1] - logf(se);
        out[4] = scal[2];
    }
}

extern "C" void kernel_launch(void* const* d_in, const int* in_sizes, int n_in,
                              void* d_out, int out_size, void* d_ws, size_t ws_size,
                              hipStream_t stream) {
    (void)in_sizes; (void)n_in; (void)out_size; (void)ws_size;
    const float* node_feat     = (const float*)d_in[0];
    const float* edge_feat     = (const float*)d_in[1];
    const int*   edge_index    = (const int*)d_in[2];
    const int*   paths         = (const int*)d_in[3];
    const int*   path_mask     = (const int*)d_in[4];
    const float* path_features = (const float*)d_in[5];
    const int*   mod_masks     = (const int*)d_in[6];
    const int*   spec_masks    = (const int*)d_in[7];
    const float* path_spectrum = (const float*)d_in[8];
    const float* W_np  = (const float*)d_in[9];
    const float* b_np  = (const float*)d_in[10];
    const float* W_ep  = (const float*)d_in[11];
    const float* b_ep  = (const float*)d_in[12];
    const float* W_msg = (const float*)d_in[13];
    const float* b_msg = (const float*)d_in[14];
    const float* W_ih  = (const float*)d_in[15];
    const float* b_ih  = (const float*)d_in[16];
    const float* W_hh  = (const float*)d_in[17];
    const float* b_hh  = (const float*)d_in[18];
    const float* W_path = (const float*)d_in[19];
    const float* b_path = (const float*)d_in[20];
    const float* W_mod  = (const float*)d_in[21];
    const float* b_mod  = (const float*)d_in[22];
    const float* c1w = (const float*)d_in[23];
    const float* c1b = (const float*)d_in[24];
    const float* c2w = (const float*)d_in[25];
    const float* c2b = (const float*)d_in[26];
    const float* W_val = (const float*)d_in[27];
    const float* b_val = (const float*)d_in[28];

    char* ws = (char*)d_ws;
    size_t off = 0;
    auto alloc = [&](size_t bytes)->char*{
        char* p = ws + off;
        off += (bytes + 255) & ~(size_t)255;
        return p;
    };
    int*    deg     = (int*)alloc((size_t)NN*4);
    int*    offs    = (int*)alloc((size_t)(NN+1)*4);
    int*    bsum    = (int*)alloc((size_t)NB*4);
    int*    Cmat    = (int*)alloc((size_t)NBLK*NBKT*4);
    int2*   bkt2    = (int2*)alloc((size_t)NE*8);
    int2*   csr2    = (int2*)alloc((size_t)NE*8);
    float*  ef_sum  = (float*)alloc((size_t)NN*FD*4);
    float*  nf_sum  = (float*)alloc((size_t)NN*FD*4);
    float*  Wf      = (float*)alloc((size_t)FD*HD*4);
    float*  bfv     = (float*)alloc((size_t)HD*4);
    ushort* W2T     = (ushort*)alloc((size_t)512*AK*2);
    float*  Wt32    = (float*)alloc((size_t)512*HD*4);
    ushort* W1T     = (ushort*)alloc((size_t)512*AK1*2);
    ushort* A       = (ushort*)alloc((size_t)NN*AK*2);
    ushort* A1p     = (ushort*)alloc((size_t)NN*AK1*2);
    float*  partial = (float*)alloc((size_t)NSB*HD*4);
    float*  gsum    = (float*)alloc((size_t)HD*4);

    hipMemsetAsync(deg, 0, (size_t)NN*4, stream);

    k_deg<<<(NE+255)/256, 256, 0, stream>>>(edge_index, deg);
    k_scan1<<<NB, 256, 0, stream>>>(deg, offs, bsum);
    k_scan2<<<1, 256, 0, stream>>>(bsum, offs);
    k_scan3<<<NB, 256, 0, stream>>>(bsum, offs);
    k_hist<<<NBLK, 256, 0, stream>>>(edge_index, Cmat);
    k_cscan<<<(NBKT+3)/4, 256, 0, stream>>>(Cmat, offs);
    k_scatA<<<NBLK, 256, 0, stream>>>(edge_index, Cmat, bkt2);
    k_scatB<<<NBKT, 256, 0, stream>>>(edge_index, bkt2, offs, csr2);
    k_gat16<<<NN/4, 256, 0, stream>>>(csr2, edge_feat, node_feat, offs, ef_sum, nf_sum);
    k_folds<<<9, 256, 0, stream>>>(W_ep, b_ep, W_msg, b_msg, Wf, bfv);
    k_wprep2<<<512, AK, 0, stream>>>(W_ih, W_hh, W_msg, Wf, bfv, b_ih, b_hh, W2T, Wt32);
    k_wprep1<<<512, AK1, 0, stream>>>(W_np, b_np, W_hh, Wt32, W2T, W1T);
    k_prep2<<<NN*32/256, 256, 0, stream>>>(node_feat, nf_sum, ef_sum, deg, A1p, A);

    const int MB = (NN+127)/128;   // 391
    // iter 1: A1p (K=64) -> fused GRU -> A.h  (h0 inline from nf)
    k_fused<true><<<dim3(4,MB), 256, 0, stream>>>(A1p, W1T, node_feat, W_np, b_np, A);
    // iter 2: gather -> fused -> A.h (in place)
    k_gather<<<NN/4, 256, 0, stream>>>(A, offs, csr2);
    k_fused<false><<<dim3(4,MB), 256, 0, stream>>>(A, W2T, node_feat, W_np, b_np, A);
    // iter 3
    k_gather<<<NN/4, 256, 0, stream>>>(A, offs, csr2);
    k_fused<false><<<dim3(4,MB), 256, 0, stream>>>(A, W2T, node_feat, W_np, b_np, A);

    k_sum1<<<NSB, 256, 0, stream>>>(A, partial);
    k_sum2<<<HD, 256, 0, stream>>>(partial, gsum);
    k_small<<<1, 512, 0, stream>>>(edge_feat, paths, path_mask, path_features,
                                   mod_masks, spec_masks, path_spectrum,
                                   W_ep, b_ep, W_path, b_path, W_mod, b_mod,
                                   c1w, c1b, c2w, c2b, W_val, b_val,
                                   gsum, (float*)d_out);
}

// Round 12
// 317.152 us; speedup vs baseline: 1.6065x; 1.0663x over previous
//
#include <hip/hip_runtime.h>
#include <math.h>

#define NN 50000
#define NE 800000
#define HD 128
#define FD 16
#define NPATH 16
#define PL 8
#define NM 6
#define NS 320
#define NB 196    // ceil(NN/256)
#define NSB 782   // ceil(NN/64)
#define AK 320    // K for iters 2-3 GEMM (hsum128 | h128 | ef16 | deg | 1 | pad)
#define AKU 160   // uints per A row
#define AK1 64    // K for iter-1 GEMM (nf16 | nfsum16 | ef16 | deg | 1 | pad)
#define EPB 2048  // edges per histogram/scatter block
#define NBLK 391  // ceil(NE/EPB)
#define NBKT 196  // buckets = dst>>8
#define NEGV -1000000000.0f

typedef unsigned int uint;
typedef unsigned short ushort;
typedef short bf16x8 __attribute__((ext_vector_type(8)));
typedef float f32x4 __attribute__((ext_vector_type(4)));

// fast transcendentals: v_exp_f32 + v_rcp_f32 (1-ulp-ish; gates are bf16 anyway)
__device__ __forceinline__ float frcp(float x){ return __builtin_amdgcn_rcpf(x); }
__device__ __forceinline__ float fsigm(float x){ return frcp(1.0f + __expf(-x)); }
__device__ __forceinline__ float ftanh(float x){ return 1.0f - 2.0f*frcp(__expf(2.0f*x) + 1.0f); }

__device__ __forceinline__ ushort f2b(float f){
    union{float f; uint u;} v; v.f=f;
    uint r = v.u + 0x7FFFu + ((v.u>>16)&1u);
    return (ushort)(r>>16);
}
__device__ __forceinline__ float b2f(ushort s){
    union{uint u; float f;} v; v.u = ((uint)s)<<16; return v.f;
}
__device__ __forceinline__ float blo(uint v){ return b2f((ushort)(v&0xFFFF)); }
__device__ __forceinline__ float bhi(uint v){ return b2f((ushort)(v>>16)); }
__device__ __forceinline__ uint pack2(float a, float b){ return (uint)f2b(a) | (((uint)f2b(b))<<16); }

// ---- degree histogram ----
__global__ void k_deg(const int* __restrict__ ei, int* __restrict__ deg){
    int e = blockIdx.x*256 + threadIdx.x;
    if (e >= NE) return;
    atomicAdd(&deg[ei[NE + e]], 1);
}

// ---- hierarchical exclusive scan over deg -> offs ----
__global__ void k_scan1(const int* __restrict__ deg, int* __restrict__ offs, int* __restrict__ bsum){
    int tid = threadIdx.x, bid = blockIdx.x;
    int idx = bid*256 + tid;
    int v = (idx<NN) ? deg[idx] : 0;
    int lane = tid&63, w = tid>>6;
    int x = v;
    #pragma unroll
    for (int d=1; d<64; d<<=1){ int y = __shfl_up(x,d); if (lane>=d) x += y; }
    __shared__ int wsum[4];
    if (lane==63) wsum[w] = x;
    __syncthreads();
    int base = 0;
    #pragma unroll
    for (int j=0;j<4;j++) if (j<w) base += wsum[j];
    if (idx<NN) offs[idx] = base + x - v;
    if (tid==255) bsum[bid] = base + x;
}
__global__ void k_scan2(int* __restrict__ bsum, int* __restrict__ offs){
    int tid = threadIdx.x;
    int v = (tid<NB) ? bsum[tid] : 0;
    int lane = tid&63, w = tid>>6;
    int x = v;
    #pragma unroll
    for (int d=1; d<64; d<<=1){ int y = __shfl_up(x,d); if (lane>=d) x += y; }
    __shared__ int wsum[4];
    if (lane==63) wsum[w] = x;
    __syncthreads();
    int base = 0;
    #pragma unroll
    for (int j=0;j<4;j++) if (j<w) base += wsum[j];
    if (tid<NB) bsum[tid] = base + x - v;
    if (tid==255) offs[NN] = base + x;
}
__global__ void k_scan3(const int* __restrict__ bsum, int* __restrict__ offs){
    int idx = blockIdx.x*256 + threadIdx.x;
    if (idx>=NN) return;
    offs[idx] += bsum[blockIdx.x];
}

// ---- counting sort phase 1: per-block bucket histogram ----
__global__ void k_hist(const int* __restrict__ ei, int* __restrict__ C){
    __shared__ int h[NBKT];
    int tid = threadIdx.x, blk = blockIdx.x;
    if (tid < NBKT) h[tid] = 0;
    __syncthreads();
    int e0 = blk*EPB;
    for (int i=tid; i<EPB; i+=256){
        int e = e0+i;
        if (e < NE) atomicAdd(&h[ei[NE+e]>>8], 1);
    }
    __syncthreads();
    if (tid < NBKT) C[blk*NBKT + tid] = h[tid];
}

// ---- phase 2: column-wise exclusive scan of C + bucket base from offs ----
__global__ void k_cscan(int* __restrict__ C, const int* __restrict__ offs){
    int b = blockIdx.x*4 + (threadIdx.x>>6);
    int lane = threadIdx.x & 63;
    if (b >= NBKT) return;
    int base = offs[b<<8];
    int carry = 0;
    for (int c=0; c<7; ++c){
        int i = c*64 + lane;
        int v = (i<NBLK)? C[i*NBKT + b] : 0;
        int x = v;
        #pragma unroll
        for (int d=1; d<64; d<<=1){ int y = __shfl_up(x,d); if (lane>=d) x += y; }
        if (i<NBLK) C[i*NBKT + b] = base + carry + (x - v);
        carry += __shfl(x, 63);
    }
}

// ---- phase 3: scatter edges into bucket-ordered array (sequential streams) ----
__global__ void k_scatA(const int* __restrict__ ei, const int* __restrict__ C,
                        int2* __restrict__ bkt2){
    __shared__ int cur[NBKT];
    __shared__ int cbase[NBKT];
    int tid = threadIdx.x, blk = blockIdx.x;
    if (tid < NBKT){ cur[tid] = 0; cbase[tid] = C[blk*NBKT + tid]; }
    __syncthreads();
    int e0 = blk*EPB;
    for (int i=tid; i<EPB; i+=256){
        int e = e0+i;
        if (e >= NE) break;
        int dst = ei[NE+e];
        int bkt = dst>>8;
        int r = atomicAdd(&cur[bkt], 1);
        bkt2[cbase[bkt] + r] = make_int2(dst, e);
    }
}

// ---- phase 4: per-bucket exact per-dst placement (single-CU 32KB window) ----
__global__ void k_scatB(const int* __restrict__ ei, const int2* __restrict__ bkt2,
                        const int* __restrict__ offs, int2* __restrict__ csr2){
    __shared__ int cur[256];
    int b = blockIdx.x, tid = threadIdx.x;
    int d0 = b<<8;
    {
        int idx = d0 + tid;
        cur[tid] = (idx<NN)? offs[idx] : 0;
    }
    __syncthreads();
    int lo = offs[d0];
    int hi = (d0+256 <= NN)? offs[d0+256] : offs[NN];
    for (int i=lo+tid; i<hi; i+=256){
        int2 p = bkt2[i];
        int pos = atomicAdd(&cur[p.x & 255], 1);
        csr2[pos] = make_int2(ei[p.y], p.y);
    }
}

// ---- per-node 16-wide sums of edge_feat (by eid) and node_feat (by src) ----
__global__ void k_gat16(const int2* __restrict__ csr2,
                        const float* __restrict__ edge_feat, const float* __restrict__ nf,
                        const int* __restrict__ offs,
                        float* __restrict__ ef_sum, float* __restrict__ nf_sum){
    int node = blockIdx.x*4 + (threadIdx.x>>6);
    int lane = threadIdx.x & 63;
    int k = lane & 15, sub = lane >> 4;
    int b = offs[node], e2 = offs[node+1];
    float ae = 0.f, an = 0.f;
    int i = b + sub;
    for (; i + 4 < e2; i += 8){
        int2 p0 = csr2[i], p1 = csr2[i+4];
        float f0 = edge_feat[(size_t)p0.y*FD + k];
        float g0 = nf[(size_t)p0.x*FD + k];
        float f1 = edge_feat[(size_t)p1.y*FD + k];
        float g1 = nf[(size_t)p1.x*FD + k];
        ae += f0 + f1; an += g0 + g1;
    }
    if (i < e2){
        int2 p0 = csr2[i];
        ae += edge_feat[(size_t)p0.y*FD + k];
        an += nf[(size_t)p0.x*FD + k];
    }
    ae += __shfl_xor(ae, 16); ae += __shfl_xor(ae, 32);
    an += __shfl_xor(an, 16); an += __shfl_xor(an, 32);
    if (sub == 0){ ef_sum[node*FD + k] = ae; nf_sum[node*FD + k] = an; }
}

// ---- Wf = W_ep@W_e ; bfv = b_ep@W_e + b_msg ----
__global__ void k_folds(const float* __restrict__ W_ep, const float* __restrict__ b_ep,
                        const float* __restrict__ W_msg, const float* __restrict__ b_msg,
                        float* __restrict__ Wf, float* __restrict__ bfv){
    int o = blockIdx.x*256 + threadIdx.x;
    if (o < FD*HD){
        int k=o>>7, c=o&127;
        float acc=0.f;
        for (int m=0;m<HD;m++) acc += W_ep[k*HD+m]*W_msg[(HD+m)*HD+c];
        Wf[o]=acc;
    } else if (o < FD*HD+HD){
        int c=o-FD*HD;
        float acc=b_msg[c];
        for (int m=0;m<HD;m++) acc += b_ep[m]*W_msg[(HD+m)*HD+c];
        bfv[c]=acc;
    }
}

// ---- build folded mega-weight W2T[512][320], col-INTERLEAVED gates: col = 4*j + g ----
// gates: 0=r, 1=z, 2=gi_n, 3=gh_n. Biases folded into k=273 (constant-1 column).
__global__ void k_wprep2(const float* __restrict__ W_ih, const float* __restrict__ W_hh,
                         const float* __restrict__ W_msg, const float* __restrict__ Wf,
                         const float* __restrict__ bfv,
                         const float* __restrict__ b_ih, const float* __restrict__ b_hh,
                         ushort* __restrict__ W2T, float* __restrict__ Wt32){
    int c = blockIdx.x;       // 0..511
    int k = threadIdx.x;      // 0..319
    int j = c>>2, g = c&3;
    float v = 0.f;
    if (k < 128){
        float acc = 0.f;
        if (g < 3){   // hsum path: (W_h @ W_ih_g^T)
            const float* wm = W_msg + (size_t)k*HD;
            const float* wi = W_ih + (size_t)(g*HD+j)*HD;
            for (int m=0;m<HD;m++) acc += wm[m]*wi[m];
        }
        Wt32[(size_t)c*HD + k] = acc;
        v = acc;
    } else if (k < 256){      // h path: W_hh gates (none for gi_n)
        int kk = k-128;
        if (g==0)      v = W_hh[(size_t)j*HD+kk];
        else if (g==1) v = W_hh[(size_t)(HD+j)*HD+kk];
        else if (g==3) v = W_hh[(size_t)(2*HD+j)*HD+kk];
    } else if (k < 272){      // ef_sum path
        if (g < 3){
            const float* wf = Wf + (size_t)(k-256)*HD;
            const float* wi = W_ih + (size_t)(g*HD+j)*HD;
            float acc=0.f;
            for (int m=0;m<HD;m++) acc += wf[m]*wi[m];
            v = acc;
        }
    } else if (k == 272){     // deg path
        if (g < 3){
            const float* wi = W_ih + (size_t)(g*HD+j)*HD;
            float acc=0.f;
            for (int m=0;m<HD;m++) acc += bfv[m]*wi[m];
            v = acc;
        }
    } else if (k == 273){     // constant-1: biases
        v = (g==0)? b_ih[j]+b_hh[j] : (g==1)? b_ih[HD+j]+b_hh[HD+j]
          : (g==2)? b_ih[2*HD+j] : b_hh[2*HD+j];
    }
    W2T[(size_t)c*AK + k] = f2b(v);
}

// ---- iter-1 weight W1T[512][64]: cols [nf16|nfsum16|ef16|deg|1|pad], W_np folded in ----
__global__ void k_wprep1(const float* __restrict__ W_np, const float* __restrict__ b_np,
                         const float* __restrict__ W_hh, const float* __restrict__ Wt32,
                         const ushort* __restrict__ W2T, ushort* __restrict__ W1T){
    int c = blockIdx.x;       // 0..511
    int k = threadIdx.x;      // 0..63
    int j = c>>2, g = c&3;
    float v = 0.f;
    if (k < 16){              // nf path: W_np @ W_hh_g^T  (g2 has no h-term)
        if (g != 2){
            int gp = (g==3)? 2 : g;
            const float* wh = W_hh + (size_t)(gp*HD + j)*HD;
            const float* wn = W_np + (size_t)k*HD;
            float acc=0.f;
            for (int m=0;m<HD;m++) acc += wn[m]*wh[m];
            v = acc;
        }
    } else if (k < 32){       // nf_sum path: W_np @ t_c (t = W_h@W_ih_g^T, zero for g3)
        const float* wt = Wt32 + (size_t)c*HD;
        const float* wn = W_np + (size_t)(k-16)*HD;
        float acc=0.f;
        for (int m=0;m<HD;m++) acc += wn[m]*wt[m];
        v = acc;
    } else if (k < 48){       // ef_sum path: copy from W2T
        v = b2f(W2T[(size_t)c*AK + 256 + (k-32)]);
    } else if (k == 48){      // deg: b_np@t_c + old deg col
        float acc = b2f(W2T[(size_t)c*AK + 272]);
        const float* wt = Wt32 + (size_t)c*HD;
        for (int m=0;m<HD;m++) acc += b_np[m]*wt[m];
        v = acc;
    } else if (k == 49){      // const-1: old biases + b_np@W_hh_g^T (h0's bias part)
        float acc = b2f(W2T[(size_t)c*AK + 273]);
        if (g != 2){
            int gp = (g==3)? 2 : g;
            const float* wh = W_hh + (size_t)(gp*HD + j)*HD;
            for (int m=0;m<HD;m++) acc += b_np[m]*wh[m];
        }
        v = acc;
    }
    W1T[(size_t)c*AK1 + k] = f2b(v);
}

// ---- light prep: A1prep[NN][64] = [nf|nfsum|ef|deg|1|0], statics into A ----
__global__ void k_prep2(const float* __restrict__ nf, const float* __restrict__ nf_sum,
                        const float* __restrict__ ef_sum, const int* __restrict__ deg,
                        ushort* __restrict__ A1p, ushort* __restrict__ A){
    int idx = blockIdx.x*256 + threadIdx.x;   // NN*32
    int n = idx>>5, c2 = idx&31;
    int k = c2*2, k1 = k+1;
    float d = (float)deg[n];
    float v0 = (k<16)? nf[n*FD+k] : (k<32)? nf_sum[n*FD+k-16] : (k<48)? ef_sum[n*FD+k-32]
             : (k==48)? d : 0.f;
    float v1 = (k1<16)? nf[n*FD+k1] : (k1<32)? nf_sum[n*FD+k1-16] : (k1<48)? ef_sum[n*FD+k1-32]
             : (k1==49)? 1.f : 0.f;
    ((uint*)A1p)[(size_t)n*32 + c2] = pack2(v0,v1);
    int col = 256 + k;
    float s0 = (col<272)? ef_sum[n*FD + col-256] : (col==272)? d : 0.f;
    float s1 = (col+1<272)? ef_sum[n*FD + col+1-256] : (col+1==273)? 1.f : 0.f;
    ((uint*)A)[(size_t)n*AKU + 128 + c2] = pack2(s0,s1);
}

// ---- fused GEMM + GRU epilogue (interleaved gates col=4j+g) -> in-place h in A ----
// IT1: Asrc=A1p (K=64, 1 step), h_old computed inline from nf. Else: Asrc=A (K=320, 5 steps).
template<bool IT1>
__global__ __launch_bounds__(256) void k_fused(const ushort* __restrict__ Asrc,
                                               const ushort* __restrict__ Bt,
                                               const float* __restrict__ nf,
                                               const float* __restrict__ W_np,
                                               const float* __restrict__ b_np,
                                               ushort* __restrict__ Ah){
    __shared__ __align__(16) short LDS[128*128];   // 32KB: As[0:8192) Bs[8192:16384); epilogue: gate tile
    __shared__ float Wnp_s[FD][32];                // 2KB, iter-1 only
    short* As = LDS;
    short* Bs = LDS + 128*64;
    const int tid = threadIdx.x;
    const int lane = tid & 63, w = tid>>6;
    const int wm = w>>1, wn = w&1;
    const int n0 = blockIdx.x*128, m0 = blockIdx.y*128;
    const int jbase = n0>>2;                       // 32 j-cols per block
    const int AKA = IT1 ? AK1 : AK;
    if (IT1){
        for (int i=tid; i<FD*32; i+=256){
            int kk=i>>5, jj=i&31;
            Wnp_s[kk][jj] = W_np[kk*HD + jbase + jj];
        }
    }
    f32x4 acc[4][4] = {};
    const int nsteps = IT1 ? 1 : 5;
    for (int kk=0; kk<nsteps; ++kk){
        __syncthreads();
        #pragma unroll
        for (int i=0;i<4;i++){
            int id = tid + i*256;
            int row = id>>3, s = id&7;
            int phys = row*64 + ((s ^ (row&7))<<3);
            int ar = m0 + row; if (ar >= NN) ar = NN-1;
            *(int4*)&As[phys] = *(const int4*)(Asrc + (size_t)ar*AKA + kk*64 + s*8);
            *(int4*)&Bs[phys] = *(const int4*)(Bt + (size_t)(n0+row)*AKA + kk*64 + s*8);
        }
        __syncthreads();
        #pragma unroll
        for (int ksel=0; ksel<2; ++ksel){
            bf16x8 af[4], bfr[4];
            #pragma unroll
            for (int t=0;t<4;t++){
                int arow = wm*64 + t*16 + (lane&15);
                int aslot = (ksel*4 + (lane>>4)) ^ (arow&7);
                af[t] = *(const bf16x8*)&As[arow*64 + aslot*8];
                int brow = wn*64 + t*16 + (lane&15);
                int bslot = (ksel*4 + (lane>>4)) ^ (brow&7);
                bfr[t] = *(const bf16x8*)&Bs[brow*64 + bslot*8];
            }
            #pragma unroll
            for (int mi=0;mi<4;mi++)
                #pragma unroll
                for (int ni=0;ni<4;ni++)
                    acc[mi][ni] = __builtin_amdgcn_mfma_f32_16x16x32_bf16(af[mi], bfr[ni], acc[mi][ni], 0,0,0);
        }
    }
    // dump gate tile to LDS (bf16), XOR swizzle at 8B (gate-quad) granularity
    __syncthreads();
    #pragma unroll
    for (int mi=0;mi<4;mi++){
        #pragma unroll
        for (int ni=0;ni<4;ni++){
            #pragma unroll
            for (int r=0;r<4;r++){
                int row = wm*64 + mi*16 + (lane>>4)*4 + r;
                int col = wn*64 + ni*16 + (lane&15);
                int pc = (col&3) | (((col>>2) ^ (row&7))<<2);
                LDS[row*128 + pc] = (short)f2b(acc[mi][ni][r]);
            }
        }
    }
    __syncthreads();
    // epilogue: thread -> (jp = tid&15 [j-pair], rg = tid>>4 [8 rows each]); fast-math gates
    {
        int jp = tid&15, rg = tid>>4;
        int jg = jbase + jp*2;                      // global j of first of pair
        #pragma unroll
        for (int rr=0; rr<8; ++rr){
            int row = rg*8 + rr;
            int n = m0 + row;
            if (n >= NN) continue;
            uint2 g0 = *(const uint2*)&LDS[row*128 + (((jp*2)   ^ (row&7))<<2)];
            uint2 g1 = *(const uint2*)&LDS[row*128 + (((jp*2+1) ^ (row&7))<<2)];
            float ha, hb;
            if constexpr (IT1){
                const float* x = nf + (size_t)n*FD;
                float a = b_np[jg], b = b_np[jg+1];
                #pragma unroll
                for (int k=0;k<FD;k++){
                    float xv = x[k];
                    a += xv*Wnp_s[k][jp*2];
                    b += xv*Wnp_s[k][jp*2+1];
                }
                ha = a; hb = b;
            } else {
                uint vh = ((const uint*)Ah)[(size_t)n*AKU + 64 + (n0>>3) + jp];
                ha = blo(vh); hb = bhi(vh);
            }
            float r0 = fsigm(blo(g0.x)), z0 = fsigm(bhi(g0.x));
            float nn0 = ftanh(blo(g0.y) + r0*bhi(g0.y));
            float r1 = fsigm(blo(g1.x)), z1 = fsigm(bhi(g1.x));
            float nn1 = ftanh(blo(g1.y) + r1*bhi(g1.y));
            float h0 = (1.f-z0)*nn0 + z0*ha;
            float h1 = (1.f-z1)*nn1 + z1*hb;
            ((uint*)Ah)[(size_t)n*AKU + 64 + (n0>>3) + jp] = pack2(h0,h1);
        }
    }
}

// ---- hsum[n] = sum over in-edges of h[src] (within same A buffer) ----
__global__ void k_gather(ushort* __restrict__ A, const int* __restrict__ offs,
                         const int2* __restrict__ csr2){
    int node = blockIdx.x*4 + (threadIdx.x>>6);
    int c2 = threadIdx.x & 63;
    int b = offs[node], e2 = offs[node+1];
    float a0 = 0.f, a1 = 0.f;
    const uint* hp = (const uint*)A;
    int i = b;
    for (; i + 8 <= e2; i += 8){
        int s0=csr2[i].x,  s1=csr2[i+1].x, s2=csr2[i+2].x, s3=csr2[i+3].x;
        int s4=csr2[i+4].x,s5=csr2[i+5].x, s6=csr2[i+6].x, s7=csr2[i+7].x;
        uint v0=hp[(size_t)s0*AKU+64+c2], v1=hp[(size_t)s1*AKU+64+c2],
             v2=hp[(size_t)s2*AKU+64+c2], v3=hp[(size_t)s3*AKU+64+c2],
             v4=hp[(size_t)s4*AKU+64+c2], v5=hp[(size_t)s5*AKU+64+c2],
             v6=hp[(size_t)s6*AKU+64+c2], v7=hp[(size_t)s7*AKU+64+c2];
        a0 += blo(v0)+blo(v1)+blo(v2)+blo(v3)+blo(v4)+blo(v5)+blo(v6)+blo(v7);
        a1 += bhi(v0)+bhi(v1)+bhi(v2)+bhi(v3)+bhi(v4)+bhi(v5)+bhi(v6)+bhi(v7);
    }
    if (i + 4 <= e2){
        int s0=csr2[i].x,s1=csr2[i+1].x,s2=csr2[i+2].x,s3=csr2[i+3].x;
        uint v0=hp[(size_t)s0*AKU+64+c2], v1=hp[(size_t)s1*AKU+64+c2],
             v2=hp[(size_t)s2*AKU+64+c2], v3=hp[(size_t)s3*AKU+64+c2];
        a0 += blo(v0)+blo(v1)+blo(v2)+blo(v3);
        a1 += bhi(v0)+bhi(v1)+bhi(v2)+bhi(v3);
        i += 4;
    }
    for (; i < e2; ++i){
        uint v = hp[(size_t)csr2[i].x*AKU+64+c2];
        a0 += blo(v); a1 += bhi(v);
    }
    ((uint*)A)[(size_t)node*AKU + c2] = pack2(a0,a1);
}

// ---- two-stage column sum of final h ----
__global__ void k_sum1(const ushort* __restrict__ A, float* __restrict__ partial){
    int bid = blockIdx.x, tid = threadIdx.x;
    int lane = tid&63, w2 = tid>>6;
    int nb = bid*64;
    float a0=0.f, a1=0.f;
    const uint* hp = (const uint*)A;
    #pragma unroll
    for (int r=w2; r<64; r+=4){
        int n = nb + r;
        if (n < NN){
            uint v = hp[(size_t)n*AKU + 64 + lane];
            a0 += blo(v); a1 += bhi(v);
        }
    }
    __shared__ float s0[4][64], s1[4][64];
    s0[w2][lane]=a0; s1[w2][lane]=a1;
    __syncthreads();
    if (w2==0){
        a0 = s0[0][lane]+s0[1][lane]+s0[2][lane]+s0[3][lane];
        a1 = s1[0][lane]+s1[1][lane]+s1[2][lane]+s1[3][lane];
        ((float2*)partial)[(size_t)bid*64 + lane] = make_float2(a0,a1);
    }
}
__global__ void k_sum2(const float* __restrict__ partial, float* __restrict__ gsum){
    int c = blockIdx.x;          // 0..127
    int tid = threadIdx.x;       // 256
    int lane = tid&63, w = tid>>6;
    float a = 0.f;
    for (int b=tid; b<NSB; b+=256) a += partial[(size_t)b*128 + c];
    #pragma unroll
    for (int d=1; d<64; d<<=1) a += __shfl_xor(a, d);
    __shared__ float sh[4];
    if (lane==0) sh[w]=a;
    __syncthreads();
    if (tid==0) gsum[c] = sh[0]+sh[1]+sh[2]+sh[3];
}

// ---- tiny agents + value head, LDS-staged z + wave-parallel reductions ----
__global__ void k_small(const float* __restrict__ ef, const int* __restrict__ paths,
                        const int* __restrict__ pmask, const float* __restrict__ pfeat,
                        const int* __restrict__ mmask, const int* __restrict__ smask,
                        const float* __restrict__ pspec,
                        const float* __restrict__ W_ep, const float* __restrict__ b_ep,
                        const float* __restrict__ W_path, const float* __restrict__ b_path,
                        const float* __restrict__ W_mod, const float* __restrict__ b_mod,
                        const float* __restrict__ c1w, const float* __restrict__ c1b,
                        const float* __restrict__ c2w, const float* __restrict__ c2b,
                        const float* __restrict__ W_val, const float* __restrict__ b_val,
                        const float* __restrict__ gsum, float* __restrict__ out){
    __shared__ float Wep_s[FD][HD];   // 8KB
    __shared__ float esum[NPATH][FD]; // 1KB
    __shared__ float z[NPATH][HD];
    __shared__ float lf[NS];
    __shared__ float spec[NS];
    __shared__ float red[8];
    __shared__ float scal[3];
    __shared__ int   sel[3];
    __shared__ float maxsh;
    int tid = threadIdx.x, lane = tid&63, w = tid>>6;

    for (int i=tid; i<FD*HD; i+=512) Wep_s[i>>7][i&127] = W_ep[i];
    if (tid < NPATH*FD){
        int p = tid>>4, k = tid&15;
        float a = 0.f;
        #pragma unroll
        for (int l=0;l<PL;l++){
            int eid = paths[p*PL + l];
            a += ef[(size_t)eid*FD + k];
        }
        esum[p][k] = a*0.125f;
    }
    __syncthreads();
    #pragma unroll
    for (int i=tid; i<NPATH*HD; i+=512){
        int p = i>>7, c = i&127;
        float a = b_ep[c];
        #pragma unroll
        for (int k=0;k<FD;k++) a += esum[p][k]*Wep_s[k][c];
        z[p][c] = a;
    }
    __syncthreads();
    { // logits_p
        int p = tid>>5, sub = tid&31;
        float part = 0.f;
        #pragma unroll
        for (int c=sub;c<HD;c+=32) part += z[p][c]*W_path[c];
        #pragma unroll
        for (int d=16; d>=1; d>>=1) part += __shfl_xor(part, d);
        if (sub==0) lf[p] = (pmask[p]==0)? NEGV : part + b_path[0];
    }
    __syncthreads();
    if (w==0){
        float v = (lane<NPATH)? lf[lane] : -3.0e38f;
        float m = v;
        #pragma unroll
        for (int d=1; d<64; d<<=1) m = fmaxf(m, __shfl_xor(m, d));
        float e = (lane<NPATH)? __expf(v-m) : 0.f;
        #pragma unroll
        for (int d=1; d<64; d<<=1) e += __shfl_xor(e, d);
        int idx = (lane<NPATH && v==m)? lane : (1<<30);
        #pragma unroll
        for (int d=1; d<64; d<<=1) idx = min(idx, __shfl_xor(idx, d));
        if (lane==0){ sel[0]=idx; scal[0] = -logf(e); }
    }
    __syncthreads();
    int pstar = sel[0];
    if (w < NM){
        float part = 0.f;
        #pragma unroll
        for (int c=lane;c<HD;c+=64) part += z[pstar][c]*W_mod[c*NM + w];
        if (lane<3) part += pfeat[pstar*3+lane]*W_mod[(HD+lane)*NM + w];
        #pragma unroll
        for (int d=1; d<64; d<<=1) part += __shfl_xor(part, d);
        if (lane==0) red[w] = (mmask[pstar*NM + w]==0)? NEGV : part + b_mod[w];
    } else if (w == 7){
        float part = gsum[lane]*W_val[lane] + gsum[lane+64]*W_val[lane+64];
        #pragma unroll
        for (int d=1; d<64; d<<=1) part += __shfl_xor(part, d);
        if (lane==0) scal[2] = part/(float)NN + b_val[0];
    }
    __syncthreads();
    if (w==0){
        float v = (lane<NM)? red[lane] : -3.0e38f;
        float m = v;
        #pragma unroll
        for (int d=1; d<64; d<<=1) m = fmaxf(m, __shfl_xor(m, d));
        float e = (lane<NM)? __expf(v-m) : 0.f;
        #pragma unroll
        for (int d=1; d<64; d<<=1) e += __shfl_xor(e, d);
        int idx = (lane<NM && v==m)? lane : (1<<30);
        #pragma unroll
        for (int d=1; d<64; d<<=1) idx = min(idx, __shfl_xor(idx, d));
        if (lane==0){ sel[1]=idx; scal[1] = -logf(e); }
    }
    __syncthreads();
    int mstar = sel[1];
    if (tid < NS) spec[tid] = pspec[pstar*NS + tid];
    __syncthreads();
    float v = -3.0e38f;
    if (tid < NS){
        float acc = c2b[0];
        #pragma unroll
        for (int ch=0; ch<8; ch++){
            float a = c1b[ch];
            #pragma unroll
            for (int k=0;k<5;k++){
                int ss = tid + k - 2;
                if (ss>=0 && ss<NS) a += spec[ss]*c1w[ch*5+k];
            }
            a = fmaxf(a, 0.f);
            acc += a*c2w[ch];
        }
        v = (smask[pstar*NM*NS + mstar*NS + tid]==0) ? NEGV : acc;
    }
    float m = v;
    #pragma unroll
    for (int d=1; d<64; d<<=1) m = fmaxf(m, __shfl_xor(m, d));
    if (lane==0) red[w] = m;
    __syncthreads();
    if (tid==0){
        float mm = red[0];
        #pragma unroll
        for (int i=1;i<8;i++) mm = fmaxf(mm, red[i]);
        maxsh = mm; sel[2] = 1<<30;
    }
    __syncthreads();
    float M2 = maxsh;
    if (tid<NS && v==M2) atomicMin(&sel[2], tid);
    float e = (tid<NS)? __expf(v-M2) : 0.f;
    #pragma unroll
    for (int d=1; d<64; d<<=1) e += __shfl_xor(e, d);
    if (lane==0) red[w] = e;
    __syncthreads();
    if (tid==0){
        float se = 0.f;
        #pragma unroll
        for (int i=0;i<8;i++) se += red[i];
        out[0] = (float)pstar;
        out[1] = (float)sel[2];
        out[2] = (float)mstar;
        out[3] = scal[0] + scal[1] - logf(se);
        out[4] = scal[2];
    }
}

extern "C" void kernel_launch(void* const* d_in, const int* in_sizes, int n_in,
                              void* d_out, int out_size, void* d_ws, size_t ws_size,
                              hipStream_t stream) {
    (void)in_sizes; (void)n_in; (void)out_size; (void)ws_size;
    const float* node_feat     = (const float*)d_in[0];
    const float* edge_feat     = (const float*)d_in[1];
    const int*   edge_index    = (const int*)d_in[2];
    const int*   paths         = (const int*)d_in[3];
    const int*   path_mask     = (const int*)d_in[4];
    const float* path_features = (const float*)d_in[5];
    const int*   mod_masks     = (const int*)d_in[6];
    const int*   spec_masks    = (const int*)d_in[7];
    const float* path_spectrum = (const float*)d_in[8];
    const float* W_np  = (const float*)d_in[9];
    const float* b_np  = (const float*)d_in[10];
    const float* W_ep  = (const float*)d_in[11];
    const float* b_ep  = (const float*)d_in[12];
    const float* W_msg = (const float*)d_in[13];
    const float* b_msg = (const float*)d_in[14];
    const float* W_ih  = (const float*)d_in[15];
    const float* b_ih  = (const float*)d_in[16];
    const float* W_hh  = (const float*)d_in[17];
    const float* b_hh  = (const float*)d_in[18];
    const float* W_path = (const float*)d_in[19];
    const float* b_path = (const float*)d_in[20];
    const float* W_mod  = (const float*)d_in[21];
    const float* b_mod  = (const float*)d_in[22];
    const float* c1w = (const float*)d_in[23];
    const float* c1b = (const float*)d_in[24];
    const float* c2w = (const float*)d_in[25];
    const float* c2b = (const float*)d_in[26];
    const float* W_val = (const float*)d_in[27];
    const float* b_val = (const float*)d_in[28];

    char* ws = (char*)d_ws;
    size_t off = 0;
    auto alloc = [&](size_t bytes)->char*{
        char* p = ws + off;
        off += (bytes + 255) & ~(size_t)255;
        return p;
    };
    int*    deg     = (int*)alloc((size_t)NN*4);
    int*    offs    = (int*)alloc((size_t)(NN+1)*4);
    int*    bsum    = (int*)alloc((size_t)NB*4);
    int*    Cmat    = (int*)alloc((size_t)NBLK*NBKT*4);
    int2*   bkt2    = (int2*)alloc((size_t)NE*8);
    int2*   csr2    = (int2*)alloc((size_t)NE*8);
    float*  ef_sum  = (float*)alloc((size_t)NN*FD*4);
    float*  nf_sum  = (float*)alloc((size_t)NN*FD*4);
    float*  Wf      = (float*)alloc((size_t)FD*HD*4);
    float*  bfv     = (float*)alloc((size_t)HD*4);
    ushort* W2T     = (ushort*)alloc((size_t)512*AK*2);
    float*  Wt32    = (float*)alloc((size_t)512*HD*4);
    ushort* W1T     = (ushort*)alloc((size_t)512*AK1*2);
    ushort* A       = (ushort*)alloc((size_t)NN*AK*2);
    ushort* A1p     = (ushort*)alloc((size_t)NN*AK1*2);
    float*  partial = (float*)alloc((size_t)NSB*HD*4);
    float*  gsum    = (float*)alloc((size_t)HD*4);

    hipMemsetAsync(deg, 0, (size_t)NN*4, stream);

    k_deg<<<(NE+255)/256, 256, 0, stream>>>(edge_index, deg);
    k_scan1<<<NB, 256, 0, stream>>>(deg, offs, bsum);
    k_scan2<<<1, 256, 0, stream>>>(bsum, offs);
    k_scan3<<<NB, 256, 0, stream>>>(bsum, offs);
    k_hist<<<NBLK, 256, 0, stream>>>(edge_index, Cmat);
    k_cscan<<<(NBKT+3)/4, 256, 0, stream>>>(Cmat, offs);
    k_scatA<<<NBLK, 256, 0, stream>>>(edge_index, Cmat, bkt2);
    k_scatB<<<NBKT, 256, 0, stream>>>(edge_index, bkt2, offs, csr2);
    k_gat16<<<NN/4, 256, 0, stream>>>(csr2, edge_feat, node_feat, offs, ef_sum, nf_sum);
    k_folds<<<9, 256, 0, stream>>>(W_ep, b_ep, W_msg, b_msg, Wf, bfv);
    k_wprep2<<<512, AK, 0, stream>>>(W_ih, W_hh, W_msg, Wf, bfv, b_ih, b_hh, W2T, Wt32);
    k_wprep1<<<512, AK1, 0, stream>>>(W_np, b_np, W_hh, Wt32, W2T, W1T);
    k_prep2<<<NN*32/256, 256, 0, stream>>>(node_feat, nf_sum, ef_sum, deg, A1p, A);

    const int MB = (NN+127)/128;   // 391
    // iter 1: A1p (K=64) -> fused GRU -> A.h  (h0 inline from nf)
    k_fused<true><<<dim3(4,MB), 256, 0, stream>>>(A1p, W1T, node_feat, W_np, b_np, A);
    // iter 2: gather -> fused -> A.h (in place)
    k_gather<<<NN/4, 256, 0, stream>>>(A, offs, csr2);
    k_fused<false><<<dim3(4,MB), 256, 0, stream>>>(A, W2T, node_feat, W_np, b_np, A);
    // iter 3
    k_gather<<<NN/4, 256, 0, stream>>>(A, offs, csr2);
    k_fused<false><<<dim3(4,MB), 256, 0, stream>>>(A, W2T, node_feat, W_np, b_np, A);

    k_sum1<<<NSB, 256, 0, stream>>>(A, partial);
    k_sum2<<<HD, 256, 0, stream>>>(partial, gsum);
    k_small<<<1, 512, 0, stream>>>(edge_feat, paths, path_mask, path_features,
                                   mod_masks, spec_masks, path_spectrum,
                                   W_ep, b_ep, W_path, b_path, W_mod, b_mod,
                                   c1w, c1b, c2w, c2b, W_val, b_val,
                                   gsum, (float*)d_out);
}

// Round 13
// 295.712 us; speedup vs baseline: 1.7230x; 1.0725x over previous
//
#include <hip/hip_runtime.h>
#include <hip/hip_bf16.h>
#include <math.h>

#define NN 50000
#define NE 800000
#define HD 128
#define FD 16
#define NPATH 16
#define PL 8
#define NM 6
#define NS 320
#define NSB 782   // ceil(NN/64)
#define AK 320    // K for iters 2-3 GEMM (hsum128 | h128 | ef16 | deg | 1 | pad)
#define AKU 160   // uints per A row
#define AK1 64    // K for iter-1 GEMM (nf16 | nfsum16 | ef16 | deg | 1 | pad)
#define EPB 2048  // edges per histogram/scatter block
#define NBLK 391  // ceil(NE/EPB)
#define NBKT 196  // buckets = dst>>8
#define MBT 391   // ceil(NN/128) m-tiles
#define NEGV -1000000000.0f

typedef unsigned int uint;
typedef unsigned short ushort;
typedef short bf16x8 __attribute__((ext_vector_type(8)));
typedef float f32x4 __attribute__((ext_vector_type(4)));

// fast transcendentals: v_exp_f32 + v_rcp_f32
__device__ __forceinline__ float frcp(float x){ return __builtin_amdgcn_rcpf(x); }
__device__ __forceinline__ float fsigm(float x){ return frcp(1.0f + __expf(-x)); }
__device__ __forceinline__ float ftanh(float x){ return 1.0f - 2.0f*frcp(__expf(2.0f*x) + 1.0f); }

// native bf16 convert (compiler packs pairs into v_cvt_pk_bf16_f32)
__device__ __forceinline__ ushort f2b(float f){
    union { __hip_bfloat16 h; ushort u; } v;
    v.h = __float2bfloat16(f);
    return v.u;
}
__device__ __forceinline__ float b2f(ushort s){
    union{uint u; float f;} v; v.u = ((uint)s)<<16; return v.f;
}
__device__ __forceinline__ float blo(uint v){ return b2f((ushort)(v&0xFFFF)); }
__device__ __forceinline__ float bhi(uint v){ return b2f((ushort)(v>>16)); }
__device__ __forceinline__ uint pack2(float a, float b){ return (uint)f2b(a) | (((uint)f2b(b))<<16); }

// ---- counting sort phase 1: per-block bucket histogram ----
__global__ void k_hist(const int* __restrict__ ei, int* __restrict__ C){
    __shared__ int h[NBKT];
    int tid = threadIdx.x, blk = blockIdx.x;
    if (tid < NBKT) h[tid] = 0;
    __syncthreads();
    int e0 = blk*EPB;
    for (int i=tid; i<EPB; i+=256){
        int e = e0+i;
        if (e < NE) atomicAdd(&h[ei[NE+e]>>8], 1);
    }
    __syncthreads();
    if (tid < NBKT) C[blk*NBKT + tid] = h[tid];
}

// ---- phase 2a: per-bucket exclusive prefix over blocks (no base) + bucket totals ----
__global__ void k_cscanA(int* __restrict__ C, int* __restrict__ bkttot){
    int b = blockIdx.x*4 + (threadIdx.x>>6);
    int lane = threadIdx.x & 63;
    if (b >= NBKT) return;
    int carry = 0;
    for (int c=0; c<7; ++c){
        int i = c*64 + lane;
        int v = (i<NBLK)? C[i*NBKT + b] : 0;
        int x = v;
        #pragma unroll
        for (int d=1; d<64; d<<=1){ int y = __shfl_up(x,d); if (lane>=d) x += y; }
        if (i<NBLK) C[i*NBKT + b] = carry + (x - v);
        carry += __shfl(x, 63);
    }
    if (lane==0) bkttot[b] = carry;
}

// ---- phase 2b: scan bucket totals -> bucket bases; offs[NN]=NE ----
__global__ void k_bscan(const int* __restrict__ bkttot, int* __restrict__ bktbase,
                        int* __restrict__ offs){
    int tid = threadIdx.x, lane = tid&63, w = tid>>6;
    int v = (tid<NBKT)? bkttot[tid] : 0;
    int x = v;
    #pragma unroll
    for (int d=1; d<64; d<<=1){ int y = __shfl_up(x,d); if (lane>=d) x += y; }
    __shared__ int wsum[4];
    if (lane==63) wsum[w] = x;
    __syncthreads();
    int base = 0;
    #pragma unroll
    for (int j=0;j<4;j++) if (j<w) base += wsum[j];
    int excl = base + x - v;
    if (tid < NBKT) bktbase[tid] = excl;
    if (tid == NBKT){ bktbase[NBKT] = excl; offs[NN] = excl; }
}

// ---- phase 3: scatter edges into bucket-ordered array (sequential streams) ----
__global__ void k_scatA(const int* __restrict__ ei, const int* __restrict__ C,
                        const int* __restrict__ bktbase, int2* __restrict__ bkt2){
    __shared__ int cur[NBKT];
    __shared__ int cbase[NBKT];
    int tid = threadIdx.x, blk = blockIdx.x;
    if (tid < NBKT){ cur[tid] = 0; cbase[tid] = bktbase[tid] + C[blk*NBKT + tid]; }
    __syncthreads();
    int e0 = blk*EPB;
    for (int i=tid; i<EPB; i+=256){
        int e = e0+i;
        if (e >= NE) break;
        int dst = ei[NE+e];
        int bkt = dst>>8;
        int r = atomicAdd(&cur[bkt], 1);
        bkt2[cbase[bkt] + r] = make_int2(dst, e);
    }
}

// ---- phase 4: per-bucket per-dst counts + scan -> offs; exact placement ----
__global__ void k_scatB(const int* __restrict__ ei, const int2* __restrict__ bkt2,
                        const int* __restrict__ bktbase,
                        int* __restrict__ offs, int2* __restrict__ csr2){
    __shared__ int cnt[256];
    __shared__ int cur[256];
    __shared__ int wsum[4];
    int b = blockIdx.x, tid = threadIdx.x, lane = tid&63, w = tid>>6;
    int d0 = b<<8;
    cnt[tid] = 0;
    __syncthreads();
    int lo = bktbase[b], hi = bktbase[b+1];
    for (int i=lo+tid; i<hi; i+=256) atomicAdd(&cnt[bkt2[i].x & 255], 1);
    __syncthreads();
    int v = cnt[tid], x = v;
    #pragma unroll
    for (int d=1; d<64; d<<=1){ int y = __shfl_up(x,d); if (lane>=d) x += y; }
    if (lane==63) wsum[w] = x;
    __syncthreads();
    int base = 0;
    #pragma unroll
    for (int j=0;j<4;j++) if (j<w) base += wsum[j];
    int o = lo + base + x - v;
    if (d0+tid < NN) offs[d0+tid] = o;
    cur[tid] = o;
    __syncthreads();
    for (int i=lo+tid; i<hi; i+=256){
        int2 p = bkt2[i];
        int pos = atomicAdd(&cur[p.x & 255], 1);
        csr2[pos] = make_int2(ei[p.y], p.y);
    }
}

// ---- per-node 16-wide sums of edge_feat (by eid) and node_feat (by src) ----
__global__ void k_gat16(const int2* __restrict__ csr2,
                        const float* __restrict__ edge_feat, const float* __restrict__ nf,
                        const int* __restrict__ offs,
                        float* __restrict__ ef_sum, float* __restrict__ nf_sum){
    int node = blockIdx.x*4 + (threadIdx.x>>6);
    int lane = threadIdx.x & 63;
    int k = lane & 15, sub = lane >> 4;
    int b = offs[node], e2 = offs[node+1];
    float ae = 0.f, an = 0.f;
    int i = b + sub;
    for (; i + 4 < e2; i += 8){
        int2 p0 = csr2[i], p1 = csr2[i+4];
        float f0 = edge_feat[(size_t)p0.y*FD + k];
        float g0 = nf[(size_t)p0.x*FD + k];
        float f1 = edge_feat[(size_t)p1.y*FD + k];
        float g1 = nf[(size_t)p1.x*FD + k];
        ae += f0 + f1; an += g0 + g1;
    }
    if (i < e2){
        int2 p0 = csr2[i];
        ae += edge_feat[(size_t)p0.y*FD + k];
        an += nf[(size_t)p0.x*FD + k];
    }
    ae += __shfl_xor(ae, 16); ae += __shfl_xor(ae, 32);
    an += __shfl_xor(an, 16); an += __shfl_xor(an, 32);
    if (sub == 0){ ef_sum[node*FD + k] = ae; nf_sum[node*FD + k] = an; }
}

// ---- Wf = W_ep@W_e ; bfv = b_ep@W_e + b_msg ----
__global__ void k_folds(const float* __restrict__ W_ep, const float* __restrict__ b_ep,
                        const float* __restrict__ W_msg, const float* __restrict__ b_msg,
                        float* __restrict__ Wf, float* __restrict__ bfv){
    int o = blockIdx.x*256 + threadIdx.x;
    if (o < FD*HD){
        int k=o>>7, c=o&127;
        float acc=0.f;
        for (int m=0;m<HD;m++) acc += W_ep[k*HD+m]*W_msg[(HD+m)*HD+c];
        Wf[o]=acc;
    } else if (o < FD*HD+HD){
        int c=o-FD*HD;
        float acc=b_msg[c];
        for (int m=0;m<HD;m++) acc += b_ep[m]*W_msg[(HD+m)*HD+c];
        bfv[c]=acc;
    }
}

// ---- build folded mega-weight W2T[512][320], col-INTERLEAVED gates: col = 4*j + g ----
__global__ void k_wprep2(const float* __restrict__ W_ih, const float* __restrict__ W_hh,
                         const float* __restrict__ W_msg, const float* __restrict__ Wf,
                         const float* __restrict__ bfv,
                         const float* __restrict__ b_ih, const float* __restrict__ b_hh,
                         ushort* __restrict__ W2T, float* __restrict__ Wt32){
    int c = blockIdx.x;       // 0..511
    int k = threadIdx.x;      // 0..319
    int j = c>>2, g = c&3;
    float v = 0.f;
    if (k < 128){
        float acc = 0.f;
        if (g < 3){   // hsum path: (W_h @ W_ih_g^T)
            const float* wm = W_msg + (size_t)k*HD;
            const float* wi = W_ih + (size_t)(g*HD+j)*HD;
            for (int m=0;m<HD;m++) acc += wm[m]*wi[m];
        }
        Wt32[(size_t)c*HD + k] = acc;
        v = acc;
    } else if (k < 256){      // h path: W_hh gates (none for gi_n)
        int kk = k-128;
        if (g==0)      v = W_hh[(size_t)j*HD+kk];
        else if (g==1) v = W_hh[(size_t)(HD+j)*HD+kk];
        else if (g==3) v = W_hh[(size_t)(2*HD+j)*HD+kk];
    } else if (k < 272){      // ef_sum path
        if (g < 3){
            const float* wf = Wf + (size_t)(k-256)*HD;
            const float* wi = W_ih + (size_t)(g*HD+j)*HD;
            float acc=0.f;
            for (int m=0;m<HD;m++) acc += wf[m]*wi[m];
            v = acc;
        }
    } else if (k == 272){     // deg path
        if (g < 3){
            const float* wi = W_ih + (size_t)(g*HD+j)*HD;
            float acc=0.f;
            for (int m=0;m<HD;m++) acc += bfv[m]*wi[m];
            v = acc;
        }
    } else if (k == 273){     // constant-1: biases
        v = (g==0)? b_ih[j]+b_hh[j] : (g==1)? b_ih[HD+j]+b_hh[HD+j]
          : (g==2)? b_ih[2*HD+j] : b_hh[2*HD+j];
    }
    W2T[(size_t)c*AK + k] = f2b(v);
}

// ---- iter-1 weight W1T[512][64] ----
__global__ void k_wprep1(const float* __restrict__ W_np, const float* __restrict__ b_np,
                         const float* __restrict__ W_hh, const float* __restrict__ Wt32,
                         const ushort* __restrict__ W2T, ushort* __restrict__ W1T){
    int c = blockIdx.x;       // 0..511
    int k = threadIdx.x;      // 0..63
    int j = c>>2, g = c&3;
    float v = 0.f;
    if (k < 16){              // nf path: W_np @ W_hh_g^T  (g2 has no h-term)
        if (g != 2){
            int gp = (g==3)? 2 : g;
            const float* wh = W_hh + (size_t)(gp*HD + j)*HD;
            const float* wn = W_np + (size_t)k*HD;
            float acc=0.f;
            for (int m=0;m<HD;m++) acc += wn[m]*wh[m];
            v = acc;
        }
    } else if (k < 32){       // nf_sum path
        const float* wt = Wt32 + (size_t)c*HD;
        const float* wn = W_np + (size_t)(k-16)*HD;
        float acc=0.f;
        for (int m=0;m<HD;m++) acc += wn[m]*wt[m];
        v = acc;
    } else if (k < 48){       // ef_sum path: copy from W2T
        v = b2f(W2T[(size_t)c*AK + 256 + (k-32)]);
    } else if (k == 48){      // deg
        float acc = b2f(W2T[(size_t)c*AK + 272]);
        const float* wt = Wt32 + (size_t)c*HD;
        for (int m=0;m<HD;m++) acc += b_np[m]*wt[m];
        v = acc;
    } else if (k == 49){      // const-1
        float acc = b2f(W2T[(size_t)c*AK + 273]);
        if (g != 2){
            int gp = (g==3)? 2 : g;
            const float* wh = W_hh + (size_t)(gp*HD + j)*HD;
            for (int m=0;m<HD;m++) acc += b_np[m]*wh[m];
        }
        v = acc;
    }
    W1T[(size_t)c*AK1 + k] = f2b(v);
}

// ---- light prep: A1prep[NN][64] = [nf|nfsum|ef|deg|1|0], statics into A ----
__global__ void k_prep2(const float* __restrict__ nf, const float* __restrict__ nf_sum,
                        const float* __restrict__ ef_sum, const int* __restrict__ offs,
                        ushort* __restrict__ A1p, ushort* __restrict__ A){
    int idx = blockIdx.x*256 + threadIdx.x;   // NN*32
    int n = idx>>5, c2 = idx&31;
    int k = c2*2, k1 = k+1;
    float d = (float)(offs[n+1] - offs[n]);
    float v0 = (k<16)? nf[n*FD+k] : (k<32)? nf_sum[n*FD+k-16] : (k<48)? ef_sum[n*FD+k-32]
             : (k==48)? d : 0.f;
    float v1 = (k1<16)? nf[n*FD+k1] : (k1<32)? nf_sum[n*FD+k1-16] : (k1<48)? ef_sum[n*FD+k1-32]
             : (k1==49)? 1.f : 0.f;
    ((uint*)A1p)[(size_t)n*32 + c2] = pack2(v0,v1);
    int col = 256 + k;
    float s0 = (col<272)? ef_sum[n*FD + col-256] : (col==272)? d : 0.f;
    float s1 = (col+1<272)? ef_sum[n*FD + col+1-256] : (col+1==273)? 1.f : 0.f;
    ((uint*)A)[(size_t)n*AKU + 128 + c2] = pack2(s0,s1);
}

// ---- fused GEMM + GRU epilogue, XCD-co-located (g,m) remap ----
// flat grid 1568: xcd=bid&7, g=(bid>>3)&3, m = xcd + 8*(bid>>5)
template<bool IT1>
__global__ __launch_bounds__(256) void k_fused(const ushort* __restrict__ Asrc,
                                               const ushort* __restrict__ Bt,
                                               const float* __restrict__ nf,
                                               const float* __restrict__ W_np,
                                               const float* __restrict__ b_np,
                                               ushort* __restrict__ Ah){
    __shared__ __align__(16) short LDS[128*128];   // exactly 32KB
    short* As = LDS;
    short* Bs = LDS + 128*64;
    const int bid = blockIdx.x;
    const int xcd = bid & 7;
    const int t = bid >> 3;
    const int gb = t & 3;
    const int mt = xcd + ((t >> 2) << 3);
    if (mt >= MBT) return;
    const int tid = threadIdx.x;
    const int lane = tid & 63, w = tid>>6;
    const int wm = w>>1, wn = w&1;
    const int n0 = gb*128, m0 = mt*128;
    const int jbase = n0>>2;                       // 32 j-cols per block
    const int AKA = IT1 ? AK1 : AK;
    f32x4 acc[4][4] = {};
    const int nsteps = IT1 ? 1 : 5;
    for (int kk=0; kk<nsteps; ++kk){
        __syncthreads();
        #pragma unroll
        for (int i=0;i<4;i++){
            int id = tid + i*256;
            int row = id>>3, s = id&7;
            int phys = row*64 + ((s ^ (row&7))<<3);
            int ar = m0 + row; if (ar >= NN) ar = NN-1;
            *(int4*)&As[phys] = *(const int4*)(Asrc + (size_t)ar*AKA + kk*64 + s*8);
            *(int4*)&Bs[phys] = *(const int4*)(Bt + (size_t)(n0+row)*AKA + kk*64 + s*8);
        }
        __syncthreads();
        #pragma unroll
        for (int ksel=0; ksel<2; ++ksel){
            bf16x8 af[4], bfr[4];
            #pragma unroll
            for (int t2=0;t2<4;t2++){
                int arow = wm*64 + t2*16 + (lane&15);
                int aslot = (ksel*4 + (lane>>4)) ^ (arow&7);
                af[t2] = *(const bf16x8*)&As[arow*64 + aslot*8];
                int brow = wn*64 + t2*16 + (lane&15);
                int bslot = (ksel*4 + (lane>>4)) ^ (brow&7);
                bfr[t2] = *(const bf16x8*)&Bs[brow*64 + bslot*8];
            }
            #pragma unroll
            for (int mi=0;mi<4;mi++)
                #pragma unroll
                for (int ni=0;ni<4;ni++)
                    acc[mi][ni] = __builtin_amdgcn_mfma_f32_16x16x32_bf16(af[mi], bfr[ni], acc[mi][ni], 0,0,0);
        }
    }
    // dump gate tile to LDS (bf16), XOR swizzle at 8B (gate-quad) granularity
    __syncthreads();
    #pragma unroll
    for (int mi=0;mi<4;mi++){
        #pragma unroll
        for (int ni=0;ni<4;ni++){
            #pragma unroll
            for (int r=0;r<4;r++){
                int row = wm*64 + mi*16 + (lane>>4)*4 + r;
                int col = wn*64 + ni*16 + (lane&15);
                int pc = (col&3) | (((col>>2) ^ (row&7))<<2);
                LDS[row*128 + pc] = (short)f2b(acc[mi][ni][r]);
            }
        }
    }
    __syncthreads();
    // epilogue: thread -> (jp = tid&15 [j-pair], rg = tid>>4 [8 rows each]); fast-math gates
    {
        int jp = tid&15, rg = tid>>4;
        int jg = jbase + jp*2;                      // global j of first of pair
        #pragma unroll
        for (int rr=0; rr<8; ++rr){
            int row = rg*8 + rr;
            int n = m0 + row;
            if (n >= NN) continue;
            uint2 g0 = *(const uint2*)&LDS[row*128 + (((jp*2)   ^ (row&7))<<2)];
            uint2 g1 = *(const uint2*)&LDS[row*128 + (((jp*2+1) ^ (row&7))<<2)];
            float ha, hb;
            if constexpr (IT1){
                const float* x = nf + (size_t)n*FD;
                float a = b_np[jg], b = b_np[jg+1];
                #pragma unroll
                for (int k=0;k<FD;k++){
                    float xv = x[k];
                    a += xv*W_np[k*HD + jg];
                    b += xv*W_np[k*HD + jg + 1];
                }
                ha = a; hb = b;
            } else {
                uint vh = ((const uint*)Ah)[(size_t)n*AKU + 64 + (n0>>3) + jp];
                ha = blo(vh); hb = bhi(vh);
            }
            float r0 = fsigm(blo(g0.x)), z0 = fsigm(bhi(g0.x));
            float nn0 = ftanh(blo(g0.y) + r0*bhi(g0.y));
            float r1 = fsigm(blo(g1.x)), z1 = fsigm(bhi(g1.x));
            float nn1 = ftanh(blo(g1.y) + r1*bhi(g1.y));
            float h0 = (1.f-z0)*nn0 + z0*ha;
            float h1 = (1.f-z1)*nn1 + z1*hb;
            ((uint*)Ah)[(size_t)n*AKU + 64 + (n0>>3) + jp] = pack2(h0,h1);
        }
    }
}

// ---- hsum[n] = sum over in-edges of h[src] (within same A buffer) ----
__global__ void k_gather(ushort* __restrict__ A, const int* __restrict__ offs,
                         const int2* __restrict__ csr2){
    int node = blockIdx.x*4 + (threadIdx.x>>6);
    int c2 = threadIdx.x & 63;
    int b = offs[node], e2 = offs[node+1];
    float a0 = 0.f, a1 = 0.f;
    const uint* hp = (const uint*)A;
    int i = b;
    for (; i + 8 <= e2; i += 8){
        int s0=csr2[i].x,  s1=csr2[i+1].x, s2=csr2[i+2].x, s3=csr2[i+3].x;
        int s4=csr2[i+4].x,s5=csr2[i+5].x, s6=csr2[i+6].x, s7=csr2[i+7].x;
        uint v0=hp[(size_t)s0*AKU+64+c2], v1=hp[(size_t)s1*AKU+64+c2],
             v2=hp[(size_t)s2*AKU+64+c2], v3=hp[(size_t)s3*AKU+64+c2],
             v4=hp[(size_t)s4*AKU+64+c2], v5=hp[(size_t)s5*AKU+64+c2],
             v6=hp[(size_t)s6*AKU+64+c2], v7=hp[(size_t)s7*AKU+64+c2];
        a0 += blo(v0)+blo(v1)+blo(v2)+blo(v3)+blo(v4)+blo(v5)+blo(v6)+blo(v7);
        a1 += bhi(v0)+bhi(v1)+bhi(v2)+bhi(v3)+bhi(v4)+bhi(v5)+bhi(v6)+bhi(v7);
    }
    if (i + 4 <= e2){
        int s0=csr2[i].x,s1=csr2[i+1].x,s2=csr2[i+2].x,s3=csr2[i+3].x;
        uint v0=hp[(size_t)s0*AKU+64+c2], v1=hp[(size_t)s1*AKU+64+c2],
             v2=hp[(size_t)s2*AKU+64+c2], v3=hp[(size_t)s3*AKU+64+c2];
        a0 += blo(v0)+blo(v1)+blo(v2)+blo(v3);
        a1 += bhi(v0)+bhi(v1)+bhi(v2)+bhi(v3);
        i += 4;
    }
    for (; i < e2; ++i){
        uint v = hp[(size_t)csr2[i].x*AKU+64+c2];
        a0 += blo(v); a1 += bhi(v);
    }
    ((uint*)A)[(size_t)node*AKU + c2] = pack2(a0,a1);
}

// ---- two-stage column sum of final h ----
__global__ void k_sum1(const ushort* __restrict__ A, float* __restrict__ partial){
    int bid = blockIdx.x, tid = threadIdx.x;
    int lane = tid&63, w2 = tid>>6;
    int nb = bid*64;
    float a0=0.f, a1=0.f;
    const uint* hp = (const uint*)A;
    #pragma unroll
    for (int r=w2; r<64; r+=4){
        int n = nb + r;
        if (n < NN){
            uint v = hp[(size_t)n*AKU + 64 + lane];
            a0 += blo(v); a1 += bhi(v);
        }
    }
    __shared__ float s0[4][64], s1[4][64];
    s0[w2][lane]=a0; s1[w2][lane]=a1;
    __syncthreads();
    if (w2==0){
        a0 = s0[0][lane]+s0[1][lane]+s0[2][lane]+s0[3][lane];
        a1 = s1[0][lane]+s1[1][lane]+s1[2][lane]+s1[3][lane];
        ((float2*)partial)[(size_t)bid*64 + lane] = make_float2(a0,a1);
    }
}
__global__ void k_sum2(const float* __restrict__ partial, float* __restrict__ gsum){
    int c = blockIdx.x;          // 0..127
    int tid = threadIdx.x;       // 256
    int lane = tid&63, w = tid>>6;
    float a = 0.f;
    for (int b=tid; b<NSB; b+=256) a += partial[(size_t)b*128 + c];
    #pragma unroll
    for (int d=1; d<64; d<<=1) a += __shfl_xor(a, d);
    __shared__ float sh[4];
    if (lane==0) sh[w]=a;
    __syncthreads();
    if (tid==0) gsum[c] = sh[0]+sh[1]+sh[2]+sh[3];
}

// ---- tiny agents + value head, LDS-staged z + wave-parallel reductions ----
__global__ void k_small(const float* __restrict__ ef, const int* __restrict__ paths,
                        const int* __restrict__ pmask, const float* __restrict__ pfeat,
                        const int* __restrict__ mmask, const int* __restrict__ smask,
                        const float* __restrict__ pspec,
                        const float* __restrict__ W_ep, const float* __restrict__ b_ep,
                        const float* __restrict__ W_path, const float* __restrict__ b_path,
                        const float* __restrict__ W_mod, const float* __restrict__ b_mod,
                        const float* __restrict__ c1w, const float* __restrict__ c1b,
                        const float* __restrict__ c2w, const float* __restrict__ c2b,
                        const float* __restrict__ W_val, const float* __restrict__ b_val,
                        const float* __restrict__ gsum, float* __restrict__ out){
    __shared__ float Wep_s[FD][HD];   // 8KB
    __shared__ float esum[NPATH][FD]; // 1KB
    __shared__ float z[NPATH][HD];
    __shared__ float lf[NS];
    __shared__ float spec[NS];
    __shared__ float red[8];
    __shared__ float scal[3];
    __shared__ int   sel[3];
    __shared__ float maxsh;
    int tid = threadIdx.x, lane = tid&63, w = tid>>6;

    for (int i=tid; i<FD*HD; i+=512) Wep_s[i>>7][i&127] = W_ep[i];
    if (tid < NPATH*FD){
        int p = tid>>4, k = tid&15;
        float a = 0.f;
        #pragma unroll
        for (int l=0;l<PL;l++){
            int eid = paths[p*PL + l];
            a += ef[(size_t)eid*FD + k];
        }
        esum[p][k] = a*0.125f;
    }
    __syncthreads();
    #pragma unroll
    for (int i=tid; i<NPATH*HD; i+=512){
        int p = i>>7, c = i&127;
        float a = b_ep[c];
        #pragma unroll
        for (int k=0;k<FD;k++) a += esum[p][k]*Wep_s[k][c];
        z[p][c] = a;
    }
    __syncthreads();
    { // logits_p
        int p = tid>>5, sub = tid&31;
        float part = 0.f;
        #pragma unroll
        for (int c=sub;c<HD;c+=32) part += z[p][c]*W_path[c];
        #pragma unroll
        for (int d=16; d>=1; d>>=1) part += __shfl_xor(part, d);
        if (sub==0) lf[p] = (pmask[p]==0)? NEGV : part + b_path[0];
    }
    __syncthreads();
    if (w==0){
        float v = (lane<NPATH)? lf[lane] : -3.0e38f;
        float m = v;
        #pragma unroll
        for (int d=1; d<64; d<<=1) m = fmaxf(m, __shfl_xor(m, d));
        float e = (lane<NPATH)? __expf(v-m) : 0.f;
        #pragma unroll
        for (int d=1; d<64; d<<=1) e += __shfl_xor(e, d);
        int idx = (lane<NPATH && v==m)? lane : (1<<30);
        #pragma unroll
        for (int d=1; d<64; d<<=1) idx = min(idx, __shfl_xor(idx, d));
        if (lane==0){ sel[0]=idx; scal[0] = -logf(e); }
    }
    __syncthreads();
    int pstar = sel[0];
    if (w < NM){
        float part = 0.f;
        #pragma unroll
        for (int c=lane;c<HD;c+=64) part += z[pstar][c]*W_mod[c*NM + w];
        if (lane<3) part += pfeat[pstar*3+lane]*W_mod[(HD+lane)*NM + w];
        #pragma unroll
        for (int d=1; d<64; d<<=1) part += __shfl_xor(part, d);
        if (lane==0) red[w] = (mmask[pstar*NM + w]==0)? NEGV : part + b_mod[w];
    } else if (w == 7){
        float part = gsum[lane]*W_val[lane] + gsum[lane+64]*W_val[lane+64];
        #pragma unroll
        for (int d=1; d<64; d<<=1) part += __shfl_xor(part, d);
        if (lane==0) scal[2] = part/(float)NN + b_val[0];
    }
    __syncthreads();
    if (w==0){
        float v = (lane<NM)? red[lane] : -3.0e38f;
        float m = v;
        #pragma unroll
        for (int d=1; d<64; d<<=1) m = fmaxf(m, __shfl_xor(m, d));
        float e = (lane<NM)? __expf(v-m) : 0.f;
        #pragma unroll
        for (int d=1; d<64; d<<=1) e += __shfl_xor(e, d);
        int idx = (lane<NM && v==m)? lane : (1<<30);
        #pragma unroll
        for (int d=1; d<64; d<<=1) idx = min(idx, __shfl_xor(idx, d));
        if (lane==0){ sel[1]=idx; scal[1] = -logf(e); }
    }
    __syncthreads();
    int mstar = sel[1];
    if (tid < NS) spec[tid] = pspec[pstar*NS + tid];
    __syncthreads();
    float v = -3.0e38f;
    if (tid < NS){
        float acc = c2b[0];
        #pragma unroll
        for (int ch=0; ch<8; ch++){
            float a = c1b[ch];
            #pragma unroll
            for (int k=0;k<5;k++){
                int ss = tid + k - 2;
                if (ss>=0 && ss<NS) a += spec[ss]*c1w[ch*5+k];
            }
            a = fmaxf(a, 0.f);
            acc += a*c2w[ch];
        }
        v = (smask[pstar*NM*NS + mstar*NS + tid]==0) ? NEGV : acc;
    }
    float m = v;
    #pragma unroll
    for (int d=1; d<64; d<<=1) m = fmaxf(m, __shfl_xor(m, d));
    if (lane==0) red[w] = m;
    __syncthreads();
    if (tid==0){
        float mm = red[0];
        #pragma unroll
        for (int i=1;i<8;i++) mm = fmaxf(mm, red[i]);
        maxsh = mm; sel[2] = 1<<30;
    }
    __syncthreads();
    float M2 = maxsh;
    if (tid<NS && v==M2) atomicMin(&sel[2], tid);
    float e = (tid<NS)? __expf(v-M2) : 0.f;
    #pragma unroll
    for (int d=1; d<64; d<<=1) e += __shfl_xor(e, d);
    if (lane==0) red[w] = e;
    __syncthreads();
    if (tid==0){
        float se = 0.f;
        #pragma unroll
        for (int i=0;i<8;i++) se += red[i];
        out[0] = (float)pstar;
        out[1] = (float)sel[2];
        out[2] = (float)mstar;
        out[3] = scal[0] + scal[1] - logf(se);
        out[4] = scal[2];
    }
}

extern "C" void kernel_launch(void* const* d_in, const int* in_sizes, int n_in,
                              void* d_out, int out_size, void* d_ws, size_t ws_size,
                              hipStream_t stream) {
    (void)in_sizes; (void)n_in; (void)out_size; (void)ws_size;
    const float* node_feat     = (const float*)d_in[0];
    const float* edge_feat     = (const float*)d_in[1];
    const int*   edge_index    = (const int*)d_in[2];
    const int*   paths         = (const int*)d_in[3];
    const int*   path_mask     = (const int*)d_in[4];
    const float* path_features = (const float*)d_in[5];
    const int*   mod_masks     = (const int*)d_in[6];
    const int*   spec_masks    = (const int*)d_in[7];
    const float* path_spectrum = (const float*)d_in[8];
    const float* W_np  = (const float*)d_in[9];
    const float* b_np  = (const float*)d_in[10];
    const float* W_ep  = (const float*)d_in[11];
    const float* b_ep  = (const float*)d_in[12];
    const float* W_msg = (const float*)d_in[13];
    const float* b_msg = (const float*)d_in[14];
    const float* W_ih  = (const float*)d_in[15];
    const float* b_ih  = (const float*)d_in[16];
    const float* W_hh  = (const float*)d_in[17];
    const float* b_hh  = (const float*)d_in[18];
    const float* W_path = (const float*)d_in[19];
    const float* b_path = (const float*)d_in[20];
    const float* W_mod  = (const float*)d_in[21];
    const float* b_mod  = (const float*)d_in[22];
    const float* c1w = (const float*)d_in[23];
    const float* c1b = (const float*)d_in[24];
    const float* c2w = (const float*)d_in[25];
    const float* c2b = (const float*)d_in[26];
    const float* W_val = (const float*)d_in[27];
    const float* b_val = (const float*)d_in[28];

    char* ws = (char*)d_ws;
    size_t off = 0;
    auto alloc = [&](size_t bytes)->char*{
        char* p = ws + off;
        off += (bytes + 255) & ~(size_t)255;
        return p;
    };
    int*    offs    = (int*)alloc((size_t)(NN+1)*4);
    int*    Cmat    = (int*)alloc((size_t)NBLK*NBKT*4);
    int*    bkttot  = (int*)alloc((size_t)NBKT*4);
    int*    bktbase = (int*)alloc((size_t)(NBKT+1)*4);
    int2*   bkt2    = (int2*)alloc((size_t)NE*8);
    int2*   csr2    = (int2*)alloc((size_t)NE*8);
    float*  ef_sum  = (float*)alloc((size_t)NN*FD*4);
    float*  nf_sum  = (float*)alloc((size_t)NN*FD*4);
    float*  Wf      = (float*)alloc((size_t)FD*HD*4);
    float*  bfv     = (float*)alloc((size_t)HD*4);
    ushort* W2T     = (ushort*)alloc((size_t)512*AK*2);
    float*  Wt32    = (float*)alloc((size_t)512*HD*4);
    ushort* W1T     = (ushort*)alloc((size_t)512*AK1*2);
    ushort* A       = (ushort*)alloc((size_t)NN*AK*2);
    ushort* A1p     = (ushort*)alloc((size_t)NN*AK1*2);
    float*  partial = (float*)alloc((size_t)NSB*HD*4);
    float*  gsum    = (float*)alloc((size_t)HD*4);

    k_hist<<<NBLK, 256, 0, stream>>>(edge_index, Cmat);
    k_cscanA<<<(NBKT+3)/4, 256, 0, stream>>>(Cmat, bkttot);
    k_bscan<<<1, 256, 0, stream>>>(bkttot, bktbase, offs);
    k_scatA<<<NBLK, 256, 0, stream>>>(edge_index, Cmat, bktbase, bkt2);
    k_scatB<<<NBKT, 256, 0, stream>>>(edge_index, bkt2, bktbase, offs, csr2);
    k_gat16<<<NN/4, 256, 0, stream>>>(csr2, edge_feat, node_feat, offs, ef_sum, nf_sum);
    k_folds<<<9, 256, 0, stream>>>(W_ep, b_ep, W_msg, b_msg, Wf, bfv);
    k_wprep2<<<512, AK, 0, stream>>>(W_ih, W_hh, W_msg, Wf, bfv, b_ih, b_hh, W2T, Wt32);
    k_wprep1<<<512, AK1, 0, stream>>>(W_np, b_np, W_hh, Wt32, W2T, W1T);
    k_prep2<<<NN*32/256, 256, 0, stream>>>(node_feat, nf_sum, ef_sum, offs, A1p, A);

    const int GRID = 8*4*49;   // 1568 (xcd, gate, m-chunk); 4 idle
    // iter 1: A1p (K=64) -> fused GRU -> A.h  (h0 inline from nf)
    k_fused<true><<<GRID, 256, 0, stream>>>(A1p, W1T, node_feat, W_np, b_np, A);
    // iter 2: gather -> fused -> A.h (in place)
    k_gather<<<NN/4, 256, 0, stream>>>(A, offs, csr2);
    k_fused<false><<<GRID, 256, 0, stream>>>(A, W2T, node_feat, W_np, b_np, A);
    // iter 3
    k_gather<<<NN/4, 256, 0, stream>>>(A, offs, csr2);
    k_fused<false><<<GRID, 256, 0, stream>>>(A, W2T, node_feat, W_np, b_np, A);

    k_sum1<<<NSB, 256, 0, stream>>>(A, partial);
    k_sum2<<<HD, 256, 0, stream>>>(partial, gsum);
    k_small<<<1, 512, 0, stream>>>(edge_feat, paths, path_mask, path_features,
                                   mod_masks, spec_masks, path_spectrum,
                                   W_ep, b_ep, W_path, b_path, W_mod, b_mod,
                                   c1w, c1b, c2w, c2b, W_val, b_val,
                                   gsum, (float*)d_out);
}

// Round 14
// 269.165 us; speedup vs baseline: 1.8929x; 1.0986x over previous
//
#include <hip/hip_runtime.h>
#include <hip/hip_bf16.h>
#include <math.h>

#define NN 50000
#define NE 800000
#define HD 128
#define FD 16
#define NPATH 16
#define PL 8
#define NM 6
#define NS 320
#define NSB 782   // ceil(NN/64)
#define AK 320    // K for iters 2-3 GEMM (hsum128 | h128 | ef16 | deg | 1 | pad)
#define AKU 160   // uints per A row
#define AK1 64    // K for iter-1 GEMM (nf16 | nfsum16 | ef16 | deg | 1 | pad)
#define EPB 2048  // edges per histogram/scatter block
#define NBLK 391  // ceil(NE/EPB)
#define NBKT 196  // buckets = dst>>8
#define MBT 391   // ceil(NN/128) m-tiles
#define NEGV -1000000000.0f

typedef unsigned int uint;
typedef unsigned short ushort;
typedef short bf16x8 __attribute__((ext_vector_type(8)));
typedef float f32x4 __attribute__((ext_vector_type(4)));

// fast transcendentals: v_exp_f32 + v_rcp_f32
__device__ __forceinline__ float frcp(float x){ return __builtin_amdgcn_rcpf(x); }
__device__ __forceinline__ float fsigm(float x){ return frcp(1.0f + __expf(-x)); }
__device__ __forceinline__ float ftanh(float x){ return 1.0f - 2.0f*frcp(__expf(2.0f*x) + 1.0f); }

// native bf16 convert
__device__ __forceinline__ ushort f2b(float f){
    union { __hip_bfloat16 h; ushort u; } v;
    v.h = __float2bfloat16(f);
    return v.u;
}
__device__ __forceinline__ float b2f(ushort s){
    union{uint u; float f;} v; v.u = ((uint)s)<<16; return v.f;
}
__device__ __forceinline__ float blo(uint v){ return b2f((ushort)(v&0xFFFF)); }
__device__ __forceinline__ float bhi(uint v){ return b2f((ushort)(v>>16)); }
__device__ __forceinline__ uint pack2(float a, float b){ return (uint)f2b(a) | (((uint)f2b(b))<<16); }

// async global->LDS 16B per lane; LDS dest wave-uniform, global src per-lane
__device__ __forceinline__ void gload16(const void* g, void* l){
    __builtin_amdgcn_global_load_lds(
        (const __attribute__((address_space(1))) unsigned int*)g,
        (__attribute__((address_space(3))) unsigned int*)l,
        16, 0, 0);
}

// ---- counting sort phase 1: per-block bucket histogram ----
__global__ void k_hist(const int* __restrict__ ei, int* __restrict__ C){
    __shared__ int h[NBKT];
    int tid = threadIdx.x, blk = blockIdx.x;
    if (tid < NBKT) h[tid] = 0;
    __syncthreads();
    int e0 = blk*EPB;
    for (int i=tid; i<EPB; i+=256){
        int e = e0+i;
        if (e < NE) atomicAdd(&h[ei[NE+e]>>8], 1);
    }
    __syncthreads();
    if (tid < NBKT) C[blk*NBKT + tid] = h[tid];
}

// ---- phase 2a: per-bucket exclusive prefix over blocks + bucket totals ----
__global__ void k_cscanA(int* __restrict__ C, int* __restrict__ bkttot){
    int b = blockIdx.x*4 + (threadIdx.x>>6);
    int lane = threadIdx.x & 63;
    if (b >= NBKT) return;
    int carry = 0;
    for (int c=0; c<7; ++c){
        int i = c*64 + lane;
        int v = (i<NBLK)? C[i*NBKT + b] : 0;
        int x = v;
        #pragma unroll
        for (int d=1; d<64; d<<=1){ int y = __shfl_up(x,d); if (lane>=d) x += y; }
        if (i<NBLK) C[i*NBKT + b] = carry + (x - v);
        carry += __shfl(x, 63);
    }
    if (lane==0) bkttot[b] = carry;
}

// ---- phase 2b: scan bucket totals -> bucket bases; offs[NN]=NE ----
__global__ void k_bscan(const int* __restrict__ bkttot, int* __restrict__ bktbase,
                        int* __restrict__ offs){
    int tid = threadIdx.x, lane = tid&63, w = tid>>6;
    int v = (tid<NBKT)? bkttot[tid] : 0;
    int x = v;
    #pragma unroll
    for (int d=1; d<64; d<<=1){ int y = __shfl_up(x,d); if (lane>=d) x += y; }
    __shared__ int wsum[4];
    if (lane==63) wsum[w] = x;
    __syncthreads();
    int base = 0;
    #pragma unroll
    for (int j=0;j<4;j++) if (j<w) base += wsum[j];
    int excl = base + x - v;
    if (tid < NBKT) bktbase[tid] = excl;
    if (tid == NBKT){ bktbase[NBKT] = excl; offs[NN] = excl; }
}

// ---- phase 3: scatter edges into bucket-ordered array (sequential streams) ----
__global__ void k_scatA(const int* __restrict__ ei, const int* __restrict__ C,
                        const int* __restrict__ bktbase, int2* __restrict__ bkt2){
    __shared__ int cur[NBKT];
    __shared__ int cbase[NBKT];
    int tid = threadIdx.x, blk = blockIdx.x;
    if (tid < NBKT){ cur[tid] = 0; cbase[tid] = bktbase[tid] + C[blk*NBKT + tid]; }
    __syncthreads();
    int e0 = blk*EPB;
    for (int i=tid; i<EPB; i+=256){
        int e = e0+i;
        if (e >= NE) break;
        int dst = ei[NE+e];
        int bkt = dst>>8;
        int r = atomicAdd(&cur[bkt], 1);
        bkt2[cbase[bkt] + r] = make_int2(dst, e);
    }
}

// ---- phase 4: per-bucket per-dst counts + scan -> offs; exact placement ----
__global__ void k_scatB(const int* __restrict__ ei, const int2* __restrict__ bkt2,
                        const int* __restrict__ bktbase,
                        int* __restrict__ offs, int2* __restrict__ csr2){
    __shared__ int cnt[256];
    __shared__ int cur[256];
    __shared__ int wsum[4];
    int b = blockIdx.x, tid = threadIdx.x, lane = tid&63, w = tid>>6;
    int d0 = b<<8;
    cnt[tid] = 0;
    __syncthreads();
    int lo = bktbase[b], hi = bktbase[b+1];
    for (int i=lo+tid; i<hi; i+=256) atomicAdd(&cnt[bkt2[i].x & 255], 1);
    __syncthreads();
    int v = cnt[tid], x = v;
    #pragma unroll
    for (int d=1; d<64; d<<=1){ int y = __shfl_up(x,d); if (lane>=d) x += y; }
    if (lane==63) wsum[w] = x;
    __syncthreads();
    int base = 0;
    #pragma unroll
    for (int j=0;j<4;j++) if (j<w) base += wsum[j];
    int o = lo + base + x - v;
    if (d0+tid < NN) offs[d0+tid] = o;
    cur[tid] = o;
    __syncthreads();
    for (int i=lo+tid; i<hi; i+=256){
        int2 p = bkt2[i];
        int pos = atomicAdd(&cur[p.x & 255], 1);
        csr2[pos] = make_int2(ei[p.y], p.y);
    }
}

// ---- per-node 16-wide sums of edge_feat (by eid) and node_feat (by src) ----
__global__ void k_gat16(const int2* __restrict__ csr2,
                        const float* __restrict__ edge_feat, const float* __restrict__ nf,
                        const int* __restrict__ offs,
                        float* __restrict__ ef_sum, float* __restrict__ nf_sum){
    int node = blockIdx.x*4 + (threadIdx.x>>6);
    int lane = threadIdx.x & 63;
    int k = lane & 15, sub = lane >> 4;
    int b = offs[node], e2 = offs[node+1];
    float ae = 0.f, an = 0.f;
    int i = b + sub;
    for (; i + 4 < e2; i += 8){
        int2 p0 = csr2[i], p1 = csr2[i+4];
        float f0 = edge_feat[(size_t)p0.y*FD + k];
        float g0 = nf[(size_t)p0.x*FD + k];
        float f1 = edge_feat[(size_t)p1.y*FD + k];
        float g1 = nf[(size_t)p1.x*FD + k];
        ae += f0 + f1; an += g0 + g1;
    }
    if (i < e2){
        int2 p0 = csr2[i];
        ae += edge_feat[(size_t)p0.y*FD + k];
        an += nf[(size_t)p0.x*FD + k];
    }
    ae += __shfl_xor(ae, 16); ae += __shfl_xor(ae, 32);
    an += __shfl_xor(an, 16); an += __shfl_xor(an, 32);
    if (sub == 0){ ef_sum[node*FD + k] = ae; nf_sum[node*FD + k] = an; }
}

// ---- Wf = W_ep@W_e ; bfv = b_ep@W_e + b_msg ----
__global__ void k_folds(const float* __restrict__ W_ep, const float* __restrict__ b_ep,
                        const float* __restrict__ W_msg, const float* __restrict__ b_msg,
                        float* __restrict__ Wf, float* __restrict__ bfv){
    int o = blockIdx.x*256 + threadIdx.x;
    if (o < FD*HD){
        int k=o>>7, c=o&127;
        float acc=0.f;
        for (int m=0;m<HD;m++) acc += W_ep[k*HD+m]*W_msg[(HD+m)*HD+c];
        Wf[o]=acc;
    } else if (o < FD*HD+HD){
        int c=o-FD*HD;
        float acc=b_msg[c];
        for (int m=0;m<HD;m++) acc += b_ep[m]*W_msg[(HD+m)*HD+c];
        bfv[c]=acc;
    }
}

// ---- build folded mega-weight W2T[512][320], col-INTERLEAVED gates: col = 4*j + g ----
__global__ void k_wprep2(const float* __restrict__ W_ih, const float* __restrict__ W_hh,
                         const float* __restrict__ W_msg, const float* __restrict__ Wf,
                         const float* __restrict__ bfv,
                         const float* __restrict__ b_ih, const float* __restrict__ b_hh,
                         ushort* __restrict__ W2T, float* __restrict__ Wt32){
    int c = blockIdx.x;       // 0..511
    int k = threadIdx.x;      // 0..319
    int j = c>>2, g = c&3;
    float v = 0.f;
    if (k < 128){
        float acc = 0.f;
        if (g < 3){   // hsum path: (W_h @ W_ih_g^T)
            const float* wm = W_msg + (size_t)k*HD;
            const float* wi = W_ih + (size_t)(g*HD+j)*HD;
            for (int m=0;m<HD;m++) acc += wm[m]*wi[m];
        }
        Wt32[(size_t)c*HD + k] = acc;
        v = acc;
    } else if (k < 256){      // h path: W_hh gates (none for gi_n)
        int kk = k-128;
        if (g==0)      v = W_hh[(size_t)j*HD+kk];
        else if (g==1) v = W_hh[(size_t)(HD+j)*HD+kk];
        else if (g==3) v = W_hh[(size_t)(2*HD+j)*HD+kk];
    } else if (k < 272){      // ef_sum path
        if (g < 3){
            const float* wf = Wf + (size_t)(k-256)*HD;
            const float* wi = W_ih + (size_t)(g*HD+j)*HD;
            float acc=0.f;
            for (int m=0;m<HD;m++) acc += wf[m]*wi[m];
            v = acc;
        }
    } else if (k == 272){     // deg path
        if (g < 3){
            const float* wi = W_ih + (size_t)(g*HD+j)*HD;
            float acc=0.f;
            for (int m=0;m<HD;m++) acc += bfv[m]*wi[m];
            v = acc;
        }
    } else if (k == 273){     // constant-1: biases
        v = (g==0)? b_ih[j]+b_hh[j] : (g==1)? b_ih[HD+j]+b_hh[HD+j]
          : (g==2)? b_ih[2*HD+j] : b_hh[2*HD+j];
    }
    W2T[(size_t)c*AK + k] = f2b(v);
}

// ---- iter-1 weight W1T[512][64] ----
__global__ void k_wprep1(const float* __restrict__ W_np, const float* __restrict__ b_np,
                         const float* __restrict__ W_hh, const float* __restrict__ Wt32,
                         const ushort* __restrict__ W2T, ushort* __restrict__ W1T){
    int c = blockIdx.x;       // 0..511
    int k = threadIdx.x;      // 0..63
    int j = c>>2, g = c&3;
    float v = 0.f;
    if (k < 16){              // nf path: W_np @ W_hh_g^T  (g2 has no h-term)
        if (g != 2){
            int gp = (g==3)? 2 : g;
            const float* wh = W_hh + (size_t)(gp*HD + j)*HD;
            const float* wn = W_np + (size_t)k*HD;
            float acc=0.f;
            for (int m=0;m<HD;m++) acc += wn[m]*wh[m];
            v = acc;
        }
    } else if (k < 32){       // nf_sum path
        const float* wt = Wt32 + (size_t)c*HD;
        const float* wn = W_np + (size_t)(k-16)*HD;
        float acc=0.f;
        for (int m=0;m<HD;m++) acc += wn[m]*wt[m];
        v = acc;
    } else if (k < 48){       // ef_sum path: copy from W2T
        v = b2f(W2T[(size_t)c*AK + 256 + (k-32)]);
    } else if (k == 48){      // deg
        float acc = b2f(W2T[(size_t)c*AK + 272]);
        const float* wt = Wt32 + (size_t)c*HD;
        for (int m=0;m<HD;m++) acc += b_np[m]*wt[m];
        v = acc;
    } else if (k == 49){      // const-1
        float acc = b2f(W2T[(size_t)c*AK + 273]);
        if (g != 2){
            int gp = (g==3)? 2 : g;
            const float* wh = W_hh + (size_t)(gp*HD + j)*HD;
            for (int m=0;m<HD;m++) acc += b_np[m]*wh[m];
        }
        v = acc;
    }
    W1T[(size_t)c*AK1 + k] = f2b(v);
}

// ---- light prep: A1prep[NN][64] = [nf|nfsum|ef|deg|1|0], statics into A ----
__global__ void k_prep2(const float* __restrict__ nf, const float* __restrict__ nf_sum,
                        const float* __restrict__ ef_sum, const int* __restrict__ offs,
                        ushort* __restrict__ A1p, ushort* __restrict__ A){
    int idx = blockIdx.x*256 + threadIdx.x;   // NN*32
    int n = idx>>5, c2 = idx&31;
    int k = c2*2, k1 = k+1;
    float d = (float)(offs[n+1] - offs[n]);
    float v0 = (k<16)? nf[n*FD+k] : (k<32)? nf_sum[n*FD+k-16] : (k<48)? ef_sum[n*FD+k-32]
             : (k==48)? d : 0.f;
    float v1 = (k1<16)? nf[n*FD+k1] : (k1<32)? nf_sum[n*FD+k1-16] : (k1<48)? ef_sum[n*FD+k1-32]
             : (k1==49)? 1.f : 0.f;
    ((uint*)A1p)[(size_t)n*32 + c2] = pack2(v0,v1);
    int col = 256 + k;
    float s0 = (col<272)? ef_sum[n*FD + col-256] : (col==272)? d : 0.f;
    float s1 = (col+1<272)? ef_sum[n*FD + col+1-256] : (col+1==273)? 1.f : 0.f;
    ((uint*)A)[(size_t)n*AKU + 128 + c2] = pack2(s0,s1);
}

// ---- fused GEMM + GRU epilogue, XCD-co-located (g,m) remap, async LDS staging ----
// flat grid 1568: xcd=bid&7, g=(bid>>3)&3, m = xcd + 8*(bid>>5)
// LDS is LINEAR; swizzle applied on per-lane GLOBAL source (m173 pattern):
//   LDS[row*64 + s*8] holds global slot s^(row&7); read XOR cancels it.
template<bool IT1>
__global__ __launch_bounds__(256, 4) void k_fused(const ushort* __restrict__ Asrc,
                                                  const ushort* __restrict__ Bt,
                                                  const float* __restrict__ nf,
                                                  const float* __restrict__ W_np,
                                                  const float* __restrict__ b_np,
                                                  ushort* __restrict__ Ah){
    __shared__ __align__(16) short LDS[128*128];   // exactly 32KB
    short* As = LDS;
    short* Bs = LDS + 128*64;
    const int bid = blockIdx.x;
    const int xcd = bid & 7;
    const int t = bid >> 3;
    const int gb = t & 3;
    const int mt = xcd + ((t >> 2) << 3);
    if (mt >= MBT) return;
    const int tid = threadIdx.x;
    const int lane = tid & 63, w = tid>>6;
    const int wm = w>>1, wn = w&1;
    const int n0 = gb*128, m0 = mt*128;
    const int jbase = n0>>2;                       // 32 j-cols per block
    const int AKA = IT1 ? AK1 : AK;
    // per-lane staging geometry (constant across K-steps)
    const int rl  = lane>>3;                       // row-in-chunk 0..7
    const int sg  = (lane&7) ^ (rl&7);             // pre-swizzled global slot
    f32x4 acc[4][4] = {};
    const int nsteps = IT1 ? 1 : 5;
    for (int kk=0; kk<nsteps; ++kk){
        __syncthreads();
        #pragma unroll
        for (int i=0;i<4;i++){
            int cc = w*4 + i;                      // chunk 0..15 (8 rows each)
            int rowl = (cc<<3) + rl;
            int ar = m0 + rowl; if (ar >= NN) ar = NN-1;
            gload16(Asrc + (size_t)ar*AKA + kk*64 + sg*8, As + cc*512);
            gload16(Bt + (size_t)(n0+rowl)*AKA + kk*64 + sg*8, Bs + cc*512);
        }
        __syncthreads();
        #pragma unroll
        for (int ksel=0; ksel<2; ++ksel){
            bf16x8 af[4], bfr[4];
            #pragma unroll
            for (int t2=0;t2<4;t2++){
                int arow = wm*64 + t2*16 + (lane&15);
                int aslot = (ksel*4 + (lane>>4)) ^ (arow&7);
                af[t2] = *(const bf16x8*)&As[arow*64 + aslot*8];
                int brow = wn*64 + t2*16 + (lane&15);
                int bslot = (ksel*4 + (lane>>4)) ^ (brow&7);
                bfr[t2] = *(const bf16x8*)&Bs[brow*64 + bslot*8];
            }
            #pragma unroll
            for (int mi=0;mi<4;mi++)
                #pragma unroll
                for (int ni=0;ni<4;ni++)
                    acc[mi][ni] = __builtin_amdgcn_mfma_f32_16x16x32_bf16(af[mi], bfr[ni], acc[mi][ni], 0,0,0);
        }
    }
    // dump gate tile to LDS (bf16), XOR swizzle at 8B (gate-quad) granularity
    __syncthreads();
    #pragma unroll
    for (int mi=0;mi<4;mi++){
        #pragma unroll
        for (int ni=0;ni<4;ni++){
            #pragma unroll
            for (int r=0;r<4;r++){
                int row = wm*64 + mi*16 + (lane>>4)*4 + r;
                int col = wn*64 + ni*16 + (lane&15);
                int pc = (col&3) | (((col>>2) ^ (row&7))<<2);
                LDS[row*128 + pc] = (short)f2b(acc[mi][ni][r]);
            }
        }
    }
    __syncthreads();
    // epilogue: thread -> (jp = tid&15 [j-pair], rg = tid>>4 [8 rows each]); fast-math gates
    {
        int jp = tid&15, rg = tid>>4;
        int jg = jbase + jp*2;                      // global j of first of pair
        #pragma unroll
        for (int rr=0; rr<8; ++rr){
            int row = rg*8 + rr;
            int n = m0 + row;
            if (n >= NN) continue;
            uint2 g0 = *(const uint2*)&LDS[row*128 + (((jp*2)   ^ (row&7))<<2)];
            uint2 g1 = *(const uint2*)&LDS[row*128 + (((jp*2+1) ^ (row&7))<<2)];
            float ha, hb;
            if constexpr (IT1){
                const float* x = nf + (size_t)n*FD;
                float a = b_np[jg], b = b_np[jg+1];
                #pragma unroll
                for (int k=0;k<FD;k++){
                    float xv = x[k];
                    a += xv*W_np[k*HD + jg];
                    b += xv*W_np[k*HD + jg + 1];
                }
                ha = a; hb = b;
            } else {
                uint vh = ((const uint*)Ah)[(size_t)n*AKU + 64 + (n0>>3) + jp];
                ha = blo(vh); hb = bhi(vh);
            }
            float r0 = fsigm(blo(g0.x)), z0 = fsigm(bhi(g0.x));
            float nn0 = ftanh(blo(g0.y) + r0*bhi(g0.y));
            float r1 = fsigm(blo(g1.x)), z1 = fsigm(bhi(g1.x));
            float nn1 = ftanh(blo(g1.y) + r1*bhi(g1.y));
            float h0 = (1.f-z0)*nn0 + z0*ha;
            float h1 = (1.f-z1)*nn1 + z1*hb;
            ((uint*)Ah)[(size_t)n*AKU + 64 + (n0>>3) + jp] = pack2(h0,h1);
        }
    }
}

// ---- hsum[n] = sum over in-edges of h[src] (within same A buffer) ----
__global__ void k_gather(ushort* __restrict__ A, const int* __restrict__ offs,
                         const int2* __restrict__ csr2){
    int node = blockIdx.x*4 + (threadIdx.x>>6);
    int c2 = threadIdx.x & 63;
    int b = offs[node], e2 = offs[node+1];
    float a0 = 0.f, a1 = 0.f;
    const uint* hp = (const uint*)A;
    int i = b;
    for (; i + 8 <= e2; i += 8){
        int s0=csr2[i].x,  s1=csr2[i+1].x, s2=csr2[i+2].x, s3=csr2[i+3].x;
        int s4=csr2[i+4].x,s5=csr2[i+5].x, s6=csr2[i+6].x, s7=csr2[i+7].x;
        uint v0=hp[(size_t)s0*AKU+64+c2], v1=hp[(size_t)s1*AKU+64+c2],
             v2=hp[(size_t)s2*AKU+64+c2], v3=hp[(size_t)s3*AKU+64+c2],
             v4=hp[(size_t)s4*AKU+64+c2], v5=hp[(size_t)s5*AKU+64+c2],
             v6=hp[(size_t)s6*AKU+64+c2], v7=hp[(size_t)s7*AKU+64+c2];
        a0 += blo(v0)+blo(v1)+blo(v2)+blo(v3)+blo(v4)+blo(v5)+blo(v6)+blo(v7);
        a1 += bhi(v0)+bhi(v1)+bhi(v2)+bhi(v3)+bhi(v4)+bhi(v5)+bhi(v6)+bhi(v7);
    }
    if (i + 4 <= e2){
        int s0=csr2[i].x,s1=csr2[i+1].x,s2=csr2[i+2].x,s3=csr2[i+3].x;
        uint v0=hp[(size_t)s0*AKU+64+c2], v1=hp[(size_t)s1*AKU+64+c2],
             v2=hp[(size_t)s2*AKU+64+c2], v3=hp[(size_t)s3*AKU+64+c2];
        a0 += blo(v0)+blo(v1)+blo(v2)+blo(v3);
        a1 += bhi(v0)+bhi(v1)+bhi(v2)+bhi(v3);
        i += 4;
    }
    for (; i < e2; ++i){
        uint v = hp[(size_t)csr2[i].x*AKU+64+c2];
        a0 += blo(v); a1 += bhi(v);
    }
    ((uint*)A)[(size_t)node*AKU + c2] = pack2(a0,a1);
}

// ---- two-stage column sum of final h ----
__global__ void k_sum1(const ushort* __restrict__ A, float* __restrict__ partial){
    int bid = blockIdx.x, tid = threadIdx.x;
    int lane = tid&63, w2 = tid>>6;
    int nb = bid*64;
    float a0=0.f, a1=0.f;
    const uint* hp = (const uint*)A;
    #pragma unroll
    for (int r=w2; r<64; r+=4){
        int n = nb + r;
        if (n < NN){
            uint v = hp[(size_t)n*AKU + 64 + lane];
            a0 += blo(v); a1 += bhi(v);
        }
    }
    __shared__ float s0[4][64], s1[4][64];
    s0[w2][lane]=a0; s1[w2][lane]=a1;
    __syncthreads();
    if (w2==0){
        a0 = s0[0][lane]+s0[1][lane]+s0[2][lane]+s0[3][lane];
        a1 = s1[0][lane]+s1[1][lane]+s1[2][lane]+s1[3][lane];
        ((float2*)partial)[(size_t)bid*64 + lane] = make_float2(a0,a1);
    }
}
__global__ void k_sum2(const float* __restrict__ partial, float* __restrict__ gsum){
    int c = blockIdx.x;          // 0..127
    int tid = threadIdx.x;       // 256
    int lane = tid&63, w = tid>>6;
    float a = 0.f;
    for (int b=tid; b<NSB; b+=256) a += partial[(size_t)b*128 + c];
    #pragma unroll
    for (int d=1; d<64; d<<=1) a += __shfl_xor(a, d);
    __shared__ float sh[4];
    if (lane==0) sh[w]=a;
    __syncthreads();
    if (tid==0) gsum[c] = sh[0]+sh[1]+sh[2]+sh[3];
}

// ---- tiny agents + value head, LDS-staged z + wave-parallel reductions ----
__global__ void k_small(const float* __restrict__ ef, const int* __restrict__ paths,
                        const int* __restrict__ pmask, const float* __restrict__ pfeat,
                        const int* __restrict__ mmask, const int* __restrict__ smask,
                        const float* __restrict__ pspec,
                        const float* __restrict__ W_ep, const float* __restrict__ b_ep,
                        const float* __restrict__ W_path, const float* __restrict__ b_path,
                        const float* __restrict__ W_mod, const float* __restrict__ b_mod,
                        const float* __restrict__ c1w, const float* __restrict__ c1b,
                        const float* __restrict__ c2w, const float* __restrict__ c2b,
                        const float* __restrict__ W_val, const float* __restrict__ b_val,
                        const float* __restrict__ gsum, float* __restrict__ out){
    __shared__ float Wep_s[FD][HD];   // 8KB
    __shared__ float esum[NPATH][FD]; // 1KB
    __shared__ float z[NPATH][HD];
    __shared__ float lf[NS];
    __shared__ float spec[NS];
    __shared__ float red[8];
    __shared__ float scal[3];
    __shared__ int   sel[3];
    __shared__ float maxsh;
    int tid = threadIdx.x, lane = tid&63, w = tid>>6;

    for (int i=tid; i<FD*HD; i+=512) Wep_s[i>>7][i&127] = W_ep[i];
    if (tid < NPATH*FD){
        int p = tid>>4, k = tid&15;
        float a = 0.f;
        #pragma unroll
        for (int l=0;l<PL;l++){
            int eid = paths[p*PL + l];
            a += ef[(size_t)eid*FD + k];
        }
        esum[p][k] = a*0.125f;
    }
    __syncthreads();
    #pragma unroll
    for (int i=tid; i<NPATH*HD; i+=512){
        int p = i>>7, c = i&127;
        float a = b_ep[c];
        #pragma unroll
        for (int k=0;k<FD;k++) a += esum[p][k]*Wep_s[k][c];
        z[p][c] = a;
    }
    __syncthreads();
    { // logits_p
        int p = tid>>5, sub = tid&31;
        float part = 0.f;
        #pragma unroll
        for (int c=sub;c<HD;c+=32) part += z[p][c]*W_path[c];
        #pragma unroll
        for (int d=16; d>=1; d>>=1) part += __shfl_xor(part, d);
        if (sub==0) lf[p] = (pmask[p]==0)? NEGV : part + b_path[0];
    }
    __syncthreads();
    if (w==0){
        float v = (lane<NPATH)? lf[lane] : -3.0e38f;
        float m = v;
        #pragma unroll
        for (int d=1; d<64; d<<=1) m = fmaxf(m, __shfl_xor(m, d));
        float e = (lane<NPATH)? __expf(v-m) : 0.f;
        #pragma unroll
        for (int d=1; d<64; d<<=1) e += __shfl_xor(e, d);
        int idx = (lane<NPATH && v==m)? lane : (1<<30);
        #pragma unroll
        for (int d=1; d<64; d<<=1) idx = min(idx, __shfl_xor(idx, d));
        if (lane==0){ sel[0]=idx; scal[0] = -logf(e); }
    }
    __syncthreads();
    int pstar = sel[0];
    if (w < NM){
        float part = 0.f;
        #pragma unroll
        for (int c=lane;c<HD;c+=64) part += z[pstar][c]*W_mod[c*NM + w];
        if (lane<3) part += pfeat[pstar*3+lane]*W_mod[(HD+lane)*NM + w];
        #pragma unroll
        for (int d=1; d<64; d<<=1) part += __shfl_xor(part, d);
        if (lane==0) red[w] = (mmask[pstar*NM + w]==0)? NEGV : part + b_mod[w];
    } else if (w == 7){
        float part = gsum[lane]*W_val[lane] + gsum[lane+64]*W_val[lane+64];
        #pragma unroll
        for (int d=1; d<64; d<<=1) part += __shfl_xor(part, d);
        if (lane==0) scal[2] = part/(float)NN + b_val[0];
    }
    __syncthreads();
    if (w==0){
        float v = (lane<NM)? red[lane] : -3.0e38f;
        float m = v;
        #pragma unroll
        for (int d=1; d<64; d<<=1) m = fmaxf(m, __shfl_xor(m, d));
        float e = (lane<NM)? __expf(v-m) : 0.f;
        #pragma unroll
        for (int d=1; d<64; d<<=1) e += __shfl_xor(e, d);
        int idx = (lane<NM && v==m)? lane : (1<<30);
        #pragma unroll
        for (int d=1; d<64; d<<=1) idx = min(idx, __shfl_xor(idx, d));
        if (lane==0){ sel[1]=idx; scal[1] = -logf(e); }
    }
    __syncthreads();
    int mstar = sel[1];
    if (tid < NS) spec[tid] = pspec[pstar*NS + tid];
    __syncthreads();
    float v = -3.0e38f;
    if (tid < NS){
        float acc = c2b[0];
        #pragma unroll
        for (int ch=0; ch<8; ch++){
            float a = c1b[ch];
            #pragma unroll
            for (int k=0;k<5;k++){
                int ss = tid + k - 2;
                if (ss>=0 && ss<NS) a += spec[ss]*c1w[ch*5+k];
            }
            a = fmaxf(a, 0.f);
            acc += a*c2w[ch];
        }
        v = (smask[pstar*NM*NS + mstar*NS + tid]==0) ? NEGV : acc;
    }
    float m = v;
    #pragma unroll
    for (int d=1; d<64; d<<=1) m = fmaxf(m, __shfl_xor(m, d));
    if (lane==0) red[w] = m;
    __syncthreads();
    if (tid==0){
        float mm = red[0];
        #pragma unroll
        for (int i=1;i<8;i++) mm = fmaxf(mm, red[i]);
        maxsh = mm; sel[2] = 1<<30;
    }
    __syncthreads();
    float M2 = maxsh;
    if (tid<NS && v==M2) atomicMin(&sel[2], tid);
    float e = (tid<NS)? __expf(v-M2) : 0.f;
    #pragma unroll
    for (int d=1; d<64; d<<=1) e += __shfl_xor(e, d);
    if (lane==0) red[w] = e;
    __syncthreads();
    if (tid==0){
        float se = 0.f;
        #pragma unroll
        for (int i=0;i<8;i++) se += red[i];
        out[0] = (float)pstar;
        out[1] = (float)sel[2];
        out[2] = (float)mstar;
        out[3] = scal[0] + scal[1] - logf(se);
        out[4] = scal[2];
    }
}

extern "C" void kernel_launch(void* const* d_in, const int* in_sizes, int n_in,
                              void* d_out, int out_size, void* d_ws, size_t ws_size,
                              hipStream_t stream) {
    (void)in_sizes; (void)n_in; (void)out_size; (void)ws_size;
    const float* node_feat     = (const float*)d_in[0];
    const float* edge_feat     = (const float*)d_in[1];
    const int*   edge_index    = (const int*)d_in[2];
    const int*   paths         = (const int*)d_in[3];
    const int*   path_mask     = (const int*)d_in[4];
    const float* path_features = (const float*)d_in[5];
    const int*   mod_masks     = (const int*)d_in[6];
    const int*   spec_masks    = (const int*)d_in[7];
    const float* path_spectrum = (const float*)d_in[8];
    const float* W_np  = (const float*)d_in[9];
    const float* b_np  = (const float*)d_in[10];
    const float* W_ep  = (const float*)d_in[11];
    const float* b_ep  = (const float*)d_in[12];
    const float* W_msg = (const float*)d_in[13];
    const float* b_msg = (const float*)d_in[14];
    const float* W_ih  = (const float*)d_in[15];
    const float* b_ih  = (const float*)d_in[16];
    const float* W_hh  = (const float*)d_in[17];
    const float* b_hh  = (const float*)d_in[18];
    const float* W_path = (const float*)d_in[19];
    const float* b_path = (const float*)d_in[20];
    const float* W_mod  = (const float*)d_in[21];
    const float* b_mod  = (const float*)d_in[22];
    const float* c1w = (const float*)d_in[23];
    const float* c1b = (const float*)d_in[24];
    const float* c2w = (const float*)d_in[25];
    const float* c2b = (const float*)d_in[26];
    const float* W_val = (const float*)d_in[27];
    const float* b_val = (const float*)d_in[28];

    char* ws = (char*)d_ws;
    size_t off = 0;
    auto alloc = [&](size_t bytes)->char*{
        char* p = ws + off;
        off += (bytes + 255) & ~(size_t)255;
        return p;
    };
    int*    offs    = (int*)alloc((size_t)(NN+1)*4);
    int*    Cmat    = (int*)alloc((size_t)NBLK*NBKT*4);
    int*    bkttot  = (int*)alloc((size_t)NBKT*4);
    int*    bktbase = (int*)alloc((size_t)(NBKT+1)*4);
    int2*   bkt2    = (int2*)alloc((size_t)NE*8);
    int2*   csr2    = (int2*)alloc((size_t)NE*8);
    float*  ef_sum  = (float*)alloc((size_t)NN*FD*4);
    float*  nf_sum  = (float*)alloc((size_t)NN*FD*4);
    float*  Wf      = (float*)alloc((size_t)FD*HD*4);
    float*  bfv     = (float*)alloc((size_t)HD*4);
    ushort* W2T     = (ushort*)alloc((size_t)512*AK*2);
    float*  Wt32    = (float*)alloc((size_t)512*HD*4);
    ushort* W1T     = (ushort*)alloc((size_t)512*AK1*2);
    ushort* A       = (ushort*)alloc((size_t)NN*AK*2);
    ushort* A1p     = (ushort*)alloc((size_t)NN*AK1*2);
    float*  partial = (float*)alloc((size_t)NSB*HD*4);
    float*  gsum    = (float*)alloc((size_t)HD*4);

    k_hist<<<NBLK, 256, 0, stream>>>(edge_index, Cmat);
    k_cscanA<<<(NBKT+3)/4, 256, 0, stream>>>(Cmat, bkttot);
    k_bscan<<<1, 256, 0, stream>>>(bkttot, bktbase, offs);
    k_scatA<<<NBLK, 256, 0, stream>>>(edge_index, Cmat, bktbase, bkt2);
    k_scatB<<<NBKT, 256, 0, stream>>>(edge_index, bkt2, bktbase, offs, csr2);
    k_gat16<<<NN/4, 256, 0, stream>>>(csr2, edge_feat, node_feat, offs, ef_sum, nf_sum);
    k_folds<<<9, 256, 0, stream>>>(W_ep, b_ep, W_msg, b_msg, Wf, bfv);
    k_wprep2<<<512, AK, 0, stream>>>(W_ih, W_hh, W_msg, Wf, bfv, b_ih, b_hh, W2T, Wt32);
    k_wprep1<<<512, AK1, 0, stream>>>(W_np, b_np, W_hh, Wt32, W2T, W1T);
    k_prep2<<<NN*32/256, 256, 0, stream>>>(node_feat, nf_sum, ef_sum, offs, A1p, A);

    const int GRID = 8*4*49;   // 1568 (xcd, gate, m-chunk); 4 idle
    // iter 1: A1p (K=64) -> fused GRU -> A.h  (h0 inline from nf)
    k_fused<true><<<GRID, 256, 0, stream>>>(A1p, W1T, node_feat, W_np, b_np, A);
    // iter 2: gather -> fused -> A.h (in place)
    k_gather<<<NN/4, 256, 0, stream>>>(A, offs, csr2);
    k_fused<false><<<GRID, 256, 0, stream>>>(A, W2T, node_feat, W_np, b_np, A);
    // iter 3
    k_gather<<<NN/4, 256, 0, stream>>>(A, offs, csr2);
    k_fused<false><<<GRID, 256, 0, stream>>>(A, W2T, node_feat, W_np, b_np, A);

    k_sum1<<<NSB, 256, 0, stream>>>(A, partial);
    k_sum2<<<HD, 256, 0, stream>>>(partial, gsum);
    k_small<<<1, 512, 0, stream>>>(edge_feat, paths, path_mask, path_features,
                                   mod_masks, spec_masks, path_spectrum,
                                   W_ep, b_ep, W_path, b_path, W_mod, b_mod,
                                   c1w, c1b, c2w, c2b, W_val, b_val,
                                   gsum, (float*)d_out);
}